// Round 13
// baseline (454.042 us; speedup 1.0000x reference)
//
#include <hip/hip_runtime.h>
#include <cmath>

namespace {

constexpr int XC = 64, XH = 128, XW = 128;
constexpr int NSEQ = 128;   // B(2) * 64 cubes
constexpr int TLEN = 1025;  // gt token + 1024
constexpr int LSEQ = 1024;
constexpr int NCH = 16;     // chunks per sequence (parallel scan)
constexpr int CHUNK = 65;   // 16*65 = 1040 >= 1025
constexpr int TT = 96;      // token tile for fused p1
constexpr int NT = 11;      // ceil(1025/96)
constexpr int SCW = 68;     // SC row: xc[32] B[16] C[16] dt0[1] pad[3]

__device__ __forceinline__ int xidx(int b, int c, int h, int w) {
    return ((b * XC + c) * XH + h) * XW + w;
}
__device__ __forceinline__ int oidx(int b, int cube, int c, int i, int j) {
    int h = cube * 2 + (i >> 3);
    int w = ((i & 7) << 4) | j;
    return xidx(b, c, h, w);
}
__device__ __forceinline__ float siluf(float v) { return v / (1.0f + __expf(-v)); }
__device__ __forceinline__ float softplusf(float v) {
    return v > 20.0f ? v : log1pf(__expf(v));
}

template <int MODE>
__device__ __forceinline__ float gather_val(const float* __restrict__ x,
                                            const float* __restrict__ s_gt,
                                            int t, int k, int b, int bi, int bj) {
    if (t == 0) return s_gt[k];
    int l = t - 1;
    if (MODE == 0) {
        int i2 = l >> 5, j2 = l & 31;
        int h = bi * 16 + (i2 >> 1), w = bj * 16 + (j2 >> 1);
        int coff = ((i2 & 1) << 1) | (j2 & 1);
        return x[xidx(b, k * 4 + coff, h, w)];
    } else if (MODE == 1) {
        int c = l >> 4, j = l & 15;
        return x[xidx(b, c, bi * 16 + k, bj * 16 + j)];
    } else {
        int c = l >> 4, i = l & 15;
        return x[xidx(b, c, bi * 16 + i, bj * 16 + k)];
    }
}

// ==== fused phase 1: gather+LN+in-proj+conv+x-proj, register-tiled GEMMs ====
template <int MODE>
__global__ __launch_bounds__(256) void k_p1(
    const float* __restrict__ x, const float* __restrict__ gt,
    const float* __restrict__ lng, const float* __restrict__ lnb,
    const float* __restrict__ in_w,    // (64,16)
    const float* __restrict__ conv_w,  // (32,4)
    const float* __restrict__ conv_b,  // (32)
    const float* __restrict__ xproj_w, // (33,32)
    float* __restrict__ Zb,            // (NSEQ,TLEN,32)
    float* __restrict__ sc)            // (NSEQ,TLEN,SCW)
{
    const int n = blockIdx.x / NT, tile = blockIdx.x % NT;
    const int t0 = tile * TT;
    const int ntk = min(TT, TLEN - t0);
    const int nth = ntk + 3;  // with 3-token front halo
    const int b = n >> 6, cube = n & 63, bi = cube >> 3, bj = cube & 7;
    const int tid = threadIdx.x;

    // s_v [TT+3][17] overlaid on s_xc [TT][37]: disjoint lifetimes
    __shared__ __align__(16) float s_pool[TT * 37];
    float (*s_v)[17]  = (float(*)[17])s_pool;
    float (*s_xc)[37] = (float(*)[37])s_pool;
    __shared__ __align__(16) float s_xi[TT + 3][36];
    __shared__ __align__(16) float s_wT[16][64];   // s_wT[k][oc] = in_w[oc][k]
    __shared__ __align__(16) float s_xpT[32][36];  // s_xpT[cc][q] = xproj_w[q+1][cc]
    __shared__ float s_xp0[32];
    __shared__ float s_cw[128], s_cb[32];
    __shared__ float s_g[16], s_bb[16], s_gt[16];
    __shared__ float s_dt0[TT];

    for (int i = tid; i < 64 * 16; i += 256) s_wT[i & 15][i >> 4] = in_w[i];
    for (int i = tid; i < 33 * 32; i += 256) {
        int r = i >> 5, cc = i & 31;
        float v = xproj_w[i];
        if (r == 0) s_xp0[cc] = v;
        else s_xpT[cc][r - 1] = v;
    }
    if (tid < 128) s_cw[tid] = conv_w[tid];
    if (tid < 32) s_cb[tid] = conv_b[tid];
    if (tid < 16) { s_g[tid] = lng[tid]; s_bb[tid] = lnb[tid]; s_gt[tid] = gt[tid]; }
    __syncthreads();

    // ---- gather + LN, token-per-thread, registers only
    if (tid < nth) {
        int t = t0 - 3 + tid;
        float v[16];
        if (t < 0) {
#pragma unroll
            for (int k = 0; k < 16; k++) v[k] = 0.f;
        } else {
#pragma unroll
            for (int k = 0; k < 16; k++) v[k] = gather_val<MODE>(x, s_gt, t, k, b, bi, bj);
            float mu = 0.f;
#pragma unroll
            for (int k = 0; k < 16; k++) mu += v[k];
            mu *= (1.f / 16.f);
            float var = 0.f;
#pragma unroll
            for (int k = 0; k < 16; k++) { float d = v[k] - mu; var += d * d; }
            float inv = rsqrtf(var * (1.f / 16.f) + 1e-5f);
#pragma unroll
            for (int k = 0; k < 16; k++) v[k] = (v[k] - mu) * inv * s_g[k] + s_bb[k];
        }
#pragma unroll
        for (int k = 0; k < 16; k++) s_v[tid][k] = v[k];
    }
    __syncthreads();

    // ---- in-proj, 4-token x 4-oc register tiles (og<8 -> xi LDS, og>=8 -> z)
    {
        const int ntt = (nth + 3) >> 2;
        for (int tl0 = tid; tl0 < ntt * 16; tl0 += 256) {
            int tt = tl0 >> 4, og = tl0 & 15;
            int oc = og * 4;
            float acc[4][4] = {{0.f}};
#pragma unroll
            for (int k = 0; k < 16; k++) {
                float4 wv = *(const float4*)&s_wT[k][oc];
                float a0 = s_v[4 * tt + 0][k];
                float a1 = s_v[4 * tt + 1][k];
                float a2 = s_v[4 * tt + 2][k];
                float a3 = s_v[4 * tt + 3][k];
                acc[0][0] += a0 * wv.x; acc[0][1] += a0 * wv.y; acc[0][2] += a0 * wv.z; acc[0][3] += a0 * wv.w;
                acc[1][0] += a1 * wv.x; acc[1][1] += a1 * wv.y; acc[1][2] += a1 * wv.z; acc[1][3] += a1 * wv.w;
                acc[2][0] += a2 * wv.x; acc[2][1] += a2 * wv.y; acc[2][2] += a2 * wv.z; acc[2][3] += a2 * wv.w;
                acc[3][0] += a3 * wv.x; acc[3][1] += a3 * wv.y; acc[3][2] += a3 * wv.z; acc[3][3] += a3 * wv.w;
            }
#pragma unroll
            for (int i = 0; i < 4; i++) {
                int tl = 4 * tt + i;
                if (tl >= nth) break;
                if (og < 8) {
                    *(float4*)&s_xi[tl][oc] =
                        make_float4(acc[i][0], acc[i][1], acc[i][2], acc[i][3]);
                } else if (tl >= 3) {
                    *(float4*)&Zb[((size_t)n * TLEN + t0 + tl - 3) * 32 + (oc - 32)] =
                        make_float4(acc[i][0], acc[i][1], acc[i][2], acc[i][3]);
                }
            }
        }
    }
    __syncthreads();  // s_v dead; pool becomes s_xc

    // ---- conv4 + silu: thread = (cc, token-group), weights in registers
    {
        int cc = tid & 31, jg = tid >> 5;
        float c0 = s_cw[cc * 4 + 0], c1 = s_cw[cc * 4 + 1];
        float c2 = s_cw[cc * 4 + 2], c3 = s_cw[cc * 4 + 3];
        float cb = s_cb[cc];
        for (int j = jg; j < ntk; j += 8) {
            float acc = 0.f;
            acc += c0 * s_xi[j + 0][cc];
            acc += c1 * s_xi[j + 1][cc];
            acc += c2 * s_xi[j + 2][cc];
            acc += c3 * s_xi[j + 3][cc];
            s_xc[j][cc] = siluf(acc + cb);
        }
    }
    __syncthreads();

    // ---- x-proj B/C rows, 4-token x 4-q register tile -> SC[32..63]
    {
        int qt = tid & 7, tt = tid >> 3;
        if (4 * tt < ntk) {
            float acc[4][4] = {{0.f}};
#pragma unroll
            for (int cc = 0; cc < 32; cc++) {
                float4 wv = *(const float4*)&s_xpT[cc][4 * qt];
                float a0 = s_xc[4 * tt + 0][cc];
                float a1 = s_xc[4 * tt + 1][cc];
                float a2 = s_xc[4 * tt + 2][cc];
                float a3 = s_xc[4 * tt + 3][cc];
                acc[0][0] += a0 * wv.x; acc[0][1] += a0 * wv.y; acc[0][2] += a0 * wv.z; acc[0][3] += a0 * wv.w;
                acc[1][0] += a1 * wv.x; acc[1][1] += a1 * wv.y; acc[1][2] += a1 * wv.z; acc[1][3] += a1 * wv.w;
                acc[2][0] += a2 * wv.x; acc[2][1] += a2 * wv.y; acc[2][2] += a2 * wv.z; acc[2][3] += a2 * wv.w;
                acc[3][0] += a3 * wv.x; acc[3][1] += a3 * wv.y; acc[3][2] += a3 * wv.z; acc[3][3] += a3 * wv.w;
            }
#pragma unroll
            for (int i = 0; i < 4; i++) {
                int j = 4 * tt + i;
                if (j < ntk)
                    *(float4*)&sc[((size_t)n * TLEN + t0 + j) * SCW + 32 + 4 * qt] =
                        make_float4(acc[i][0], acc[i][1], acc[i][2], acc[i][3]);
            }
        }
        // dt0 per token (reads only s_xc / s_xp0)
        if (tid < ntk) {
            float acc = 0.f;
#pragma unroll
            for (int cc = 0; cc < 32; cc++) acc += s_xc[tid][cc] * s_xp0[cc];
            s_dt0[tid] = acc;
        }
    }
    __syncthreads();

    // ---- xc + dt0 emits (coalesced stores)
    {
        float* scb = sc + ((size_t)n * TLEN + t0) * SCW;
        for (int it = tid; it < ntk * 32; it += 256) {
            int j = it >> 5, cc = it & 31;
            scb[j * SCW + cc] = s_xc[j][cc];
        }
        if (tid < ntk) scb[tid * SCW + 64] = s_dt0[tid];
    }
}

// -------- phase 2a: per-chunk scan summaries; thread = (d, s-group of 4) ----
__global__ __launch_bounds__(128) void k_scan1(const float* __restrict__ sc,
                                               const float* __restrict__ A_log,
                                               const float* __restrict__ dt_w,
                                               const float* __restrict__ dt_b,
                                               float* __restrict__ Psum,
                                               float* __restrict__ Fsum)
{
    int n = blockIdx.x >> 4;
    int c = blockIdx.x & (NCH - 1);
    int t0 = c * CHUNK;
    int nt = min(CHUNK, TLEN - t0);
    __shared__ __align__(16) float s_sc[CHUNK * SCW];
    __shared__ float s_dt[CHUNK * 32];
    __shared__ float s_dw[32], s_db[32];
    const float* src = sc + ((size_t)n * TLEN + t0) * SCW;
    int nv4 = nt * (SCW / 4);
    for (int i = threadIdx.x; i < nv4; i += 128)
        ((float4*)s_sc)[i] = ((const float4*)src)[i];
    int tid = threadIdx.x, d = tid >> 2, sg = tid & 3;
    if (tid < 32) { s_dw[tid] = dt_w[tid]; s_db[tid] = dt_b[tid]; }
    float4 Av = *(const float4*)&A_log[d * 16 + sg * 4];
    float A0 = -__expf(Av.x), A1 = -__expf(Av.y), A2 = -__expf(Av.z), A3 = -__expf(Av.w);
    __syncthreads();
    // parallel dt expansion (outside the serial loop)
    for (int i = tid; i < nt * 32; i += 128) {
        int t = i >> 5, dd = i & 31;
        s_dt[i] = softplusf(s_sc[t * SCW + 64] * s_dw[dd] + s_db[dd]);
    }
    __syncthreads();
    float h0 = 0.f, h1 = 0.f, h2 = 0.f, h3 = 0.f;
    float P0 = 1.f, P1 = 1.f, P2 = 1.f, P3 = 1.f;
    for (int t = 0; t < nt; t++) {
        const float* p = s_sc + t * SCW;
        float dt = s_dt[t * 32 + d], xc = p[d];
        float4 Bv = *(const float4*)&p[32 + sg * 4];
        float a0 = __expf(dt * A0); h0 = a0 * h0 + dt * Bv.x * xc; P0 *= a0;
        float a1 = __expf(dt * A1); h1 = a1 * h1 + dt * Bv.y * xc; P1 *= a1;
        float a2 = __expf(dt * A2); h2 = a2 * h2 + dt * Bv.z * xc; P2 *= a2;
        float a3 = __expf(dt * A3); h3 = a3 * h3 + dt * Bv.w * xc; P3 *= a3;
    }
    size_t base = ((size_t)n * NCH + c) * 512 + d * 16 + sg * 4;
    *(float4*)&Psum[base] = make_float4(P0, P1, P2, P3);
    *(float4*)&Fsum[base] = make_float4(h0, h1, h2, h3);
}

// -------- phase 2b: combine chunk summaries -> incoming state per chunk -----
__global__ __launch_bounds__(512) void k_comb(const float* __restrict__ Psum,
                                              const float* __restrict__ Fsum,
                                              float* __restrict__ Hin)
{
    int n = blockIdx.x, tid = threadIdx.x;
    const float* pb = Psum + (size_t)n * NCH * 512;
    const float* fb = Fsum + (size_t)n * NCH * 512;
    float* hb = Hin + (size_t)n * NCH * 512;
    float H = 0.f;
#pragma unroll
    for (int c = 0; c < NCH; c++) {
        float P = pb[(size_t)c * 512 + tid];
        float F = fb[(size_t)c * 512 + tid];
        hb[(size_t)c * 512 + tid] = H;
        H = F + P * H;
    }
}

// -------- phase 2c: per-chunk scan pass 2, thread = (d, s-group of 4) -------
__global__ __launch_bounds__(128) void k_scan2(const float* __restrict__ sc,
                                               const float* __restrict__ A_log,
                                               const float* __restrict__ dt_w,
                                               const float* __restrict__ dt_b,
                                               const float* __restrict__ Dp,
                                               const float* __restrict__ Hin,
                                               float* __restrict__ yc)  // (NSEQ,TLEN,32)
{
    int n = blockIdx.x >> 4;
    int c = blockIdx.x & (NCH - 1);
    int t0 = c * CHUNK;
    int nt = min(CHUNK, TLEN - t0);
    __shared__ __align__(16) float s_sc[CHUNK * SCW];
    __shared__ float s_dt[CHUNK * 32];
    __shared__ __align__(16) float s_y[CHUNK * 32];
    __shared__ float s_dw[32], s_db[32];
    const float* src = sc + ((size_t)n * TLEN + t0) * SCW;
    int nv4 = nt * (SCW / 4);
    for (int i = threadIdx.x; i < nv4; i += 128)
        ((float4*)s_sc)[i] = ((const float4*)src)[i];
    int tid = threadIdx.x, d = tid >> 2, sg = tid & 3;
    if (tid < 32) { s_dw[tid] = dt_w[tid]; s_db[tid] = dt_b[tid]; }
    float4 Av = *(const float4*)&A_log[d * 16 + sg * 4];
    float A0 = -__expf(Av.x), A1 = -__expf(Av.y), A2 = -__expf(Av.z), A3 = -__expf(Av.w);
    float Dd = Dp[d];
    float4 Hv = *(const float4*)&Hin[((size_t)n * NCH + c) * 512 + d * 16 + sg * 4];
    float h0 = Hv.x, h1 = Hv.y, h2 = Hv.z, h3 = Hv.w;
    __syncthreads();
    // parallel dt expansion (outside the serial loop)
    for (int i = tid; i < nt * 32; i += 128) {
        int t = i >> 5, dd = i & 31;
        s_dt[i] = softplusf(s_sc[t * SCW + 64] * s_dw[dd] + s_db[dd]);
    }
    __syncthreads();
    for (int t = 0; t < nt; t++) {
        const float* p = s_sc + t * SCW;
        float dt = s_dt[t * 32 + d], xc = p[d];
        float4 Bv = *(const float4*)&p[32 + sg * 4];
        float4 Cv = *(const float4*)&p[48 + sg * 4];
        float a0 = __expf(dt * A0); h0 = a0 * h0 + dt * Bv.x * xc;
        float a1 = __expf(dt * A1); h1 = a1 * h1 + dt * Bv.y * xc;
        float a2 = __expf(dt * A2); h2 = a2 * h2 + dt * Bv.z * xc;
        float a3 = __expf(dt * A3); h3 = a3 * h3 + dt * Bv.w * xc;
        float pp = h0 * Cv.x + h1 * Cv.y + h2 * Cv.z + h3 * Cv.w;
        pp += __shfl_xor(pp, 1);
        pp += __shfl_xor(pp, 2);
        if (sg == 0) s_y[t * 32 + d] = pp + Dd * xc;
    }
    __syncthreads();
    float* yb = yc + ((size_t)n * TLEN + t0) * 32;
    int ny4 = nt * 8;
    for (int i = threadIdx.x; i < ny4; i += 128)
        ((float4*)yb)[i] = ((const float4*)s_y)[i];
}

// ---------------- phase 3: gate + out-proj + scatter ------------------------
template <int MODE>
__global__ void k_p3(const float* __restrict__ yc, const float* __restrict__ Zb,
                     const float* __restrict__ out_w,  // (16,32)
                     float* __restrict__ out)
{
    __shared__ float s_w[16 * 32];
    for (int i = threadIdx.x; i < 512; i += blockDim.x) s_w[i] = out_w[i];
    __syncthreads();
    int tid = blockIdx.x * blockDim.x + threadIdx.x;
    if (tid >= NSEQ * LSEQ) return;
    int n = tid >> 10, l = tid & 1023, t = l + 1;
    const float* y = yc + ((size_t)n * TLEN + t) * 32;
    const float* z = Zb + ((size_t)n * TLEN + t) * 32;
    float yv[32];
#pragma unroll
    for (int c = 0; c < 32; c++) yv[c] = y[c] * siluf(z[c]);
    float o[16];
#pragma unroll
    for (int j = 0; j < 16; j++) {
        float acc = 0.f;
#pragma unroll
        for (int c = 0; c < 32; c++) acc += yv[c] * s_w[j * 32 + c];
        o[j] = acc * (1.0f / 3.0f);
    }
    int b = n >> 6, cube = n & 63;
    if (MODE == 0) {
        int i2 = l >> 5, j2 = l & 31;
        int io = i2 >> 1, jo = j2 >> 1;
        int coff = ((i2 & 1) << 1) | (j2 & 1);
#pragma unroll
        for (int j = 0; j < 16; j++) out[oidx(b, cube, j * 4 + coff, io, jo)] = o[j];
    } else if (MODE == 1) {
        int c = l >> 4, jj = l & 15;
#pragma unroll
        for (int j = 0; j < 16; j++) out[oidx(b, cube, c, j, jj)] += o[j];
    } else {
        int c = l >> 4, ii = l & 15;
#pragma unroll
        for (int j = 0; j < 16; j++) out[oidx(b, cube, c, ii, j)] += o[j];
    }
}

}  // namespace

extern "C" void kernel_launch(void* const* d_in, const int* in_sizes, int n_in,
                              void* d_out, int out_size, void* d_ws, size_t ws_size,
                              hipStream_t stream) {
    const float* x   = (const float*)d_in[0];
    const float* gt1 = (const float*)d_in[1];
    const float* gt2 = (const float*)d_in[2];
    const float* ln1g = (const float*)d_in[3];
    const float* ln1b = (const float*)d_in[4];
    const float* ln2g = (const float*)d_in[5];
    const float* ln2b = (const float*)d_in[6];
    const float* m[2][9];
    for (int mi = 0; mi < 2; mi++)
        for (int k = 0; k < 9; k++) m[mi][k] = (const float*)d_in[7 + mi * 9 + k];
    float* out = (float*)d_out;

    float* ws = (float*)d_ws;
    float* ZB = ws;                               // 128*1025*32 (16.8 MB)
    float* SC = ZB + (size_t)NSEQ * TLEN * 32;    // 128*1025*68 (35.7 MB)
    float* YC = SC + (size_t)NSEQ * TLEN * SCW;   // 16.8 MB
    float* PS = YC + (size_t)NSEQ * TLEN * 32;    // 4.2 MB
    float* FS = PS + (size_t)NSEQ * NCH * 512;    // 4.2 MB
    float* HI = FS + (size_t)NSEQ * NCH * 512;    // 4.2 MB

    dim3 gtile(NSEQ * NT);
    dim3 gscan(NSEQ * NCH);
    dim3 grd3((NSEQ * LSEQ + 255) / 256);

    for (int mode = 0; mode < 3; mode++) {
        int pi = (mode == 0) ? 0 : 1;
        const float* gt = (mode == 0) ? gt1 : gt2;
        const float* lg = (mode == 0) ? ln1g : ln2g;
        const float* lb = (mode == 0) ? ln1b : ln2b;
        const float* const* P = m[pi];
        // P: 0 in_w, 1 conv_w, 2 conv_b, 3 xproj_w, 4 dt_w, 5 dt_b, 6 A_log, 7 D, 8 out_w
        if (mode == 0)
            k_p1<0><<<gtile, dim3(256), 0, stream>>>(x, gt, lg, lb, P[0], P[1], P[2], P[3], ZB, SC);
        else if (mode == 1)
            k_p1<1><<<gtile, dim3(256), 0, stream>>>(x, gt, lg, lb, P[0], P[1], P[2], P[3], ZB, SC);
        else
            k_p1<2><<<gtile, dim3(256), 0, stream>>>(x, gt, lg, lb, P[0], P[1], P[2], P[3], ZB, SC);
        k_scan1<<<gscan, dim3(128), 0, stream>>>(SC, P[6], P[4], P[5], PS, FS);
        k_comb<<<dim3(NSEQ), dim3(512), 0, stream>>>(PS, FS, HI);
        k_scan2<<<gscan, dim3(128), 0, stream>>>(SC, P[6], P[4], P[5], P[7], HI, YC);
        if (mode == 0)      k_p3<0><<<grd3, dim3(256), 0, stream>>>(YC, ZB, P[8], out);
        else if (mode == 1) k_p3<1><<<grd3, dim3(256), 0, stream>>>(YC, ZB, P[8], out);
        else                k_p3<2><<<grd3, dim3(256), 0, stream>>>(YC, ZB, P[8], out);
    }
}

// Round 14
// 448.770 us; speedup vs baseline: 1.0117x; 1.0117x over previous
//
#include <hip/hip_runtime.h>
#include <cmath>

namespace {

constexpr int XC = 64, XH = 128, XW = 128;
constexpr int NSEQ = 128;   // B(2) * 64 cubes
constexpr int TLEN = 1025;  // gt token + 1024
constexpr int LSEQ = 1024;
constexpr int NCH = 16;     // chunks per sequence (parallel scan)
constexpr int CHUNK = 65;   // 16*65 = 1040 >= 1025
constexpr int TT = 96;      // token tile for fused p1
constexpr int NT = 11;      // ceil(1025/96)

__device__ __forceinline__ int xidx(int b, int c, int h, int w) {
    return ((b * XC + c) * XH + h) * XW + w;
}
__device__ __forceinline__ int oidx(int b, int cube, int c, int i, int j) {
    int h = cube * 2 + (i >> 3);
    int w = ((i & 7) << 4) | j;
    return xidx(b, c, h, w);
}
__device__ __forceinline__ float siluf(float v) { return v / (1.0f + __expf(-v)); }
__device__ __forceinline__ float softplusf(float v) {
    return v > 20.0f ? v : log1pf(__expf(v));
}

template <int MODE>
__device__ __forceinline__ float gather_val(const float* __restrict__ x,
                                            const float* __restrict__ s_gt,
                                            int t, int k, int b, int bi, int bj) {
    if (t == 0) return s_gt[k];
    int l = t - 1;
    if (MODE == 0) {
        int i2 = l >> 5, j2 = l & 31;
        int h = bi * 16 + (i2 >> 1), w = bj * 16 + (j2 >> 1);
        int coff = ((i2 & 1) << 1) | (j2 & 1);
        return x[xidx(b, k * 4 + coff, h, w)];
    } else if (MODE == 1) {
        int c = l >> 4, j = l & 15;
        return x[xidx(b, c, bi * 16 + k, bj * 16 + j)];
    } else {
        int c = l >> 4, i = l & 15;
        return x[xidx(b, c, bi * 16 + i, bj * 16 + k)];
    }
}

// ==== fused phase 1: gather+LN+in-proj+conv+x-proj, register-tiled GEMMs ====
template <int MODE>
__global__ __launch_bounds__(256) void k_p1(
    const float* __restrict__ x, const float* __restrict__ gt,
    const float* __restrict__ lng, const float* __restrict__ lnb,
    const float* __restrict__ in_w,    // (64,16)
    const float* __restrict__ conv_w,  // (32,4)
    const float* __restrict__ conv_b,  // (32)
    const float* __restrict__ xproj_w, // (33,32)
    const float* __restrict__ dt_w,    // (32,1)
    const float* __restrict__ dt_b,    // (32)
    float* __restrict__ Zb,            // (NSEQ,TLEN,32)
    float* __restrict__ sc)            // (NSEQ,TLEN,96): xc[32] dt[32] B[16] C[16]
{
    const int n = blockIdx.x / NT, tile = blockIdx.x % NT;
    const int t0 = tile * TT;
    const int ntk = min(TT, TLEN - t0);
    const int nth = ntk + 3;  // with 3-token front halo
    const int b = n >> 6, cube = n & 63, bi = cube >> 3, bj = cube & 7;
    const int tid = threadIdx.x;

    // s_v [TT+3][17] overlaid on s_xc [TT][37]: disjoint lifetimes
    __shared__ __align__(16) float s_pool[TT * 37];
    float (*s_v)[17]  = (float(*)[17])s_pool;
    float (*s_xc)[37] = (float(*)[37])s_pool;
    __shared__ __align__(16) float s_xi[TT + 3][36];
    __shared__ __align__(16) float s_wT[16][64];   // s_wT[k][oc] = in_w[oc][k]
    __shared__ __align__(16) float s_xpT[32][36];  // s_xpT[cc][q] = xproj_w[q+1][cc]
    __shared__ float s_xp0[32];
    __shared__ float s_cw[128], s_cb[32], s_dw[32], s_db[32];
    __shared__ float s_g[16], s_bb[16], s_gt[16];
    __shared__ float s_dt0[TT];

    for (int i = tid; i < 64 * 16; i += 256) s_wT[i & 15][i >> 4] = in_w[i];
    for (int i = tid; i < 33 * 32; i += 256) {
        int r = i >> 5, cc = i & 31;
        float v = xproj_w[i];
        if (r == 0) s_xp0[cc] = v;
        else s_xpT[cc][r - 1] = v;
    }
    if (tid < 128) s_cw[tid] = conv_w[tid];
    if (tid < 32) { s_cb[tid] = conv_b[tid]; s_dw[tid] = dt_w[tid]; s_db[tid] = dt_b[tid]; }
    if (tid < 16) { s_g[tid] = lng[tid]; s_bb[tid] = lnb[tid]; s_gt[tid] = gt[tid]; }
    __syncthreads();

    // ---- gather + LN, token-per-thread, registers only
    if (tid < nth) {
        int t = t0 - 3 + tid;
        float v[16];
        if (t < 0) {
#pragma unroll
            for (int k = 0; k < 16; k++) v[k] = 0.f;
        } else {
#pragma unroll
            for (int k = 0; k < 16; k++) v[k] = gather_val<MODE>(x, s_gt, t, k, b, bi, bj);
            float mu = 0.f;
#pragma unroll
            for (int k = 0; k < 16; k++) mu += v[k];
            mu *= (1.f / 16.f);
            float var = 0.f;
#pragma unroll
            for (int k = 0; k < 16; k++) { float d = v[k] - mu; var += d * d; }
            float inv = rsqrtf(var * (1.f / 16.f) + 1e-5f);
#pragma unroll
            for (int k = 0; k < 16; k++) v[k] = (v[k] - mu) * inv * s_g[k] + s_bb[k];
        }
#pragma unroll
        for (int k = 0; k < 16; k++) s_v[tid][k] = v[k];
    }
    __syncthreads();

    // ---- in-proj, 4-token x 4-oc register tiles (og<8 -> xi LDS, og>=8 -> z)
    {
        const int ntt = (nth + 3) >> 2;
        for (int tl0 = tid; tl0 < ntt * 16; tl0 += 256) {
            int tt = tl0 >> 4, og = tl0 & 15;
            int oc = og * 4;
            float acc[4][4] = {{0.f}};
#pragma unroll
            for (int k = 0; k < 16; k++) {
                float4 wv = *(const float4*)&s_wT[k][oc];
                float a0 = s_v[4 * tt + 0][k];
                float a1 = s_v[4 * tt + 1][k];
                float a2 = s_v[4 * tt + 2][k];
                float a3 = s_v[4 * tt + 3][k];
                acc[0][0] += a0 * wv.x; acc[0][1] += a0 * wv.y; acc[0][2] += a0 * wv.z; acc[0][3] += a0 * wv.w;
                acc[1][0] += a1 * wv.x; acc[1][1] += a1 * wv.y; acc[1][2] += a1 * wv.z; acc[1][3] += a1 * wv.w;
                acc[2][0] += a2 * wv.x; acc[2][1] += a2 * wv.y; acc[2][2] += a2 * wv.z; acc[2][3] += a2 * wv.w;
                acc[3][0] += a3 * wv.x; acc[3][1] += a3 * wv.y; acc[3][2] += a3 * wv.z; acc[3][3] += a3 * wv.w;
            }
#pragma unroll
            for (int i = 0; i < 4; i++) {
                int tl = 4 * tt + i;
                if (tl >= nth) break;
                if (og < 8) {
                    *(float4*)&s_xi[tl][oc] =
                        make_float4(acc[i][0], acc[i][1], acc[i][2], acc[i][3]);
                } else if (tl >= 3) {
                    *(float4*)&Zb[((size_t)n * TLEN + t0 + tl - 3) * 32 + (oc - 32)] =
                        make_float4(acc[i][0], acc[i][1], acc[i][2], acc[i][3]);
                }
            }
        }
    }
    __syncthreads();  // s_v dead; pool becomes s_xc

    // ---- conv4 + silu: thread = (cc, token-group), weights in registers
    {
        int cc = tid & 31, jg = tid >> 5;
        float c0 = s_cw[cc * 4 + 0], c1 = s_cw[cc * 4 + 1];
        float c2 = s_cw[cc * 4 + 2], c3 = s_cw[cc * 4 + 3];
        float cb = s_cb[cc];
        for (int j = jg; j < ntk; j += 8) {
            float acc = 0.f;
            acc += c0 * s_xi[j + 0][cc];
            acc += c1 * s_xi[j + 1][cc];
            acc += c2 * s_xi[j + 2][cc];
            acc += c3 * s_xi[j + 3][cc];
            s_xc[j][cc] = siluf(acc + cb);
        }
    }
    __syncthreads();

    // ---- x-proj B/C rows, 4-token x 4-q register tile
    {
        int qt = tid & 7, tt = tid >> 3;
        if (4 * tt < ntk) {
            float acc[4][4] = {{0.f}};
#pragma unroll
            for (int cc = 0; cc < 32; cc++) {
                float4 wv = *(const float4*)&s_xpT[cc][4 * qt];
                float a0 = s_xc[4 * tt + 0][cc];
                float a1 = s_xc[4 * tt + 1][cc];
                float a2 = s_xc[4 * tt + 2][cc];
                float a3 = s_xc[4 * tt + 3][cc];
                acc[0][0] += a0 * wv.x; acc[0][1] += a0 * wv.y; acc[0][2] += a0 * wv.z; acc[0][3] += a0 * wv.w;
                acc[1][0] += a1 * wv.x; acc[1][1] += a1 * wv.y; acc[1][2] += a1 * wv.z; acc[1][3] += a1 * wv.w;
                acc[2][0] += a2 * wv.x; acc[2][1] += a2 * wv.y; acc[2][2] += a2 * wv.z; acc[2][3] += a2 * wv.w;
                acc[3][0] += a3 * wv.x; acc[3][1] += a3 * wv.y; acc[3][2] += a3 * wv.z; acc[3][3] += a3 * wv.w;
            }
#pragma unroll
            for (int i = 0; i < 4; i++) {
                int j = 4 * tt + i;
                if (j < ntk)
                    *(float4*)&sc[((size_t)n * TLEN + t0 + j) * 96 + 64 + 4 * qt] =
                        make_float4(acc[i][0], acc[i][1], acc[i][2], acc[i][3]);
            }
        }
        // dt0 per token (reads only s_xc / s_xp0)
        if (tid < ntk) {
            float acc = 0.f;
#pragma unroll
            for (int cc = 0; cc < 32; cc++) acc += s_xc[tid][cc] * s_xp0[cc];
            s_dt0[tid] = acc;
        }
    }
    __syncthreads();

    // ---- dt block + xc block emits (coalesced stores)
    {
        float* scb = sc + ((size_t)n * TLEN + t0) * 96;
        for (int it = tid; it < ntk * 32; it += 256) {
            int j = it >> 5, d = it & 31;
            scb[j * 96 + 32 + d] = softplusf(s_dt0[j] * s_dw[d] + s_db[d]);
        }
        for (int it = tid; it < ntk * 32; it += 256) {
            int j = it >> 5, cc = it & 31;
            scb[j * 96 + cc] = s_xc[j][cc];
        }
    }
}

// -------- phase 2a: per-chunk scan summaries; thread = (d, s-group of 4) ----
__global__ __launch_bounds__(128) void k_scan1(const float* __restrict__ sc,
                                               const float* __restrict__ A_log,
                                               float* __restrict__ Psum,
                                               float* __restrict__ Fsum)
{
    int n = blockIdx.x >> 4;
    int c = blockIdx.x & (NCH - 1);
    int t0 = c * CHUNK;
    int nt = min(CHUNK, TLEN - t0);
    __shared__ __align__(16) float s_sc[CHUNK * 96];
    const float* src = sc + ((size_t)n * TLEN + t0) * 96;
    int nv4 = nt * 24;
    for (int i = threadIdx.x; i < nv4; i += 128)
        ((float4*)s_sc)[i] = ((const float4*)src)[i];
    int tid = threadIdx.x, d = tid >> 2, sg = tid & 3;
    float4 Av = *(const float4*)&A_log[d * 16 + sg * 4];
    float A0 = -__expf(Av.x), A1 = -__expf(Av.y), A2 = -__expf(Av.z), A3 = -__expf(Av.w);
    __syncthreads();
    float h0 = 0.f, h1 = 0.f, h2 = 0.f, h3 = 0.f;
    float P0 = 1.f, P1 = 1.f, P2 = 1.f, P3 = 1.f;
    for (int t = 0; t < nt; t++) {
        const float* p = s_sc + t * 96;
        float dt = p[32 + d], xc = p[d];
        float4 Bv = *(const float4*)&p[64 + sg * 4];
        float a0 = __expf(dt * A0); h0 = a0 * h0 + dt * Bv.x * xc; P0 *= a0;
        float a1 = __expf(dt * A1); h1 = a1 * h1 + dt * Bv.y * xc; P1 *= a1;
        float a2 = __expf(dt * A2); h2 = a2 * h2 + dt * Bv.z * xc; P2 *= a2;
        float a3 = __expf(dt * A3); h3 = a3 * h3 + dt * Bv.w * xc; P3 *= a3;
    }
    size_t base = ((size_t)n * NCH + c) * 512 + d * 16 + sg * 4;
    *(float4*)&Psum[base] = make_float4(P0, P1, P2, P3);
    *(float4*)&Fsum[base] = make_float4(h0, h1, h2, h3);
}

// -- phase 2b+2c fused: combine prologue + per-chunk scan pass 2 -------------
__global__ __launch_bounds__(128) void k_scan2(const float* __restrict__ sc,
                                               const float* __restrict__ A_log,
                                               const float* __restrict__ Dp,
                                               const float* __restrict__ Psum,
                                               const float* __restrict__ Fsum,
                                               float* __restrict__ yc)  // (NSEQ,TLEN,32)
{
    int n = blockIdx.x >> 4;
    int c = blockIdx.x & (NCH - 1);
    int t0 = c * CHUNK;
    int nt = min(CHUNK, TLEN - t0);
    __shared__ __align__(16) float s_sc[CHUNK * 96];
    __shared__ __align__(16) float s_y[CHUNK * 32];
    const float* src = sc + ((size_t)n * TLEN + t0) * 96;
    int nv4 = nt * 24;
    for (int i = threadIdx.x; i < nv4; i += 128)
        ((float4*)s_sc)[i] = ((const float4*)src)[i];
    int tid = threadIdx.x, d = tid >> 2, sg = tid & 3;
    float4 Av = *(const float4*)&A_log[d * 16 + sg * 4];
    float A0 = -__expf(Av.x), A1 = -__expf(Av.y), A2 = -__expf(Av.z), A3 = -__expf(Av.w);
    float Dd = Dp[d];
    // combine prologue: fold chunks 0..c-1 (same FP order as former k_comb)
    float h0 = 0.f, h1 = 0.f, h2 = 0.f, h3 = 0.f;
    for (int cc = 0; cc < c; cc++) {
        size_t bb = ((size_t)n * NCH + cc) * 512 + d * 16 + sg * 4;
        float4 Pv = *(const float4*)&Psum[bb];
        float4 Fv = *(const float4*)&Fsum[bb];
        h0 = Fv.x + Pv.x * h0;
        h1 = Fv.y + Pv.y * h1;
        h2 = Fv.z + Pv.z * h2;
        h3 = Fv.w + Pv.w * h3;
    }
    __syncthreads();
    for (int t = 0; t < nt; t++) {
        const float* p = s_sc + t * 96;
        float dt = p[32 + d], xc = p[d];
        float4 Bv = *(const float4*)&p[64 + sg * 4];
        float4 Cv = *(const float4*)&p[80 + sg * 4];
        float a0 = __expf(dt * A0); h0 = a0 * h0 + dt * Bv.x * xc;
        float a1 = __expf(dt * A1); h1 = a1 * h1 + dt * Bv.y * xc;
        float a2 = __expf(dt * A2); h2 = a2 * h2 + dt * Bv.z * xc;
        float a3 = __expf(dt * A3); h3 = a3 * h3 + dt * Bv.w * xc;
        float pp = h0 * Cv.x + h1 * Cv.y + h2 * Cv.z + h3 * Cv.w;
        pp += __shfl_xor(pp, 1);
        pp += __shfl_xor(pp, 2);
        if (sg == 0) s_y[t * 32 + d] = pp + Dd * xc;
    }
    __syncthreads();
    float* yb = yc + ((size_t)n * TLEN + t0) * 32;
    int ny4 = nt * 8;
    for (int i = threadIdx.x; i < ny4; i += 128)
        ((float4*)yb)[i] = ((const float4*)s_y)[i];
}

// ---------------- phase 3: gate + out-proj + scatter ------------------------
template <int MODE>
__global__ void k_p3(const float* __restrict__ yc, const float* __restrict__ Zb,
                     const float* __restrict__ out_w,  // (16,32)
                     float* __restrict__ out)
{
    __shared__ float s_w[16 * 32];
    for (int i = threadIdx.x; i < 512; i += blockDim.x) s_w[i] = out_w[i];
    __syncthreads();
    int tid = blockIdx.x * blockDim.x + threadIdx.x;
    if (tid >= NSEQ * LSEQ) return;
    int n = tid >> 10, l = tid & 1023, t = l + 1;
    const float* y = yc + ((size_t)n * TLEN + t) * 32;
    const float* z = Zb + ((size_t)n * TLEN + t) * 32;
    float yv[32];
#pragma unroll
    for (int c = 0; c < 32; c++) yv[c] = y[c] * siluf(z[c]);
    float o[16];
#pragma unroll
    for (int j = 0; j < 16; j++) {
        float acc = 0.f;
#pragma unroll
        for (int c = 0; c < 32; c++) acc += yv[c] * s_w[j * 32 + c];
        o[j] = acc * (1.0f / 3.0f);
    }
    int b = n >> 6, cube = n & 63;
    if (MODE == 0) {
        int i2 = l >> 5, j2 = l & 31;
        int io = i2 >> 1, jo = j2 >> 1;
        int coff = ((i2 & 1) << 1) | (j2 & 1);
#pragma unroll
        for (int j = 0; j < 16; j++) out[oidx(b, cube, j * 4 + coff, io, jo)] = o[j];
    } else if (MODE == 1) {
        int c = l >> 4, jj = l & 15;
#pragma unroll
        for (int j = 0; j < 16; j++) out[oidx(b, cube, c, j, jj)] += o[j];
    } else {
        int c = l >> 4, ii = l & 15;
#pragma unroll
        for (int j = 0; j < 16; j++) out[oidx(b, cube, c, ii, j)] += o[j];
    }
}

}  // namespace

extern "C" void kernel_launch(void* const* d_in, const int* in_sizes, int n_in,
                              void* d_out, int out_size, void* d_ws, size_t ws_size,
                              hipStream_t stream) {
    const float* x   = (const float*)d_in[0];
    const float* gt1 = (const float*)d_in[1];
    const float* gt2 = (const float*)d_in[2];
    const float* ln1g = (const float*)d_in[3];
    const float* ln1b = (const float*)d_in[4];
    const float* ln2g = (const float*)d_in[5];
    const float* ln2b = (const float*)d_in[6];
    const float* m[2][9];
    for (int mi = 0; mi < 2; mi++)
        for (int k = 0; k < 9; k++) m[mi][k] = (const float*)d_in[7 + mi * 9 + k];
    float* out = (float*)d_out;

    float* ws = (float*)d_ws;
    float* ZB = ws;                               // 128*1025*32 (16.8 MB)
    float* SC = ZB + (size_t)NSEQ * TLEN * 32;    // 128*1025*96 (50.4 MB)
    float* YC = SC + (size_t)NSEQ * TLEN * 96;    // 16.8 MB
    float* PS = YC + (size_t)NSEQ * TLEN * 32;    // 4.2 MB
    float* FS = PS + (size_t)NSEQ * NCH * 512;    // 4.2 MB

    dim3 gtile(NSEQ * NT);
    dim3 gscan(NSEQ * NCH);
    dim3 grd3((NSEQ * LSEQ + 255) / 256);

    for (int mode = 0; mode < 3; mode++) {
        int pi = (mode == 0) ? 0 : 1;
        const float* gt = (mode == 0) ? gt1 : gt2;
        const float* lg = (mode == 0) ? ln1g : ln2g;
        const float* lb = (mode == 0) ? ln1b : ln2b;
        const float* const* P = m[pi];
        // P: 0 in_w, 1 conv_w, 2 conv_b, 3 xproj_w, 4 dt_w, 5 dt_b, 6 A_log, 7 D, 8 out_w
        if (mode == 0)
            k_p1<0><<<gtile, dim3(256), 0, stream>>>(x, gt, lg, lb, P[0], P[1], P[2], P[3], P[4], P[5], ZB, SC);
        else if (mode == 1)
            k_p1<1><<<gtile, dim3(256), 0, stream>>>(x, gt, lg, lb, P[0], P[1], P[2], P[3], P[4], P[5], ZB, SC);
        else
            k_p1<2><<<gtile, dim3(256), 0, stream>>>(x, gt, lg, lb, P[0], P[1], P[2], P[3], P[4], P[5], ZB, SC);
        k_scan1<<<gscan, dim3(128), 0, stream>>>(SC, P[6], PS, FS);
        k_scan2<<<gscan, dim3(128), 0, stream>>>(SC, P[6], P[7], PS, FS, YC);
        if (mode == 0)      k_p3<0><<<grd3, dim3(256), 0, stream>>>(YC, ZB, P[8], out);
        else if (mode == 1) k_p3<1><<<grd3, dim3(256), 0, stream>>>(YC, ZB, P[8], out);
        else                k_p3<2><<<grd3, dim3(256), 0, stream>>>(YC, ZB, P[8], out);
    }
}

// Round 15
// 437.141 us; speedup vs baseline: 1.0387x; 1.0266x over previous
//
#include <hip/hip_runtime.h>
#include <cmath>

namespace {

constexpr int XC = 64, XH = 128, XW = 128;
constexpr int NSEQ = 128;   // B(2) * 64 cubes
constexpr int TLEN = 1025;  // gt token + 1024
constexpr int LSEQ = 1024;
constexpr int NCH = 16;     // chunks per sequence (parallel scan)
constexpr int CHUNK = 65;   // 16*65 = 1040 >= 1025
constexpr int TT = 96;      // token tile for fused p1
constexpr int NT = 11;      // ceil(1025/96)

struct MP {
    const float *in_w, *conv_w, *conv_b, *xproj_w, *dt_w, *dt_b, *A_log, *D, *out_w;
};

__device__ __forceinline__ int xidx(int b, int c, int h, int w) {
    return ((b * XC + c) * XH + h) * XW + w;
}
__device__ __forceinline__ int oidx(int b, int cube, int c, int i, int j) {
    int h = cube * 2 + (i >> 3);
    int w = ((i & 7) << 4) | j;
    return xidx(b, c, h, w);
}
__device__ __forceinline__ float siluf(float v) { return v / (1.0f + __expf(-v)); }
__device__ __forceinline__ float softplusf(float v) {
    return v > 20.0f ? v : log1pf(__expf(v));
}

template <int MODE>
__device__ __forceinline__ float gather_val(const float* __restrict__ x,
                                            const float* __restrict__ s_gt,
                                            int t, int k, int b, int bi, int bj) {
    if (t == 0) return s_gt[k];
    int l = t - 1;
    if (MODE == 0) {
        int i2 = l >> 5, j2 = l & 31;
        int h = bi * 16 + (i2 >> 1), w = bj * 16 + (j2 >> 1);
        int coff = ((i2 & 1) << 1) | (j2 & 1);
        return x[xidx(b, k * 4 + coff, h, w)];
    } else if (MODE == 1) {
        int c = l >> 4, j = l & 15;
        return x[xidx(b, c, bi * 16 + k, bj * 16 + j)];
    } else {
        int c = l >> 4, i = l & 15;
        return x[xidx(b, c, bi * 16 + i, bj * 16 + k)];
    }
}
__device__ __forceinline__ float gather_rt(int mode, const float* __restrict__ x,
                                           const float* __restrict__ s_gt,
                                           int t, int k, int b, int bi, int bj) {
    if (mode == 0) return gather_val<0>(x, s_gt, t, k, b, bi, bj);
    if (mode == 1) return gather_val<1>(x, s_gt, t, k, b, bi, bj);
    return gather_val<2>(x, s_gt, t, k, b, bi, bj);
}

// ==== phase 1 (batched over modes via blockIdx.y): r12 body =================
__global__ __launch_bounds__(256) void kb_p1(
    const float* __restrict__ x,
    const float* __restrict__ gt1, const float* __restrict__ gt2,
    const float* __restrict__ ln1g, const float* __restrict__ ln1b,
    const float* __restrict__ ln2g, const float* __restrict__ ln2b,
    MP P0, MP P1, int mode_base,
    float* __restrict__ ZB, float* __restrict__ SC,
    size_t zstride, size_t scstride)
{
    const int mode = mode_base + (int)blockIdx.y;
    const MP P = (mode == 0) ? P0 : P1;
    const float* gt  = (mode == 0) ? gt1 : gt2;
    const float* lng = (mode == 0) ? ln1g : ln2g;
    const float* lnb = (mode == 0) ? ln1b : ln2b;
    float* Zb = ZB + (size_t)blockIdx.y * zstride;
    float* sc = SC + (size_t)blockIdx.y * scstride;

    const int n = blockIdx.x / NT, tile = blockIdx.x % NT;
    const int t0 = tile * TT;
    const int ntk = min(TT, TLEN - t0);
    const int nth = ntk + 3;  // with 3-token front halo
    const int b = n >> 6, cube = n & 63, bi = cube >> 3, bj = cube & 7;
    const int tid = threadIdx.x;

    // s_v [TT+3][17] overlaid on s_xc [TT][37]: disjoint lifetimes
    __shared__ __align__(16) float s_pool[TT * 37];
    float (*s_v)[17]  = (float(*)[17])s_pool;
    float (*s_xc)[37] = (float(*)[37])s_pool;
    __shared__ __align__(16) float s_xi[TT + 3][36];
    __shared__ __align__(16) float s_wT[16][64];   // s_wT[k][oc] = in_w[oc][k]
    __shared__ __align__(16) float s_xpT[32][36];  // s_xpT[cc][q] = xproj_w[q+1][cc]
    __shared__ float s_xp0[32];
    __shared__ float s_cw[128], s_cb[32], s_dw[32], s_db[32];
    __shared__ float s_g[16], s_bb[16], s_gt[16];
    __shared__ float s_dt0[TT];

    for (int i = tid; i < 64 * 16; i += 256) s_wT[i & 15][i >> 4] = P.in_w[i];
    for (int i = tid; i < 33 * 32; i += 256) {
        int r = i >> 5, cc = i & 31;
        float v = P.xproj_w[i];
        if (r == 0) s_xp0[cc] = v;
        else s_xpT[cc][r - 1] = v;
    }
    if (tid < 128) s_cw[tid] = P.conv_w[tid];
    if (tid < 32) { s_cb[tid] = P.conv_b[tid]; s_dw[tid] = P.dt_w[tid]; s_db[tid] = P.dt_b[tid]; }
    if (tid < 16) { s_g[tid] = lng[tid]; s_bb[tid] = lnb[tid]; s_gt[tid] = gt[tid]; }
    __syncthreads();

    // ---- gather + LN, token-per-thread, registers only
    if (tid < nth) {
        int t = t0 - 3 + tid;
        float v[16];
        if (t < 0) {
#pragma unroll
            for (int k = 0; k < 16; k++) v[k] = 0.f;
        } else {
#pragma unroll
            for (int k = 0; k < 16; k++) v[k] = gather_rt(mode, x, s_gt, t, k, b, bi, bj);
            float mu = 0.f;
#pragma unroll
            for (int k = 0; k < 16; k++) mu += v[k];
            mu *= (1.f / 16.f);
            float var = 0.f;
#pragma unroll
            for (int k = 0; k < 16; k++) { float d = v[k] - mu; var += d * d; }
            float inv = rsqrtf(var * (1.f / 16.f) + 1e-5f);
#pragma unroll
            for (int k = 0; k < 16; k++) v[k] = (v[k] - mu) * inv * s_g[k] + s_bb[k];
        }
#pragma unroll
        for (int k = 0; k < 16; k++) s_v[tid][k] = v[k];
    }
    __syncthreads();

    // ---- in-proj, 4-token x 4-oc register tiles (og<8 -> xi LDS, og>=8 -> z)
    {
        const int ntt = (nth + 3) >> 2;
        for (int tl0 = tid; tl0 < ntt * 16; tl0 += 256) {
            int tt = tl0 >> 4, og = tl0 & 15;
            int oc = og * 4;
            float acc[4][4] = {{0.f}};
#pragma unroll
            for (int k = 0; k < 16; k++) {
                float4 wv = *(const float4*)&s_wT[k][oc];
                float a0 = s_v[4 * tt + 0][k];
                float a1 = s_v[4 * tt + 1][k];
                float a2 = s_v[4 * tt + 2][k];
                float a3 = s_v[4 * tt + 3][k];
                acc[0][0] += a0 * wv.x; acc[0][1] += a0 * wv.y; acc[0][2] += a0 * wv.z; acc[0][3] += a0 * wv.w;
                acc[1][0] += a1 * wv.x; acc[1][1] += a1 * wv.y; acc[1][2] += a1 * wv.z; acc[1][3] += a1 * wv.w;
                acc[2][0] += a2 * wv.x; acc[2][1] += a2 * wv.y; acc[2][2] += a2 * wv.z; acc[2][3] += a2 * wv.w;
                acc[3][0] += a3 * wv.x; acc[3][1] += a3 * wv.y; acc[3][2] += a3 * wv.z; acc[3][3] += a3 * wv.w;
            }
#pragma unroll
            for (int i = 0; i < 4; i++) {
                int tl = 4 * tt + i;
                if (tl >= nth) break;
                if (og < 8) {
                    *(float4*)&s_xi[tl][oc] =
                        make_float4(acc[i][0], acc[i][1], acc[i][2], acc[i][3]);
                } else if (tl >= 3) {
                    *(float4*)&Zb[((size_t)n * TLEN + t0 + tl - 3) * 32 + (oc - 32)] =
                        make_float4(acc[i][0], acc[i][1], acc[i][2], acc[i][3]);
                }
            }
        }
    }
    __syncthreads();  // s_v dead; pool becomes s_xc

    // ---- conv4 + silu: thread = (cc, token-group), weights in registers
    {
        int cc = tid & 31, jg = tid >> 5;
        float c0 = s_cw[cc * 4 + 0], c1 = s_cw[cc * 4 + 1];
        float c2 = s_cw[cc * 4 + 2], c3 = s_cw[cc * 4 + 3];
        float cb = s_cb[cc];
        for (int j = jg; j < ntk; j += 8) {
            float acc = 0.f;
            acc += c0 * s_xi[j + 0][cc];
            acc += c1 * s_xi[j + 1][cc];
            acc += c2 * s_xi[j + 2][cc];
            acc += c3 * s_xi[j + 3][cc];
            s_xc[j][cc] = siluf(acc + cb);
        }
    }
    __syncthreads();

    // ---- x-proj B/C rows, 4-token x 4-q register tile
    {
        int qt = tid & 7, tt = tid >> 3;
        if (4 * tt < ntk) {
            float acc[4][4] = {{0.f}};
#pragma unroll
            for (int cc = 0; cc < 32; cc++) {
                float4 wv = *(const float4*)&s_xpT[cc][4 * qt];
                float a0 = s_xc[4 * tt + 0][cc];
                float a1 = s_xc[4 * tt + 1][cc];
                float a2 = s_xc[4 * tt + 2][cc];
                float a3 = s_xc[4 * tt + 3][cc];
                acc[0][0] += a0 * wv.x; acc[0][1] += a0 * wv.y; acc[0][2] += a0 * wv.z; acc[0][3] += a0 * wv.w;
                acc[1][0] += a1 * wv.x; acc[1][1] += a1 * wv.y; acc[1][2] += a1 * wv.z; acc[1][3] += a1 * wv.w;
                acc[2][0] += a2 * wv.x; acc[2][1] += a2 * wv.y; acc[2][2] += a2 * wv.z; acc[2][3] += a2 * wv.w;
                acc[3][0] += a3 * wv.x; acc[3][1] += a3 * wv.y; acc[3][2] += a3 * wv.z; acc[3][3] += a3 * wv.w;
            }
#pragma unroll
            for (int i = 0; i < 4; i++) {
                int j = 4 * tt + i;
                if (j < ntk)
                    *(float4*)&sc[((size_t)n * TLEN + t0 + j) * 96 + 64 + 4 * qt] =
                        make_float4(acc[i][0], acc[i][1], acc[i][2], acc[i][3]);
            }
        }
        // dt0 per token (reads only s_xc / s_xp0)
        if (tid < ntk) {
            float acc = 0.f;
#pragma unroll
            for (int cc = 0; cc < 32; cc++) acc += s_xc[tid][cc] * s_xp0[cc];
            s_dt0[tid] = acc;
        }
    }
    __syncthreads();

    // ---- dt block + xc block emits (coalesced stores)
    {
        float* scb = sc + ((size_t)n * TLEN + t0) * 96;
        for (int it = tid; it < ntk * 32; it += 256) {
            int j = it >> 5, d = it & 31;
            scb[j * 96 + 32 + d] = softplusf(s_dt0[j] * s_dw[d] + s_db[d]);
        }
        for (int it = tid; it < ntk * 32; it += 256) {
            int j = it >> 5, cc = it & 31;
            scb[j * 96 + cc] = s_xc[j][cc];
        }
    }
}

// -------- phase 2a (batched): per-chunk scan summaries ----------------------
__global__ __launch_bounds__(128) void kb_scan1(
    const float* __restrict__ SC, MP P0, MP P1, int mode_base,
    float* __restrict__ PS, float* __restrict__ FS,
    size_t scstride, size_t pstride)
{
    const int mode = mode_base + (int)blockIdx.y;
    const float* A_log = (mode == 0) ? P0.A_log : P1.A_log;
    const float* sc = SC + (size_t)blockIdx.y * scstride;
    float* Psum = PS + (size_t)blockIdx.y * pstride;
    float* Fsum = FS + (size_t)blockIdx.y * pstride;

    int n = blockIdx.x >> 4;
    int c = blockIdx.x & (NCH - 1);
    int t0 = c * CHUNK;
    int nt = min(CHUNK, TLEN - t0);
    __shared__ __align__(16) float s_sc[CHUNK * 96];
    const float* src = sc + ((size_t)n * TLEN + t0) * 96;
    int nv4 = nt * 24;
    for (int i = threadIdx.x; i < nv4; i += 128)
        ((float4*)s_sc)[i] = ((const float4*)src)[i];
    int tid = threadIdx.x, d = tid >> 2, sg = tid & 3;
    float4 Av = *(const float4*)&A_log[d * 16 + sg * 4];
    float A0 = -__expf(Av.x), A1 = -__expf(Av.y), A2 = -__expf(Av.z), A3 = -__expf(Av.w);
    __syncthreads();
    float h0 = 0.f, h1 = 0.f, h2 = 0.f, h3 = 0.f;
    float P0v = 1.f, P1v = 1.f, P2v = 1.f, P3v = 1.f;
    for (int t = 0; t < nt; t++) {
        const float* p = s_sc + t * 96;
        float dt = p[32 + d], xc = p[d];
        float4 Bv = *(const float4*)&p[64 + sg * 4];
        float a0 = __expf(dt * A0); h0 = a0 * h0 + dt * Bv.x * xc; P0v *= a0;
        float a1 = __expf(dt * A1); h1 = a1 * h1 + dt * Bv.y * xc; P1v *= a1;
        float a2 = __expf(dt * A2); h2 = a2 * h2 + dt * Bv.z * xc; P2v *= a2;
        float a3 = __expf(dt * A3); h3 = a3 * h3 + dt * Bv.w * xc; P3v *= a3;
    }
    size_t base = ((size_t)n * NCH + c) * 512 + d * 16 + sg * 4;
    *(float4*)&Psum[base] = make_float4(P0v, P1v, P2v, P3v);
    *(float4*)&Fsum[base] = make_float4(h0, h1, h2, h3);
}

// -------- phase 2b (batched): combine chunk summaries -----------------------
__global__ __launch_bounds__(512) void kb_comb(
    const float* __restrict__ PS, const float* __restrict__ FS,
    float* __restrict__ HI, size_t pstride)
{
    const float* Psum = PS + (size_t)blockIdx.y * pstride;
    const float* Fsum = FS + (size_t)blockIdx.y * pstride;
    float* Hin = HI + (size_t)blockIdx.y * pstride;
    int n = blockIdx.x, tid = threadIdx.x;
    const float* pb = Psum + (size_t)n * NCH * 512;
    const float* fb = Fsum + (size_t)n * NCH * 512;
    float* hb = Hin + (size_t)n * NCH * 512;
    float H = 0.f;
#pragma unroll
    for (int c = 0; c < NCH; c++) {
        float P = pb[(size_t)c * 512 + tid];
        float F = fb[(size_t)c * 512 + tid];
        hb[(size_t)c * 512 + tid] = H;
        H = F + P * H;
    }
}

// -------- phase 2c (batched): per-chunk scan pass 2, emit y -----------------
__global__ __launch_bounds__(128) void kb_scan2(
    const float* __restrict__ SC, MP P0, MP P1, int mode_base,
    const float* __restrict__ HI, float* __restrict__ YC,
    size_t scstride, size_t pstride, size_t ystride)
{
    const int mode = mode_base + (int)blockIdx.y;
    const float* A_log = (mode == 0) ? P0.A_log : P1.A_log;
    const float* Dp = (mode == 0) ? P0.D : P1.D;
    const float* sc = SC + (size_t)blockIdx.y * scstride;
    const float* Hin = HI + (size_t)blockIdx.y * pstride;
    float* yc = YC + (size_t)blockIdx.y * ystride;

    int n = blockIdx.x >> 4;
    int c = blockIdx.x & (NCH - 1);
    int t0 = c * CHUNK;
    int nt = min(CHUNK, TLEN - t0);
    __shared__ __align__(16) float s_sc[CHUNK * 96];
    __shared__ __align__(16) float s_y[CHUNK * 32];
    const float* src = sc + ((size_t)n * TLEN + t0) * 96;
    int nv4 = nt * 24;
    for (int i = threadIdx.x; i < nv4; i += 128)
        ((float4*)s_sc)[i] = ((const float4*)src)[i];
    int tid = threadIdx.x, d = tid >> 2, sg = tid & 3;
    float4 Av = *(const float4*)&A_log[d * 16 + sg * 4];
    float A0 = -__expf(Av.x), A1 = -__expf(Av.y), A2 = -__expf(Av.z), A3 = -__expf(Av.w);
    float Dd = Dp[d];
    float4 Hv = *(const float4*)&Hin[((size_t)n * NCH + c) * 512 + d * 16 + sg * 4];
    float h0 = Hv.x, h1 = Hv.y, h2 = Hv.z, h3 = Hv.w;
    __syncthreads();
    for (int t = 0; t < nt; t++) {
        const float* p = s_sc + t * 96;
        float dt = p[32 + d], xc = p[d];
        float4 Bv = *(const float4*)&p[64 + sg * 4];
        float4 Cv = *(const float4*)&p[80 + sg * 4];
        float a0 = __expf(dt * A0); h0 = a0 * h0 + dt * Bv.x * xc;
        float a1 = __expf(dt * A1); h1 = a1 * h1 + dt * Bv.y * xc;
        float a2 = __expf(dt * A2); h2 = a2 * h2 + dt * Bv.z * xc;
        float a3 = __expf(dt * A3); h3 = a3 * h3 + dt * Bv.w * xc;
        float pp = h0 * Cv.x + h1 * Cv.y + h2 * Cv.z + h3 * Cv.w;
        pp += __shfl_xor(pp, 1);
        pp += __shfl_xor(pp, 2);
        if (sg == 0) s_y[t * 32 + d] = pp + Dd * xc;
    }
    __syncthreads();
    float* yb = yc + ((size_t)n * TLEN + t0) * 32;
    int ny4 = nt * 8;
    for (int i = threadIdx.x; i < ny4; i += 128)
        ((float4*)yb)[i] = ((const float4*)s_y)[i];
}

// ---------------- phase 3: gate + out-proj + scatter (per-mode) -------------
template <int MODE>
__global__ void k_p3(const float* __restrict__ yc, const float* __restrict__ Zb,
                     const float* __restrict__ out_w,  // (16,32)
                     float* __restrict__ out)
{
    __shared__ float s_w[16 * 32];
    for (int i = threadIdx.x; i < 512; i += blockDim.x) s_w[i] = out_w[i];
    __syncthreads();
    int tid = blockIdx.x * blockDim.x + threadIdx.x;
    if (tid >= NSEQ * LSEQ) return;
    int n = tid >> 10, l = tid & 1023, t = l + 1;
    const float* y = yc + ((size_t)n * TLEN + t) * 32;
    const float* z = Zb + ((size_t)n * TLEN + t) * 32;
    float yv[32];
#pragma unroll
    for (int c = 0; c < 32; c++) yv[c] = y[c] * siluf(z[c]);
    float o[16];
#pragma unroll
    for (int j = 0; j < 16; j++) {
        float acc = 0.f;
#pragma unroll
        for (int c = 0; c < 32; c++) acc += yv[c] * s_w[j * 32 + c];
        o[j] = acc * (1.0f / 3.0f);
    }
    int b = n >> 6, cube = n & 63;
    if (MODE == 0) {
        int i2 = l >> 5, j2 = l & 31;
        int io = i2 >> 1, jo = j2 >> 1;
        int coff = ((i2 & 1) << 1) | (j2 & 1);
#pragma unroll
        for (int j = 0; j < 16; j++) out[oidx(b, cube, j * 4 + coff, io, jo)] = o[j];
    } else if (MODE == 1) {
        int c = l >> 4, jj = l & 15;
#pragma unroll
        for (int j = 0; j < 16; j++) out[oidx(b, cube, c, j, jj)] += o[j];
    } else {
        int c = l >> 4, ii = l & 15;
#pragma unroll
        for (int j = 0; j < 16; j++) out[oidx(b, cube, c, ii, j)] += o[j];
    }
}

}  // namespace

extern "C" void kernel_launch(void* const* d_in, const int* in_sizes, int n_in,
                              void* d_out, int out_size, void* d_ws, size_t ws_size,
                              hipStream_t stream) {
    const float* x   = (const float*)d_in[0];
    const float* gt1 = (const float*)d_in[1];
    const float* gt2 = (const float*)d_in[2];
    const float* ln1g = (const float*)d_in[3];
    const float* ln1b = (const float*)d_in[4];
    const float* ln2g = (const float*)d_in[5];
    const float* ln2b = (const float*)d_in[6];
    MP P[2];
    for (int mi = 0; mi < 2; mi++) {
        P[mi].in_w   = (const float*)d_in[7 + mi * 9 + 0];
        P[mi].conv_w = (const float*)d_in[7 + mi * 9 + 1];
        P[mi].conv_b = (const float*)d_in[7 + mi * 9 + 2];
        P[mi].xproj_w= (const float*)d_in[7 + mi * 9 + 3];
        P[mi].dt_w   = (const float*)d_in[7 + mi * 9 + 4];
        P[mi].dt_b   = (const float*)d_in[7 + mi * 9 + 5];
        P[mi].A_log  = (const float*)d_in[7 + mi * 9 + 6];
        P[mi].D      = (const float*)d_in[7 + mi * 9 + 7];
        P[mi].out_w  = (const float*)d_in[7 + mi * 9 + 8];
    }
    float* out = (float*)d_out;

    const size_t ZBs = (size_t)NSEQ * TLEN * 32;   // 4.2M floats
    const size_t SCs = (size_t)NSEQ * TLEN * 96;   // 12.6M
    const size_t YCs = (size_t)NSEQ * TLEN * 32;   // 4.2M
    const size_t PSs = (size_t)NSEQ * NCH * 512;   // 1.05M
    const size_t permode = ZBs + SCs + YCs + 3 * PSs;
    const bool fused = ws_size >= (size_t)3 * permode * sizeof(float);
    const int nm = fused ? 3 : 1;

    float* ws = (float*)d_ws;
    float* ZB = ws;
    float* SC = ZB + (size_t)nm * ZBs;
    float* YC = SC + (size_t)nm * SCs;
    float* PS = YC + (size_t)nm * YCs;
    float* FS = PS + (size_t)nm * PSs;
    float* HI = FS + (size_t)nm * PSs;

    dim3 b256(256), b128(128), b512(512);
    dim3 grd3((NSEQ * LSEQ + 255) / 256);

    if (fused) {
        kb_p1<<<dim3(NSEQ * NT, 3), b256, 0, stream>>>(
            x, gt1, gt2, ln1g, ln1b, ln2g, ln2b, P[0], P[1], 0, ZB, SC, ZBs, SCs);
        kb_scan1<<<dim3(NSEQ * NCH, 3), b128, 0, stream>>>(
            SC, P[0], P[1], 0, PS, FS, SCs, PSs);
        kb_comb<<<dim3(NSEQ, 3), b512, 0, stream>>>(PS, FS, HI, PSs);
        kb_scan2<<<dim3(NSEQ * NCH, 3), b128, 0, stream>>>(
            SC, P[0], P[1], 0, HI, YC, SCs, PSs, YCs);
        // p3 per-mode, sequential, non-atomic (= then += then +=)
        k_p3<0><<<grd3, b256, 0, stream>>>(YC + 0 * YCs, ZB + 0 * ZBs, P[0].out_w, out);
        k_p3<1><<<grd3, b256, 0, stream>>>(YC + 1 * YCs, ZB + 1 * ZBs, P[1].out_w, out);
        k_p3<2><<<grd3, b256, 0, stream>>>(YC + 2 * YCs, ZB + 2 * ZBs, P[1].out_w, out);
    } else {
        for (int mode = 0; mode < 3; mode++) {
            int pi = (mode == 0) ? 0 : 1;
            kb_p1<<<dim3(NSEQ * NT, 1), b256, 0, stream>>>(
                x, gt1, gt2, ln1g, ln1b, ln2g, ln2b, P[0], P[1], mode, ZB, SC, ZBs, SCs);
            kb_scan1<<<dim3(NSEQ * NCH, 1), b128, 0, stream>>>(
                SC, P[0], P[1], mode, PS, FS, SCs, PSs);
            kb_comb<<<dim3(NSEQ, 1), b512, 0, stream>>>(PS, FS, HI, PSs);
            kb_scan2<<<dim3(NSEQ * NCH, 1), b128, 0, stream>>>(
                SC, P[0], P[1], mode, HI, YC, SCs, PSs, YCs);
            if (mode == 0)      k_p3<0><<<grd3, b256, 0, stream>>>(YC, ZB, P[pi].out_w, out);
            else if (mode == 1) k_p3<1><<<grd3, b256, 0, stream>>>(YC, ZB, P[pi].out_w, out);
            else                k_p3<2><<<grd3, b256, 0, stream>>>(YC, ZB, P[pi].out_w, out);
        }
    }
}

// Round 16
// 388.715 us; speedup vs baseline: 1.1681x; 1.1246x over previous
//
#include <hip/hip_runtime.h>
#include <cmath>

namespace {

constexpr int XC = 64, XH = 128, XW = 128;
constexpr int NSEQ = 128;   // B(2) * 64 cubes
constexpr int TLEN = 1025;  // gt token + 1024
constexpr int LSEQ = 1024;
constexpr int NCH = 16;     // chunks per sequence (parallel scan)
constexpr int CHUNK = 65;   // 16*65 = 1040 >= 1025
constexpr int TT = 96;      // token tile for fused p1
constexpr int NT = 11;      // ceil(1025/96)

struct MP {
    const float *in_w, *conv_w, *conv_b, *xproj_w, *dt_w, *dt_b, *A_log, *D, *out_w;
};

__device__ __forceinline__ int xidx(int b, int c, int h, int w) {
    return ((b * XC + c) * XH + h) * XW + w;
}
__device__ __forceinline__ int oidx(int b, int cube, int c, int i, int j) {
    int h = cube * 2 + (i >> 3);
    int w = ((i & 7) << 4) | j;
    return xidx(b, c, h, w);
}
__device__ __forceinline__ float siluf(float v) { return v / (1.0f + __expf(-v)); }
__device__ __forceinline__ float softplusf(float v) {
    return v > 20.0f ? v : log1pf(__expf(v));
}

template <int MODE>
__device__ __forceinline__ float gather_val(const float* __restrict__ x,
                                            const float* __restrict__ s_gt,
                                            int t, int k, int b, int bi, int bj) {
    if (t == 0) return s_gt[k];
    int l = t - 1;
    if (MODE == 0) {
        int i2 = l >> 5, j2 = l & 31;
        int h = bi * 16 + (i2 >> 1), w = bj * 16 + (j2 >> 1);
        int coff = ((i2 & 1) << 1) | (j2 & 1);
        return x[xidx(b, k * 4 + coff, h, w)];
    } else if (MODE == 1) {
        int c = l >> 4, j = l & 15;
        return x[xidx(b, c, bi * 16 + k, bj * 16 + j)];
    } else {
        int c = l >> 4, i = l & 15;
        return x[xidx(b, c, bi * 16 + i, bj * 16 + k)];
    }
}
__device__ __forceinline__ float gather_rt(int mode, const float* __restrict__ x,
                                           const float* __restrict__ s_gt,
                                           int t, int k, int b, int bi, int bj) {
    if (mode == 0) return gather_val<0>(x, s_gt, t, k, b, bi, bj);
    if (mode == 1) return gather_val<1>(x, s_gt, t, k, b, bi, bj);
    return gather_val<2>(x, s_gt, t, k, b, bi, bj);
}

// ==== phase 1: gather+LN+in-proj+conv+x-proj (MODE_C=-1 -> blockIdx.y mode) =
template <int MODE_C>
__global__ __launch_bounds__(256) void k_p1(
    const float* __restrict__ x,
    const float* __restrict__ gt1, const float* __restrict__ gt2,
    const float* __restrict__ ln1g, const float* __restrict__ ln1b,
    const float* __restrict__ ln2g, const float* __restrict__ ln2b,
    MP P0, MP P1, int mode_base,
    float* __restrict__ ZB0, float* __restrict__ SC0, size_t arena)
{
    const int mode = (MODE_C >= 0) ? MODE_C : (mode_base + (int)blockIdx.y);
    const MP P = (mode == 0) ? P0 : P1;
    const float* gt  = (mode == 0) ? gt1 : gt2;
    const float* lng = (mode == 0) ? ln1g : ln2g;
    const float* lnb = (mode == 0) ? ln1b : ln2b;
    float* Zb = ZB0 + (size_t)blockIdx.y * arena;
    float* sc = SC0 + (size_t)blockIdx.y * arena;

    const int n = blockIdx.x / NT, tile = blockIdx.x % NT;
    const int t0 = tile * TT;
    const int ntk = min(TT, TLEN - t0);
    const int nth = ntk + 3;  // with 3-token front halo
    const int b = n >> 6, cube = n & 63, bi = cube >> 3, bj = cube & 7;
    const int tid = threadIdx.x;

    // s_v [TT+3][17] overlaid on s_xc [TT][37]: disjoint lifetimes
    __shared__ __align__(16) float s_pool[TT * 37];
    float (*s_v)[17]  = (float(*)[17])s_pool;
    float (*s_xc)[37] = (float(*)[37])s_pool;
    __shared__ __align__(16) float s_xi[TT + 3][36];
    __shared__ __align__(16) float s_wT[16][64];   // s_wT[k][oc] = in_w[oc][k]
    __shared__ __align__(16) float s_xpT[32][36];  // s_xpT[cc][q] = xproj_w[q+1][cc]
    __shared__ float s_xp0[32];
    __shared__ float s_cw[128], s_cb[32], s_dw[32], s_db[32];
    __shared__ float s_g[16], s_bb[16], s_gt[16];
    __shared__ float s_dt0[TT];

    for (int i = tid; i < 64 * 16; i += 256) s_wT[i & 15][i >> 4] = P.in_w[i];
    for (int i = tid; i < 33 * 32; i += 256) {
        int r = i >> 5, cc = i & 31;
        float v = P.xproj_w[i];
        if (r == 0) s_xp0[cc] = v;
        else s_xpT[cc][r - 1] = v;
    }
    if (tid < 128) s_cw[tid] = P.conv_w[tid];
    if (tid < 32) { s_cb[tid] = P.conv_b[tid]; s_dw[tid] = P.dt_w[tid]; s_db[tid] = P.dt_b[tid]; }
    if (tid < 16) { s_g[tid] = lng[tid]; s_bb[tid] = lnb[tid]; s_gt[tid] = gt[tid]; }
    __syncthreads();

    // ---- gather + LN, token-per-thread, registers only
    if (tid < nth) {
        int t = t0 - 3 + tid;
        float v[16];
        if (t < 0) {
#pragma unroll
            for (int k = 0; k < 16; k++) v[k] = 0.f;
        } else {
#pragma unroll
            for (int k = 0; k < 16; k++) {
                if (MODE_C >= 0) v[k] = gather_val<(MODE_C >= 0 ? MODE_C : 0)>(x, s_gt, t, k, b, bi, bj);
                else             v[k] = gather_rt(mode, x, s_gt, t, k, b, bi, bj);
            }
            float mu = 0.f;
#pragma unroll
            for (int k = 0; k < 16; k++) mu += v[k];
            mu *= (1.f / 16.f);
            float var = 0.f;
#pragma unroll
            for (int k = 0; k < 16; k++) { float d = v[k] - mu; var += d * d; }
            float inv = rsqrtf(var * (1.f / 16.f) + 1e-5f);
#pragma unroll
            for (int k = 0; k < 16; k++) v[k] = (v[k] - mu) * inv * s_g[k] + s_bb[k];
        }
#pragma unroll
        for (int k = 0; k < 16; k++) s_v[tid][k] = v[k];
    }
    __syncthreads();

    // ---- in-proj, 4-token x 4-oc register tiles (og<8 -> xi LDS, og>=8 -> z)
    {
        const int ntt = (nth + 3) >> 2;
        for (int tl0 = tid; tl0 < ntt * 16; tl0 += 256) {
            int tt = tl0 >> 4, og = tl0 & 15;
            int oc = og * 4;
            float acc[4][4] = {{0.f}};
#pragma unroll
            for (int k = 0; k < 16; k++) {
                float4 wv = *(const float4*)&s_wT[k][oc];
                float a0 = s_v[4 * tt + 0][k];
                float a1 = s_v[4 * tt + 1][k];
                float a2 = s_v[4 * tt + 2][k];
                float a3 = s_v[4 * tt + 3][k];
                acc[0][0] += a0 * wv.x; acc[0][1] += a0 * wv.y; acc[0][2] += a0 * wv.z; acc[0][3] += a0 * wv.w;
                acc[1][0] += a1 * wv.x; acc[1][1] += a1 * wv.y; acc[1][2] += a1 * wv.z; acc[1][3] += a1 * wv.w;
                acc[2][0] += a2 * wv.x; acc[2][1] += a2 * wv.y; acc[2][2] += a2 * wv.z; acc[2][3] += a2 * wv.w;
                acc[3][0] += a3 * wv.x; acc[3][1] += a3 * wv.y; acc[3][2] += a3 * wv.z; acc[3][3] += a3 * wv.w;
            }
#pragma unroll
            for (int i = 0; i < 4; i++) {
                int tl = 4 * tt + i;
                if (tl >= nth) break;
                if (og < 8) {
                    *(float4*)&s_xi[tl][oc] =
                        make_float4(acc[i][0], acc[i][1], acc[i][2], acc[i][3]);
                } else if (tl >= 3) {
                    *(float4*)&Zb[((size_t)n * TLEN + t0 + tl - 3) * 32 + (oc - 32)] =
                        make_float4(acc[i][0], acc[i][1], acc[i][2], acc[i][3]);
                }
            }
        }
    }
    __syncthreads();  // s_v dead; pool becomes s_xc

    // ---- conv4 + silu: thread = (cc, token-group), weights in registers
    {
        int cc = tid & 31, jg = tid >> 5;
        float c0 = s_cw[cc * 4 + 0], c1 = s_cw[cc * 4 + 1];
        float c2 = s_cw[cc * 4 + 2], c3 = s_cw[cc * 4 + 3];
        float cb = s_cb[cc];
        for (int j = jg; j < ntk; j += 8) {
            float acc = 0.f;
            acc += c0 * s_xi[j + 0][cc];
            acc += c1 * s_xi[j + 1][cc];
            acc += c2 * s_xi[j + 2][cc];
            acc += c3 * s_xi[j + 3][cc];
            s_xc[j][cc] = siluf(acc + cb);
        }
    }
    __syncthreads();

    // ---- x-proj B/C rows, 4-token x 4-q register tile
    {
        int qt = tid & 7, tt = tid >> 3;
        if (4 * tt < ntk) {
            float acc[4][4] = {{0.f}};
#pragma unroll
            for (int cc = 0; cc < 32; cc++) {
                float4 wv = *(const float4*)&s_xpT[cc][4 * qt];
                float a0 = s_xc[4 * tt + 0][cc];
                float a1 = s_xc[4 * tt + 1][cc];
                float a2 = s_xc[4 * tt + 2][cc];
                float a3 = s_xc[4 * tt + 3][cc];
                acc[0][0] += a0 * wv.x; acc[0][1] += a0 * wv.y; acc[0][2] += a0 * wv.z; acc[0][3] += a0 * wv.w;
                acc[1][0] += a1 * wv.x; acc[1][1] += a1 * wv.y; acc[1][2] += a1 * wv.z; acc[1][3] += a1 * wv.w;
                acc[2][0] += a2 * wv.x; acc[2][1] += a2 * wv.y; acc[2][2] += a2 * wv.z; acc[2][3] += a2 * wv.w;
                acc[3][0] += a3 * wv.x; acc[3][1] += a3 * wv.y; acc[3][2] += a3 * wv.z; acc[3][3] += a3 * wv.w;
            }
#pragma unroll
            for (int i = 0; i < 4; i++) {
                int j = 4 * tt + i;
                if (j < ntk)
                    *(float4*)&sc[((size_t)n * TLEN + t0 + j) * 96 + 64 + 4 * qt] =
                        make_float4(acc[i][0], acc[i][1], acc[i][2], acc[i][3]);
            }
        }
        // dt0 per token (reads only s_xc / s_xp0)
        if (tid < ntk) {
            float acc = 0.f;
#pragma unroll
            for (int cc = 0; cc < 32; cc++) acc += s_xc[tid][cc] * s_xp0[cc];
            s_dt0[tid] = acc;
        }
    }
    __syncthreads();

    // ---- dt block + xc block emits (coalesced stores)
    {
        float* scb = sc + ((size_t)n * TLEN + t0) * 96;
        for (int it = tid; it < ntk * 32; it += 256) {
            int j = it >> 5, d = it & 31;
            scb[j * 96 + 32 + d] = softplusf(s_dt0[j] * s_dw[d] + s_db[d]);
        }
        for (int it = tid; it < ntk * 32; it += 256) {
            int j = it >> 5, cc = it & 31;
            scb[j * 96 + cc] = s_xc[j][cc];
        }
    }
}

// -------- phase 2a: per-chunk scan summaries; thread = (d, s-group of 4) ----
template <int MODE_C>
__global__ __launch_bounds__(128) void k_scan1(
    const float* __restrict__ SC0, MP P0, MP P1, int mode_base,
    float* __restrict__ PS0, float* __restrict__ FS0, size_t arena)
{
    const int mode = (MODE_C >= 0) ? MODE_C : (mode_base + (int)blockIdx.y);
    const float* A_log = (mode == 0) ? P0.A_log : P1.A_log;
    const float* sc = SC0 + (size_t)blockIdx.y * arena;
    float* Psum = PS0 + (size_t)blockIdx.y * arena;
    float* Fsum = FS0 + (size_t)blockIdx.y * arena;

    int n = blockIdx.x >> 4;
    int c = blockIdx.x & (NCH - 1);
    int t0 = c * CHUNK;
    int nt = min(CHUNK, TLEN - t0);
    __shared__ __align__(16) float s_sc[CHUNK * 96];
    const float* src = sc + ((size_t)n * TLEN + t0) * 96;
    int nv4 = nt * 24;
    for (int i = threadIdx.x; i < nv4; i += 128)
        ((float4*)s_sc)[i] = ((const float4*)src)[i];
    int tid = threadIdx.x, d = tid >> 2, sg = tid & 3;
    float4 Av = *(const float4*)&A_log[d * 16 + sg * 4];
    float A0 = -__expf(Av.x), A1 = -__expf(Av.y), A2 = -__expf(Av.z), A3 = -__expf(Av.w);
    __syncthreads();
    float h0 = 0.f, h1 = 0.f, h2 = 0.f, h3 = 0.f;
    float P0v = 1.f, P1v = 1.f, P2v = 1.f, P3v = 1.f;
    for (int t = 0; t < nt; t++) {
        const float* p = s_sc + t * 96;
        float dt = p[32 + d], xc = p[d];
        float4 Bv = *(const float4*)&p[64 + sg * 4];
        float a0 = __expf(dt * A0); h0 = a0 * h0 + dt * Bv.x * xc; P0v *= a0;
        float a1 = __expf(dt * A1); h1 = a1 * h1 + dt * Bv.y * xc; P1v *= a1;
        float a2 = __expf(dt * A2); h2 = a2 * h2 + dt * Bv.z * xc; P2v *= a2;
        float a3 = __expf(dt * A3); h3 = a3 * h3 + dt * Bv.w * xc; P3v *= a3;
    }
    size_t base = ((size_t)n * NCH + c) * 512 + d * 16 + sg * 4;
    *(float4*)&Psum[base] = make_float4(P0v, P1v, P2v, P3v);
    *(float4*)&Fsum[base] = make_float4(h0, h1, h2, h3);
}

// -------- phase 2b: combine chunk summaries -> incoming state per chunk -----
__global__ __launch_bounds__(512) void k_comb(
    const float* __restrict__ PS0, const float* __restrict__ FS0,
    float* __restrict__ HI0, size_t arena)
{
    const float* Psum = PS0 + (size_t)blockIdx.y * arena;
    const float* Fsum = FS0 + (size_t)blockIdx.y * arena;
    float* Hin = HI0 + (size_t)blockIdx.y * arena;
    int n = blockIdx.x, tid = threadIdx.x;
    const float* pb = Psum + (size_t)n * NCH * 512;
    const float* fb = Fsum + (size_t)n * NCH * 512;
    float* hb = Hin + (size_t)n * NCH * 512;
    float H = 0.f;
#pragma unroll
    for (int c = 0; c < NCH; c++) {
        float P = pb[(size_t)c * 512 + tid];
        float F = fb[(size_t)c * 512 + tid];
        hb[(size_t)c * 512 + tid] = H;
        H = F + P * H;
    }
}

// -------- phase 2c: per-chunk scan pass 2, thread = (d, s-group of 4) -------
template <int MODE_C>
__global__ __launch_bounds__(128) void k_scan2(
    const float* __restrict__ SC0, MP P0, MP P1, int mode_base,
    const float* __restrict__ HI0, float* __restrict__ YC0, size_t arena)
{
    const int mode = (MODE_C >= 0) ? MODE_C : (mode_base + (int)blockIdx.y);
    const float* A_log = (mode == 0) ? P0.A_log : P1.A_log;
    const float* Dp = (mode == 0) ? P0.D : P1.D;
    const float* sc = SC0 + (size_t)blockIdx.y * arena;
    const float* Hin = HI0 + (size_t)blockIdx.y * arena;
    float* yc = YC0 + (size_t)blockIdx.y * arena;

    int n = blockIdx.x >> 4;
    int c = blockIdx.x & (NCH - 1);
    int t0 = c * CHUNK;
    int nt = min(CHUNK, TLEN - t0);
    __shared__ __align__(16) float s_sc[CHUNK * 96];
    __shared__ __align__(16) float s_y[CHUNK * 32];
    const float* src = sc + ((size_t)n * TLEN + t0) * 96;
    int nv4 = nt * 24;
    for (int i = threadIdx.x; i < nv4; i += 128)
        ((float4*)s_sc)[i] = ((const float4*)src)[i];
    int tid = threadIdx.x, d = tid >> 2, sg = tid & 3;
    float4 Av = *(const float4*)&A_log[d * 16 + sg * 4];
    float A0 = -__expf(Av.x), A1 = -__expf(Av.y), A2 = -__expf(Av.z), A3 = -__expf(Av.w);
    float Dd = Dp[d];
    float4 Hv = *(const float4*)&Hin[((size_t)n * NCH + c) * 512 + d * 16 + sg * 4];
    float h0 = Hv.x, h1 = Hv.y, h2 = Hv.z, h3 = Hv.w;
    __syncthreads();
    for (int t = 0; t < nt; t++) {
        const float* p = s_sc + t * 96;
        float dt = p[32 + d], xc = p[d];
        float4 Bv = *(const float4*)&p[64 + sg * 4];
        float4 Cv = *(const float4*)&p[80 + sg * 4];
        float a0 = __expf(dt * A0); h0 = a0 * h0 + dt * Bv.x * xc;
        float a1 = __expf(dt * A1); h1 = a1 * h1 + dt * Bv.y * xc;
        float a2 = __expf(dt * A2); h2 = a2 * h2 + dt * Bv.z * xc;
        float a3 = __expf(dt * A3); h3 = a3 * h3 + dt * Bv.w * xc;
        float pp = h0 * Cv.x + h1 * Cv.y + h2 * Cv.z + h3 * Cv.w;
        pp += __shfl_xor(pp, 1);
        pp += __shfl_xor(pp, 2);
        if (sg == 0) s_y[t * 32 + d] = pp + Dd * xc;
    }
    __syncthreads();
    float* yb = yc + ((size_t)n * TLEN + t0) * 32;
    int ny4 = nt * 8;
    for (int i = threadIdx.x; i < ny4; i += 128)
        ((float4*)yb)[i] = ((const float4*)s_y)[i];
}

// ---------------- phase 3: gate + out-proj + scatter (per-mode) -------------
template <int MODE>
__global__ void k_p3(const float* __restrict__ yc, const float* __restrict__ Zb,
                     const float* __restrict__ out_w,  // (16,32)
                     float* __restrict__ out)
{
    __shared__ float s_w[16 * 32];
    for (int i = threadIdx.x; i < 512; i += blockDim.x) s_w[i] = out_w[i];
    __syncthreads();
    int tid = blockIdx.x * blockDim.x + threadIdx.x;
    if (tid >= NSEQ * LSEQ) return;
    int n = tid >> 10, l = tid & 1023, t = l + 1;
    const float* y = yc + ((size_t)n * TLEN + t) * 32;
    const float* z = Zb + ((size_t)n * TLEN + t) * 32;
    float yv[32];
#pragma unroll
    for (int c = 0; c < 32; c++) yv[c] = y[c] * siluf(z[c]);
    float o[16];
#pragma unroll
    for (int j = 0; j < 16; j++) {
        float acc = 0.f;
#pragma unroll
        for (int c = 0; c < 32; c++) acc += yv[c] * s_w[j * 32 + c];
        o[j] = acc * (1.0f / 3.0f);
    }
    int b = n >> 6, cube = n & 63;
    if (MODE == 0) {
        int i2 = l >> 5, j2 = l & 31;
        int io = i2 >> 1, jo = j2 >> 1;
        int coff = ((i2 & 1) << 1) | (j2 & 1);
#pragma unroll
        for (int j = 0; j < 16; j++) out[oidx(b, cube, j * 4 + coff, io, jo)] = o[j];
    } else if (MODE == 1) {
        int c = l >> 4, jj = l & 15;
#pragma unroll
        for (int j = 0; j < 16; j++) out[oidx(b, cube, c, j, jj)] += o[j];
    } else {
        int c = l >> 4, ii = l & 15;
#pragma unroll
        for (int j = 0; j < 16; j++) out[oidx(b, cube, c, ii, j)] += o[j];
    }
}

}  // namespace

extern "C" void kernel_launch(void* const* d_in, const int* in_sizes, int n_in,
                              void* d_out, int out_size, void* d_ws, size_t ws_size,
                              hipStream_t stream) {
    const float* x   = (const float*)d_in[0];
    const float* gt1 = (const float*)d_in[1];
    const float* gt2 = (const float*)d_in[2];
    const float* ln1g = (const float*)d_in[3];
    const float* ln1b = (const float*)d_in[4];
    const float* ln2g = (const float*)d_in[5];
    const float* ln2b = (const float*)d_in[6];
    MP P[2];
    for (int mi = 0; mi < 2; mi++) {
        P[mi].in_w   = (const float*)d_in[7 + mi * 9 + 0];
        P[mi].conv_w = (const float*)d_in[7 + mi * 9 + 1];
        P[mi].conv_b = (const float*)d_in[7 + mi * 9 + 2];
        P[mi].xproj_w= (const float*)d_in[7 + mi * 9 + 3];
        P[mi].dt_w   = (const float*)d_in[7 + mi * 9 + 4];
        P[mi].dt_b   = (const float*)d_in[7 + mi * 9 + 5];
        P[mi].A_log  = (const float*)d_in[7 + mi * 9 + 6];
        P[mi].D      = (const float*)d_in[7 + mi * 9 + 7];
        P[mi].out_w  = (const float*)d_in[7 + mi * 9 + 8];
    }
    float* out = (float*)d_out;

    const size_t ZBs = (size_t)NSEQ * TLEN * 32;
    const size_t SCs = (size_t)NSEQ * TLEN * 96;
    const size_t YCs = (size_t)NSEQ * TLEN * 32;
    const size_t PSs = (size_t)NSEQ * NCH * 512;
    const size_t arena = ZBs + SCs + YCs + 3 * PSs;   // floats per mode-slot

    float* A0 = (float*)d_ws;
    auto ZB = [&](int y) { return A0 + (size_t)y * arena; };
    auto SC = [&](int y) { return A0 + (size_t)y * arena + ZBs; };
    auto YC = [&](int y) { return A0 + (size_t)y * arena + ZBs + SCs; };
    auto PS = [&](int y) { return A0 + (size_t)y * arena + ZBs + SCs + YCs; };
    auto FS = [&](int y) { return PS(y) + PSs; };
    auto HI = [&](int y) { return FS(y) + PSs; };

    const bool fits3 = ws_size >= 3 * arena * sizeof(float);
    const bool fits2 = ws_size >= 2 * arena * sizeof(float);

    dim3 b256(256), b128(128), b512(512);
    dim3 grd3((NSEQ * LSEQ + 255) / 256);

    if (fits3) {
        k_p1<-1><<<dim3(NSEQ * NT, 3), b256, 0, stream>>>(
            x, gt1, gt2, ln1g, ln1b, ln2g, ln2b, P[0], P[1], 0, ZB(0), SC(0), arena);
        k_scan1<-1><<<dim3(NSEQ * NCH, 3), b128, 0, stream>>>(
            SC(0), P[0], P[1], 0, PS(0), FS(0), arena);
        k_comb<<<dim3(NSEQ, 3), b512, 0, stream>>>(PS(0), FS(0), HI(0), arena);
        k_scan2<-1><<<dim3(NSEQ * NCH, 3), b128, 0, stream>>>(
            SC(0), P[0], P[1], 0, HI(0), YC(0), arena);
        k_p3<0><<<grd3, b256, 0, stream>>>(YC(0), ZB(0), P[0].out_w, out);
        k_p3<1><<<grd3, b256, 0, stream>>>(YC(1), ZB(1), P[1].out_w, out);
        k_p3<2><<<grd3, b256, 0, stream>>>(YC(2), ZB(2), P[1].out_w, out);
    } else if (fits2) {
        // mode 0 serial (templated, r12-exact) into arena 0
        k_p1<0><<<dim3(NSEQ * NT, 1), b256, 0, stream>>>(
            x, gt1, gt2, ln1g, ln1b, ln2g, ln2b, P[0], P[1], 0, ZB(0), SC(0), arena);
        k_scan1<0><<<dim3(NSEQ * NCH, 1), b128, 0, stream>>>(
            SC(0), P[0], P[1], 0, PS(0), FS(0), arena);
        k_comb<<<dim3(NSEQ, 1), b512, 0, stream>>>(PS(0), FS(0), HI(0), arena);
        k_scan2<0><<<dim3(NSEQ * NCH, 1), b128, 0, stream>>>(
            SC(0), P[0], P[1], 0, HI(0), YC(0), arena);
        k_p3<0><<<grd3, b256, 0, stream>>>(YC(0), ZB(0), P[0].out_w, out);
        // modes 1,2 batched into arenas 0,1 (stream order protects arena-0 reuse)
        k_p1<-1><<<dim3(NSEQ * NT, 2), b256, 0, stream>>>(
            x, gt1, gt2, ln1g, ln1b, ln2g, ln2b, P[0], P[1], 1, ZB(0), SC(0), arena);
        k_scan1<-1><<<dim3(NSEQ * NCH, 2), b128, 0, stream>>>(
            SC(0), P[0], P[1], 1, PS(0), FS(0), arena);
        k_comb<<<dim3(NSEQ, 2), b512, 0, stream>>>(PS(0), FS(0), HI(0), arena);
        k_scan2<-1><<<dim3(NSEQ * NCH, 2), b128, 0, stream>>>(
            SC(0), P[0], P[1], 1, HI(0), YC(0), arena);
        k_p3<1><<<grd3, b256, 0, stream>>>(YC(0), ZB(0), P[1].out_w, out);
        k_p3<2><<<grd3, b256, 0, stream>>>(YC(1), ZB(1), P[1].out_w, out);
    } else {
        // r12-exact serial, arena 0 only
        for (int mode = 0; mode < 3; mode++) {
            if (mode == 0)
                k_p1<0><<<dim3(NSEQ * NT, 1), b256, 0, stream>>>(
                    x, gt1, gt2, ln1g, ln1b, ln2g, ln2b, P[0], P[1], 0, ZB(0), SC(0), arena);
            else if (mode == 1)
                k_p1<1><<<dim3(NSEQ * NT, 1), b256, 0, stream>>>(
                    x, gt1, gt2, ln1g, ln1b, ln2g, ln2b, P[0], P[1], 0, ZB(0), SC(0), arena);
            else
                k_p1<2><<<dim3(NSEQ * NT, 1), b256, 0, stream>>>(
                    x, gt1, gt2, ln1g, ln1b, ln2g, ln2b, P[0], P[1], 0, ZB(0), SC(0), arena);
            if (mode == 0)
                k_scan1<0><<<dim3(NSEQ * NCH, 1), b128, 0, stream>>>(SC(0), P[0], P[1], 0, PS(0), FS(0), arena);
            else if (mode == 1)
                k_scan1<1><<<dim3(NSEQ * NCH, 1), b128, 0, stream>>>(SC(0), P[0], P[1], 0, PS(0), FS(0), arena);
            else
                k_scan1<2><<<dim3(NSEQ * NCH, 1), b128, 0, stream>>>(SC(0), P[0], P[1], 0, PS(0), FS(0), arena);
            k_comb<<<dim3(NSEQ, 1), b512, 0, stream>>>(PS(0), FS(0), HI(0), arena);
            if (mode == 0)
                k_scan2<0><<<dim3(NSEQ * NCH, 1), b128, 0, stream>>>(SC(0), P[0], P[1], 0, HI(0), YC(0), arena);
            else if (mode == 1)
                k_scan2<1><<<dim3(NSEQ * NCH, 1), b128, 0, stream>>>(SC(0), P[0], P[1], 0, HI(0), YC(0), arena);
            else
                k_scan2<2><<<dim3(NSEQ * NCH, 1), b128, 0, stream>>>(SC(0), P[0], P[1], 0, HI(0), YC(0), arena);
            if (mode == 0)      k_p3<0><<<grd3, b256, 0, stream>>>(YC(0), ZB(0), P[0].out_w, out);
            else if (mode == 1) k_p3<1><<<grd3, b256, 0, stream>>>(YC(0), ZB(0), P[1].out_w, out);
            else                k_p3<2><<<grd3, b256, 0, stream>>>(YC(0), ZB(0), P[1].out_w, out);
        }
    }
}

// Round 17
// 356.743 us; speedup vs baseline: 1.2727x; 1.0896x over previous
//
#include <hip/hip_runtime.h>
#include <cmath>

namespace {

constexpr int XC = 64, XH = 128, XW = 128;
constexpr int NSEQ = 128;   // B(2) * 64 cubes
constexpr int TLEN = 1025;  // gt token + 1024
constexpr int LSEQ = 1024;
constexpr int NCH = 16;     // chunks per sequence (parallel scan)
constexpr int CHUNK = 65;   // 16*65 = 1040 >= 1025
constexpr int TT = 96;      // token tile for fused p1
constexpr int NT = 11;      // ceil(1025/96)

struct MP {
    const float *in_w, *conv_w, *conv_b, *xproj_w, *dt_w, *dt_b, *A_log, *D, *out_w;
};

__device__ __forceinline__ int xidx(int b, int c, int h, int w) {
    return ((b * XC + c) * XH + h) * XW + w;
}
__device__ __forceinline__ int oidx(int b, int cube, int c, int i, int j) {
    int h = cube * 2 + (i >> 3);
    int w = ((i & 7) << 4) | j;
    return xidx(b, c, h, w);
}
__device__ __forceinline__ float siluf(float v) { return v / (1.0f + __expf(-v)); }
__device__ __forceinline__ float softplusf(float v) {
    return v > 20.0f ? v : log1pf(__expf(v));
}

template <int MODE>
__device__ __forceinline__ float gather_val(const float* __restrict__ x,
                                            const float* __restrict__ s_gt,
                                            int t, int k, int b, int bi, int bj) {
    if (t == 0) return s_gt[k];
    int l = t - 1;
    if (MODE == 0) {
        int i2 = l >> 5, j2 = l & 31;
        int h = bi * 16 + (i2 >> 1), w = bj * 16 + (j2 >> 1);
        int coff = ((i2 & 1) << 1) | (j2 & 1);
        return x[xidx(b, k * 4 + coff, h, w)];
    } else if (MODE == 1) {
        int c = l >> 4, j = l & 15;
        return x[xidx(b, c, bi * 16 + k, bj * 16 + j)];
    } else {
        int c = l >> 4, i = l & 15;
        return x[xidx(b, c, bi * 16 + i, bj * 16 + k)];
    }
}
__device__ __forceinline__ float gather_rt(int mode, const float* __restrict__ x,
                                           const float* __restrict__ s_gt,
                                           int t, int k, int b, int bi, int bj) {
    if (mode == 0) return gather_val<0>(x, s_gt, t, k, b, bi, bj);
    if (mode == 1) return gather_val<1>(x, s_gt, t, k, b, bi, bj);
    return gather_val<2>(x, s_gt, t, k, b, bi, bj);
}

// ==== phase 1: gather+LN+in-proj+conv+x-proj (MODE_C=-1 -> blockIdx.y mode) =
template <int MODE_C>
__global__ __launch_bounds__(256) void k_p1(
    const float* __restrict__ x,
    const float* __restrict__ gt1, const float* __restrict__ gt2,
    const float* __restrict__ ln1g, const float* __restrict__ ln1b,
    const float* __restrict__ ln2g, const float* __restrict__ ln2b,
    MP P0, MP P1, int mode_base,
    float* __restrict__ ZB0, float* __restrict__ SC0, size_t arena)
{
    const int mode = (MODE_C >= 0) ? MODE_C : (mode_base + (int)blockIdx.y);
    const MP P = (mode == 0) ? P0 : P1;
    const float* gt  = (mode == 0) ? gt1 : gt2;
    const float* lng = (mode == 0) ? ln1g : ln2g;
    const float* lnb = (mode == 0) ? ln1b : ln2b;
    float* Zb = ZB0 + (size_t)blockIdx.y * arena;
    float* sc = SC0 + (size_t)blockIdx.y * arena;

    const int n = blockIdx.x / NT, tile = blockIdx.x % NT;
    const int t0 = tile * TT;
    const int ntk = min(TT, TLEN - t0);
    const int nth = ntk + 3;  // with 3-token front halo
    const int b = n >> 6, cube = n & 63, bi = cube >> 3, bj = cube & 7;
    const int tid = threadIdx.x;

    // s_v [TT+3][17] overlaid on s_xc [TT][37]: disjoint lifetimes
    __shared__ __align__(16) float s_pool[TT * 37];
    float (*s_v)[17]  = (float(*)[17])s_pool;
    float (*s_xc)[37] = (float(*)[37])s_pool;
    __shared__ __align__(16) float s_xi[TT + 3][36];
    __shared__ __align__(16) float s_wT[16][64];   // s_wT[k][oc] = in_w[oc][k]
    __shared__ __align__(16) float s_xpT[32][36];  // s_xpT[cc][q] = xproj_w[q+1][cc]
    __shared__ float s_xp0[32];
    __shared__ float s_cw[128], s_cb[32], s_dw[32], s_db[32];
    __shared__ float s_g[16], s_bb[16], s_gt[16];
    __shared__ float s_dt0[TT];

    for (int i = tid; i < 64 * 16; i += 256) s_wT[i & 15][i >> 4] = P.in_w[i];
    for (int i = tid; i < 33 * 32; i += 256) {
        int r = i >> 5, cc = i & 31;
        float v = P.xproj_w[i];
        if (r == 0) s_xp0[cc] = v;
        else s_xpT[cc][r - 1] = v;
    }
    if (tid < 128) s_cw[tid] = P.conv_w[tid];
    if (tid < 32) { s_cb[tid] = P.conv_b[tid]; s_dw[tid] = P.dt_w[tid]; s_db[tid] = P.dt_b[tid]; }
    if (tid < 16) { s_g[tid] = lng[tid]; s_bb[tid] = lnb[tid]; s_gt[tid] = gt[tid]; }
    __syncthreads();

    // ---- gather + LN, token-per-thread, registers only
    if (tid < nth) {
        int t = t0 - 3 + tid;
        float v[16];
        if (t < 0) {
#pragma unroll
            for (int k = 0; k < 16; k++) v[k] = 0.f;
        } else {
#pragma unroll
            for (int k = 0; k < 16; k++) {
                if (MODE_C >= 0) v[k] = gather_val<(MODE_C >= 0 ? MODE_C : 0)>(x, s_gt, t, k, b, bi, bj);
                else             v[k] = gather_rt(mode, x, s_gt, t, k, b, bi, bj);
            }
            float mu = 0.f;
#pragma unroll
            for (int k = 0; k < 16; k++) mu += v[k];
            mu *= (1.f / 16.f);
            float var = 0.f;
#pragma unroll
            for (int k = 0; k < 16; k++) { float d = v[k] - mu; var += d * d; }
            float inv = rsqrtf(var * (1.f / 16.f) + 1e-5f);
#pragma unroll
            for (int k = 0; k < 16; k++) v[k] = (v[k] - mu) * inv * s_g[k] + s_bb[k];
        }
#pragma unroll
        for (int k = 0; k < 16; k++) s_v[tid][k] = v[k];
    }
    __syncthreads();

    // ---- in-proj, 4-token x 4-oc register tiles (og<8 -> xi LDS, og>=8 -> z)
    {
        const int ntt = (nth + 3) >> 2;
        for (int tl0 = tid; tl0 < ntt * 16; tl0 += 256) {
            int tt = tl0 >> 4, og = tl0 & 15;
            int oc = og * 4;
            float acc[4][4] = {{0.f}};
#pragma unroll
            for (int k = 0; k < 16; k++) {
                float4 wv = *(const float4*)&s_wT[k][oc];
                float a0 = s_v[4 * tt + 0][k];
                float a1 = s_v[4 * tt + 1][k];
                float a2 = s_v[4 * tt + 2][k];
                float a3 = s_v[4 * tt + 3][k];
                acc[0][0] += a0 * wv.x; acc[0][1] += a0 * wv.y; acc[0][2] += a0 * wv.z; acc[0][3] += a0 * wv.w;
                acc[1][0] += a1 * wv.x; acc[1][1] += a1 * wv.y; acc[1][2] += a1 * wv.z; acc[1][3] += a1 * wv.w;
                acc[2][0] += a2 * wv.x; acc[2][1] += a2 * wv.y; acc[2][2] += a2 * wv.z; acc[2][3] += a2 * wv.w;
                acc[3][0] += a3 * wv.x; acc[3][1] += a3 * wv.y; acc[3][2] += a3 * wv.z; acc[3][3] += a3 * wv.w;
            }
#pragma unroll
            for (int i = 0; i < 4; i++) {
                int tl = 4 * tt + i;
                if (tl >= nth) break;
                if (og < 8) {
                    *(float4*)&s_xi[tl][oc] =
                        make_float4(acc[i][0], acc[i][1], acc[i][2], acc[i][3]);
                } else if (tl >= 3) {
                    *(float4*)&Zb[((size_t)n * TLEN + t0 + tl - 3) * 32 + (oc - 32)] =
                        make_float4(acc[i][0], acc[i][1], acc[i][2], acc[i][3]);
                }
            }
        }
    }
    __syncthreads();  // s_v dead; pool becomes s_xc

    // ---- conv4 + silu: thread = (cc, token-group), weights in registers
    {
        int cc = tid & 31, jg = tid >> 5;
        float c0 = s_cw[cc * 4 + 0], c1 = s_cw[cc * 4 + 1];
        float c2 = s_cw[cc * 4 + 2], c3 = s_cw[cc * 4 + 3];
        float cb = s_cb[cc];
        for (int j = jg; j < ntk; j += 8) {
            float acc = 0.f;
            acc += c0 * s_xi[j + 0][cc];
            acc += c1 * s_xi[j + 1][cc];
            acc += c2 * s_xi[j + 2][cc];
            acc += c3 * s_xi[j + 3][cc];
            s_xc[j][cc] = siluf(acc + cb);
        }
    }
    __syncthreads();

    // ---- x-proj B/C rows, 4-token x 4-q register tile
    {
        int qt = tid & 7, tt = tid >> 3;
        if (4 * tt < ntk) {
            float acc[4][4] = {{0.f}};
#pragma unroll
            for (int cc = 0; cc < 32; cc++) {
                float4 wv = *(const float4*)&s_xpT[cc][4 * qt];
                float a0 = s_xc[4 * tt + 0][cc];
                float a1 = s_xc[4 * tt + 1][cc];
                float a2 = s_xc[4 * tt + 2][cc];
                float a3 = s_xc[4 * tt + 3][cc];
                acc[0][0] += a0 * wv.x; acc[0][1] += a0 * wv.y; acc[0][2] += a0 * wv.z; acc[0][3] += a0 * wv.w;
                acc[1][0] += a1 * wv.x; acc[1][1] += a1 * wv.y; acc[1][2] += a1 * wv.z; acc[1][3] += a1 * wv.w;
                acc[2][0] += a2 * wv.x; acc[2][1] += a2 * wv.y; acc[2][2] += a2 * wv.z; acc[2][3] += a2 * wv.w;
                acc[3][0] += a3 * wv.x; acc[3][1] += a3 * wv.y; acc[3][2] += a3 * wv.z; acc[3][3] += a3 * wv.w;
            }
#pragma unroll
            for (int i = 0; i < 4; i++) {
                int j = 4 * tt + i;
                if (j < ntk)
                    *(float4*)&sc[((size_t)n * TLEN + t0 + j) * 96 + 64 + 4 * qt] =
                        make_float4(acc[i][0], acc[i][1], acc[i][2], acc[i][3]);
            }
        }
        // dt0 per token (reads only s_xc / s_xp0)
        if (tid < ntk) {
            float acc = 0.f;
#pragma unroll
            for (int cc = 0; cc < 32; cc++) acc += s_xc[tid][cc] * s_xp0[cc];
            s_dt0[tid] = acc;
        }
    }
    __syncthreads();

    // ---- dt block + xc block emits (coalesced stores)
    {
        float* scb = sc + ((size_t)n * TLEN + t0) * 96;
        for (int it = tid; it < ntk * 32; it += 256) {
            int j = it >> 5, d = it & 31;
            scb[j * 96 + 32 + d] = softplusf(s_dt0[j] * s_dw[d] + s_db[d]);
        }
        for (int it = tid; it < ntk * 32; it += 256) {
            int j = it >> 5, cc = it & 31;
            scb[j * 96 + cc] = s_xc[j][cc];
        }
    }
}

// -------- phase 2a: per-chunk scan summaries; thread = (d, s-group of 4) ----
template <int MODE_C>
__global__ __launch_bounds__(128) void k_scan1(
    const float* __restrict__ SC0, MP P0, MP P1, int mode_base,
    float* __restrict__ PS0, float* __restrict__ FS0, size_t arena)
{
    const int mode = (MODE_C >= 0) ? MODE_C : (mode_base + (int)blockIdx.y);
    const float* A_log = (mode == 0) ? P0.A_log : P1.A_log;
    const float* sc = SC0 + (size_t)blockIdx.y * arena;
    float* Psum = PS0 + (size_t)blockIdx.y * arena;
    float* Fsum = FS0 + (size_t)blockIdx.y * arena;

    int n = blockIdx.x >> 4;
    int c = blockIdx.x & (NCH - 1);
    int t0 = c * CHUNK;
    int nt = min(CHUNK, TLEN - t0);
    __shared__ __align__(16) float s_sc[CHUNK * 96];
    const float* src = sc + ((size_t)n * TLEN + t0) * 96;
    int nv4 = nt * 24;
    for (int i = threadIdx.x; i < nv4; i += 128)
        ((float4*)s_sc)[i] = ((const float4*)src)[i];
    int tid = threadIdx.x, d = tid >> 2, sg = tid & 3;
    float4 Av = *(const float4*)&A_log[d * 16 + sg * 4];
    float A0 = -__expf(Av.x), A1 = -__expf(Av.y), A2 = -__expf(Av.z), A3 = -__expf(Av.w);
    __syncthreads();
    float h0 = 0.f, h1 = 0.f, h2 = 0.f, h3 = 0.f;
    float P0v = 1.f, P1v = 1.f, P2v = 1.f, P3v = 1.f;
    for (int t = 0; t < nt; t++) {
        const float* p = s_sc + t * 96;
        float dt = p[32 + d], xc = p[d];
        float4 Bv = *(const float4*)&p[64 + sg * 4];
        float a0 = __expf(dt * A0); h0 = a0 * h0 + dt * Bv.x * xc; P0v *= a0;
        float a1 = __expf(dt * A1); h1 = a1 * h1 + dt * Bv.y * xc; P1v *= a1;
        float a2 = __expf(dt * A2); h2 = a2 * h2 + dt * Bv.z * xc; P2v *= a2;
        float a3 = __expf(dt * A3); h3 = a3 * h3 + dt * Bv.w * xc; P3v *= a3;
    }
    size_t base = ((size_t)n * NCH + c) * 512 + d * 16 + sg * 4;
    *(float4*)&Psum[base] = make_float4(P0v, P1v, P2v, P3v);
    *(float4*)&Fsum[base] = make_float4(h0, h1, h2, h3);
}

// -------- phase 2b: combine chunk summaries -> incoming state per chunk -----
__global__ __launch_bounds__(512) void k_comb(
    const float* __restrict__ PS0, const float* __restrict__ FS0,
    float* __restrict__ HI0, size_t arena)
{
    const float* Psum = PS0 + (size_t)blockIdx.y * arena;
    const float* Fsum = FS0 + (size_t)blockIdx.y * arena;
    float* Hin = HI0 + (size_t)blockIdx.y * arena;
    int n = blockIdx.x, tid = threadIdx.x;
    const float* pb = Psum + (size_t)n * NCH * 512;
    const float* fb = Fsum + (size_t)n * NCH * 512;
    float* hb = Hin + (size_t)n * NCH * 512;
    float H = 0.f;
#pragma unroll
    for (int c = 0; c < NCH; c++) {
        float P = pb[(size_t)c * 512 + tid];
        float F = fb[(size_t)c * 512 + tid];
        hb[(size_t)c * 512 + tid] = H;
        H = F + P * H;
    }
}

// --- phase 2c: scan pass 2; y written IN PLACE over SC's xc slot ------------
template <int MODE_C>
__global__ __launch_bounds__(128) void k_scan2(
    float* __restrict__ SC0, MP P0, MP P1, int mode_base,
    const float* __restrict__ HI0, size_t arena)
{
    const int mode = (MODE_C >= 0) ? MODE_C : (mode_base + (int)blockIdx.y);
    const float* A_log = (mode == 0) ? P0.A_log : P1.A_log;
    const float* Dp = (mode == 0) ? P0.D : P1.D;
    float* sc = SC0 + (size_t)blockIdx.y * arena;
    const float* Hin = HI0 + (size_t)blockIdx.y * arena;

    int n = blockIdx.x >> 4;
    int c = blockIdx.x & (NCH - 1);
    int t0 = c * CHUNK;
    int nt = min(CHUNK, TLEN - t0);
    __shared__ __align__(16) float s_sc[CHUNK * 96];
    __shared__ __align__(16) float s_y[CHUNK * 32];
    const float* src = sc + ((size_t)n * TLEN + t0) * 96;
    int nv4 = nt * 24;
    for (int i = threadIdx.x; i < nv4; i += 128)
        ((float4*)s_sc)[i] = ((const float4*)src)[i];
    int tid = threadIdx.x, d = tid >> 2, sg = tid & 3;
    float4 Av = *(const float4*)&A_log[d * 16 + sg * 4];
    float A0 = -__expf(Av.x), A1 = -__expf(Av.y), A2 = -__expf(Av.z), A3 = -__expf(Av.w);
    float Dd = Dp[d];
    float4 Hv = *(const float4*)&Hin[((size_t)n * NCH + c) * 512 + d * 16 + sg * 4];
    float h0 = Hv.x, h1 = Hv.y, h2 = Hv.z, h3 = Hv.w;
    __syncthreads();
    for (int t = 0; t < nt; t++) {
        const float* p = s_sc + t * 96;
        float dt = p[32 + d], xc = p[d];
        float4 Bv = *(const float4*)&p[64 + sg * 4];
        float4 Cv = *(const float4*)&p[80 + sg * 4];
        float a0 = __expf(dt * A0); h0 = a0 * h0 + dt * Bv.x * xc;
        float a1 = __expf(dt * A1); h1 = a1 * h1 + dt * Bv.y * xc;
        float a2 = __expf(dt * A2); h2 = a2 * h2 + dt * Bv.z * xc;
        float a3 = __expf(dt * A3); h3 = a3 * h3 + dt * Bv.w * xc;
        float pp = h0 * Cv.x + h1 * Cv.y + h2 * Cv.z + h3 * Cv.w;
        pp += __shfl_xor(pp, 1);
        pp += __shfl_xor(pp, 2);
        if (sg == 0) s_y[t * 32 + d] = pp + Dd * xc;
    }
    __syncthreads();
    // write y back over SC's xc slot (this block's rows only; reads done)
    float* yb = sc + ((size_t)n * TLEN + t0) * 96;
    for (int i = threadIdx.x; i < nt * 8; i += 128) {
        int j = i >> 3, q = i & 7;
        *(float4*)&yb[j * 96 + q * 4] = ((const float4*)s_y)[i];
    }
}

// ---------------- phase 3: gate + out-proj + scatter (per-mode) -------------
// y lives in SC rows (stride 96, offset 0)
template <int MODE>
__global__ void k_p3(const float* __restrict__ ysc, const float* __restrict__ Zb,
                     const float* __restrict__ out_w,  // (16,32)
                     float* __restrict__ out)
{
    __shared__ float s_w[16 * 32];
    for (int i = threadIdx.x; i < 512; i += blockDim.x) s_w[i] = out_w[i];
    __syncthreads();
    int tid = blockIdx.x * blockDim.x + threadIdx.x;
    if (tid >= NSEQ * LSEQ) return;
    int n = tid >> 10, l = tid & 1023, t = l + 1;
    const float* y = ysc + ((size_t)n * TLEN + t) * 96;
    const float* z = Zb + ((size_t)n * TLEN + t) * 32;
    float yv[32];
#pragma unroll
    for (int c = 0; c < 32; c++) yv[c] = y[c] * siluf(z[c]);
    float o[16];
#pragma unroll
    for (int j = 0; j < 16; j++) {
        float acc = 0.f;
#pragma unroll
        for (int c = 0; c < 32; c++) acc += yv[c] * s_w[j * 32 + c];
        o[j] = acc * (1.0f / 3.0f);
    }
    int b = n >> 6, cube = n & 63;
    if (MODE == 0) {
        int i2 = l >> 5, j2 = l & 31;
        int io = i2 >> 1, jo = j2 >> 1;
        int coff = ((i2 & 1) << 1) | (j2 & 1);
#pragma unroll
        for (int j = 0; j < 16; j++) out[oidx(b, cube, j * 4 + coff, io, jo)] = o[j];
    } else if (MODE == 1) {
        int c = l >> 4, jj = l & 15;
#pragma unroll
        for (int j = 0; j < 16; j++) out[oidx(b, cube, c, j, jj)] += o[j];
    } else {
        int c = l >> 4, ii = l & 15;
#pragma unroll
        for (int j = 0; j < 16; j++) out[oidx(b, cube, c, ii, j)] += o[j];
    }
}

}  // namespace

extern "C" void kernel_launch(void* const* d_in, const int* in_sizes, int n_in,
                              void* d_out, int out_size, void* d_ws, size_t ws_size,
                              hipStream_t stream) {
    const float* x   = (const float*)d_in[0];
    const float* gt1 = (const float*)d_in[1];
    const float* gt2 = (const float*)d_in[2];
    const float* ln1g = (const float*)d_in[3];
    const float* ln1b = (const float*)d_in[4];
    const float* ln2g = (const float*)d_in[5];
    const float* ln2b = (const float*)d_in[6];
    MP P[2];
    for (int mi = 0; mi < 2; mi++) {
        P[mi].in_w   = (const float*)d_in[7 + mi * 9 + 0];
        P[mi].conv_w = (const float*)d_in[7 + mi * 9 + 1];
        P[mi].conv_b = (const float*)d_in[7 + mi * 9 + 2];
        P[mi].xproj_w= (const float*)d_in[7 + mi * 9 + 3];
        P[mi].dt_w   = (const float*)d_in[7 + mi * 9 + 4];
        P[mi].dt_b   = (const float*)d_in[7 + mi * 9 + 5];
        P[mi].A_log  = (const float*)d_in[7 + mi * 9 + 6];
        P[mi].D      = (const float*)d_in[7 + mi * 9 + 7];
        P[mi].out_w  = (const float*)d_in[7 + mi * 9 + 8];
    }
    float* out = (float*)d_out;

    const size_t ZBs = (size_t)NSEQ * TLEN * 32;   // 4.2M floats
    const size_t SCs = (size_t)NSEQ * TLEN * 96;   // 12.6M (y aliased in-place)
    const size_t PSs = (size_t)NSEQ * NCH * 512;   // 1.05M
    const size_t arena = ZBs + SCs + 3 * PSs;      // 19.95M floats = 79.8 MB

    float* A0 = (float*)d_ws;
    auto ZB = [&](int y) { return A0 + (size_t)y * arena; };
    auto SC = [&](int y) { return A0 + (size_t)y * arena + ZBs; };
    auto PS = [&](int y) { return A0 + (size_t)y * arena + ZBs + SCs; };
    auto FS = [&](int y) { return PS(y) + PSs; };
    auto HI = [&](int y) { return FS(y) + PSs; };

    const bool fits3 = ws_size >= 3 * arena * sizeof(float);
    const bool fits2 = ws_size >= 2 * arena * sizeof(float);

    dim3 b256(256), b128(128), b512(512);
    dim3 grd3((NSEQ * LSEQ + 255) / 256);

    if (fits3) {
        k_p1<-1><<<dim3(NSEQ * NT, 3), b256, 0, stream>>>(
            x, gt1, gt2, ln1g, ln1b, ln2g, ln2b, P[0], P[1], 0, ZB(0), SC(0), arena);
        k_scan1<-1><<<dim3(NSEQ * NCH, 3), b128, 0, stream>>>(
            SC(0), P[0], P[1], 0, PS(0), FS(0), arena);
        k_comb<<<dim3(NSEQ, 3), b512, 0, stream>>>(PS(0), FS(0), HI(0), arena);
        k_scan2<-1><<<dim3(NSEQ * NCH, 3), b128, 0, stream>>>(
            SC(0), P[0], P[1], 0, HI(0), arena);
        k_p3<0><<<grd3, b256, 0, stream>>>(SC(0), ZB(0), P[0].out_w, out);
        k_p3<1><<<grd3, b256, 0, stream>>>(SC(1), ZB(1), P[1].out_w, out);
        k_p3<2><<<grd3, b256, 0, stream>>>(SC(2), ZB(2), P[1].out_w, out);
    } else if (fits2) {
        // mode 0 serial (templated) into arena 0
        k_p1<0><<<dim3(NSEQ * NT, 1), b256, 0, stream>>>(
            x, gt1, gt2, ln1g, ln1b, ln2g, ln2b, P[0], P[1], 0, ZB(0), SC(0), arena);
        k_scan1<0><<<dim3(NSEQ * NCH, 1), b128, 0, stream>>>(
            SC(0), P[0], P[1], 0, PS(0), FS(0), arena);
        k_comb<<<dim3(NSEQ, 1), b512, 0, stream>>>(PS(0), FS(0), HI(0), arena);
        k_scan2<0><<<dim3(NSEQ * NCH, 1), b128, 0, stream>>>(
            SC(0), P[0], P[1], 0, HI(0), arena);
        k_p3<0><<<grd3, b256, 0, stream>>>(SC(0), ZB(0), P[0].out_w, out);
        // modes 1,2 batched into arenas 0,1 (stream order protects arena-0 reuse)
        k_p1<-1><<<dim3(NSEQ * NT, 2), b256, 0, stream>>>(
            x, gt1, gt2, ln1g, ln1b, ln2g, ln2b, P[0], P[1], 1, ZB(0), SC(0), arena);
        k_scan1<-1><<<dim3(NSEQ * NCH, 2), b128, 0, stream>>>(
            SC(0), P[0], P[1], 1, PS(0), FS(0), arena);
        k_comb<<<dim3(NSEQ, 2), b512, 0, stream>>>(PS(0), FS(0), HI(0), arena);
        k_scan2<-1><<<dim3(NSEQ * NCH, 2), b128, 0, stream>>>(
            SC(0), P[0], P[1], 1, HI(0), arena);
        k_p3<1><<<grd3, b256, 0, stream>>>(SC(0), ZB(0), P[1].out_w, out);
        k_p3<2><<<grd3, b256, 0, stream>>>(SC(1), ZB(1), P[1].out_w, out);
    } else {
        // serial, arena 0 only
        for (int mode = 0; mode < 3; mode++) {
            if (mode == 0)
                k_p1<0><<<dim3(NSEQ * NT, 1), b256, 0, stream>>>(
                    x, gt1, gt2, ln1g, ln1b, ln2g, ln2b, P[0], P[1], 0, ZB(0), SC(0), arena);
            else if (mode == 1)
                k_p1<1><<<dim3(NSEQ * NT, 1), b256, 0, stream>>>(
                    x, gt1, gt2, ln1g, ln1b, ln2g, ln2b, P[0], P[1], 0, ZB(0), SC(0), arena);
            else
                k_p1<2><<<dim3(NSEQ * NT, 1), b256, 0, stream>>>(
                    x, gt1, gt2, ln1g, ln1b, ln2g, ln2b, P[0], P[1], 0, ZB(0), SC(0), arena);
            if (mode == 0)
                k_scan1<0><<<dim3(NSEQ * NCH, 1), b128, 0, stream>>>(SC(0), P[0], P[1], 0, PS(0), FS(0), arena);
            else if (mode == 1)
                k_scan1<1><<<dim3(NSEQ * NCH, 1), b128, 0, stream>>>(SC(0), P[0], P[1], 0, PS(0), FS(0), arena);
            else
                k_scan1<2><<<dim3(NSEQ * NCH, 1), b128, 0, stream>>>(SC(0), P[0], P[1], 0, PS(0), FS(0), arena);
            k_comb<<<dim3(NSEQ, 1), b512, 0, stream>>>(PS(0), FS(0), HI(0), arena);
            if (mode == 0)
                k_scan2<0><<<dim3(NSEQ * NCH, 1), b128, 0, stream>>>(SC(0), P[0], P[1], 0, HI(0), arena);
            else if (mode == 1)
                k_scan2<1><<<dim3(NSEQ * NCH, 1), b128, 0, stream>>>(SC(0), P[0], P[1], 0, HI(0), arena);
            else
                k_scan2<2><<<dim3(NSEQ * NCH, 1), b128, 0, stream>>>(SC(0), P[0], P[1], 0, HI(0), arena);
            if (mode == 0)      k_p3<0><<<grd3, b256, 0, stream>>>(SC(0), ZB(0), P[0].out_w, out);
            else if (mode == 1) k_p3<1><<<grd3, b256, 0, stream>>>(SC(0), ZB(0), P[1].out_w, out);
            else                k_p3<2><<<grd3, b256, 0, stream>>>(SC(0), ZB(0), P[1].out_w, out);
        }
    }
}

// Round 18
// 322.741 us; speedup vs baseline: 1.4068x; 1.1054x over previous
//
#include <hip/hip_runtime.h>
#include <cmath>

namespace {

constexpr int XC = 64, XH = 128, XW = 128;
constexpr int NSEQ = 128;   // B(2) * 64 cubes
constexpr int TLEN = 1025;  // gt token + 1024
constexpr int LSEQ = 1024;
constexpr int NCH = 16;     // chunks per sequence (parallel scan)
constexpr int CHUNK = 65;   // 16*65 = 1040 >= 1025
constexpr int TT = 96;      // token tile for fused p1
constexpr int NT = 11;      // ceil(1025/96)

struct MP {
    const float *in_w, *conv_w, *conv_b, *xproj_w, *dt_w, *dt_b, *A_log, *D, *out_w;
};

__device__ __forceinline__ int xidx(int b, int c, int h, int w) {
    return ((b * XC + c) * XH + h) * XW + w;
}
__device__ __forceinline__ int oidx(int b, int cube, int c, int i, int j) {
    int h = cube * 2 + (i >> 3);
    int w = ((i & 7) << 4) | j;
    return xidx(b, c, h, w);
}
__device__ __forceinline__ float siluf(float v) { return v / (1.0f + __expf(-v)); }
__device__ __forceinline__ float softplusf(float v) {
    return v > 20.0f ? v : log1pf(__expf(v));
}

template <int MODE>
__device__ __forceinline__ float gather_val(const float* __restrict__ x,
                                            const float* __restrict__ s_gt,
                                            int t, int k, int b, int bi, int bj) {
    if (t == 0) return s_gt[k];
    int l = t - 1;
    if (MODE == 0) {
        int i2 = l >> 5, j2 = l & 31;
        int h = bi * 16 + (i2 >> 1), w = bj * 16 + (j2 >> 1);
        int coff = ((i2 & 1) << 1) | (j2 & 1);
        return x[xidx(b, k * 4 + coff, h, w)];
    } else if (MODE == 1) {
        int c = l >> 4, j = l & 15;
        return x[xidx(b, c, bi * 16 + k, bj * 16 + j)];
    } else {
        int c = l >> 4, i = l & 15;
        return x[xidx(b, c, bi * 16 + i, bj * 16 + k)];
    }
}
__device__ __forceinline__ float gather_rt(int mode, const float* __restrict__ x,
                                           const float* __restrict__ s_gt,
                                           int t, int k, int b, int bi, int bj) {
    if (mode == 0) return gather_val<0>(x, s_gt, t, k, b, bi, bj);
    if (mode == 1) return gather_val<1>(x, s_gt, t, k, b, bi, bj);
    return gather_val<2>(x, s_gt, t, k, b, bi, bj);
}

// ==== phase 1: gather+LN+in-proj+conv+x-proj (MODE_C=-1 -> blockIdx.y mode) =
template <int MODE_C>
__global__ __launch_bounds__(256) void k_p1(
    const float* __restrict__ x,
    const float* __restrict__ gt1, const float* __restrict__ gt2,
    const float* __restrict__ ln1g, const float* __restrict__ ln1b,
    const float* __restrict__ ln2g, const float* __restrict__ ln2b,
    MP P0, MP P1, int mode_base,
    float* __restrict__ ZB0, float* __restrict__ SC0, size_t arena)
{
    const int mode = (MODE_C >= 0) ? MODE_C : (mode_base + (int)blockIdx.y);
    const MP P = (mode == 0) ? P0 : P1;
    const float* gt  = (mode == 0) ? gt1 : gt2;
    const float* lng = (mode == 0) ? ln1g : ln2g;
    const float* lnb = (mode == 0) ? ln1b : ln2b;
    float* Zb = ZB0 + (size_t)blockIdx.y * arena;
    float* sc = SC0 + (size_t)blockIdx.y * arena;

    const int n = blockIdx.x / NT, tile = blockIdx.x % NT;
    const int t0 = tile * TT;
    const int ntk = min(TT, TLEN - t0);
    const int nth = ntk + 3;  // with 3-token front halo
    const int b = n >> 6, cube = n & 63, bi = cube >> 3, bj = cube & 7;
    const int tid = threadIdx.x;

    // s_v [TT+3][17] overlaid on s_xc [TT][37]: disjoint lifetimes
    __shared__ __align__(16) float s_pool[TT * 37];
    float (*s_v)[17]  = (float(*)[17])s_pool;
    float (*s_xc)[37] = (float(*)[37])s_pool;
    __shared__ __align__(16) float s_xi[TT + 3][36];
    __shared__ __align__(16) float s_wT[16][64];   // s_wT[k][oc] = in_w[oc][k]
    __shared__ __align__(16) float s_xpT[32][36];  // s_xpT[cc][q] = xproj_w[q+1][cc]
    __shared__ float s_xp0[32];
    __shared__ float s_cw[128], s_cb[32], s_dw[32], s_db[32];
    __shared__ float s_g[16], s_bb[16], s_gt[16];
    __shared__ float s_dt0[TT];

    for (int i = tid; i < 64 * 16; i += 256) s_wT[i & 15][i >> 4] = P.in_w[i];
    for (int i = tid; i < 33 * 32; i += 256) {
        int r = i >> 5, cc = i & 31;
        float v = P.xproj_w[i];
        if (r == 0) s_xp0[cc] = v;
        else s_xpT[cc][r - 1] = v;
    }
    if (tid < 128) s_cw[tid] = P.conv_w[tid];
    if (tid < 32) { s_cb[tid] = P.conv_b[tid]; s_dw[tid] = P.dt_w[tid]; s_db[tid] = P.dt_b[tid]; }
    if (tid < 16) { s_g[tid] = lng[tid]; s_bb[tid] = lnb[tid]; s_gt[tid] = gt[tid]; }
    __syncthreads();

    // ---- gather + LN, token-per-thread, registers only
    if (tid < nth) {
        int t = t0 - 3 + tid;
        float v[16];
        if (t < 0) {
#pragma unroll
            for (int k = 0; k < 16; k++) v[k] = 0.f;
        } else {
#pragma unroll
            for (int k = 0; k < 16; k++) {
                if (MODE_C >= 0) v[k] = gather_val<(MODE_C >= 0 ? MODE_C : 0)>(x, s_gt, t, k, b, bi, bj);
                else             v[k] = gather_rt(mode, x, s_gt, t, k, b, bi, bj);
            }
            float mu = 0.f;
#pragma unroll
            for (int k = 0; k < 16; k++) mu += v[k];
            mu *= (1.f / 16.f);
            float var = 0.f;
#pragma unroll
            for (int k = 0; k < 16; k++) { float d = v[k] - mu; var += d * d; }
            float inv = rsqrtf(var * (1.f / 16.f) + 1e-5f);
#pragma unroll
            for (int k = 0; k < 16; k++) v[k] = (v[k] - mu) * inv * s_g[k] + s_bb[k];
        }
#pragma unroll
        for (int k = 0; k < 16; k++) s_v[tid][k] = v[k];
    }
    __syncthreads();

    // ---- in-proj, 4-token x 4-oc register tiles (og<8 -> xi LDS, og>=8 -> z)
    {
        const int ntt = (nth + 3) >> 2;
        for (int tl0 = tid; tl0 < ntt * 16; tl0 += 256) {
            int tt = tl0 >> 4, og = tl0 & 15;
            int oc = og * 4;
            float acc[4][4] = {{0.f}};
#pragma unroll
            for (int k = 0; k < 16; k++) {
                float4 wv = *(const float4*)&s_wT[k][oc];
                float a0 = s_v[4 * tt + 0][k];
                float a1 = s_v[4 * tt + 1][k];
                float a2 = s_v[4 * tt + 2][k];
                float a3 = s_v[4 * tt + 3][k];
                acc[0][0] += a0 * wv.x; acc[0][1] += a0 * wv.y; acc[0][2] += a0 * wv.z; acc[0][3] += a0 * wv.w;
                acc[1][0] += a1 * wv.x; acc[1][1] += a1 * wv.y; acc[1][2] += a1 * wv.z; acc[1][3] += a1 * wv.w;
                acc[2][0] += a2 * wv.x; acc[2][1] += a2 * wv.y; acc[2][2] += a2 * wv.z; acc[2][3] += a2 * wv.w;
                acc[3][0] += a3 * wv.x; acc[3][1] += a3 * wv.y; acc[3][2] += a3 * wv.z; acc[3][3] += a3 * wv.w;
            }
#pragma unroll
            for (int i = 0; i < 4; i++) {
                int tl = 4 * tt + i;
                if (tl >= nth) break;
                if (og < 8) {
                    *(float4*)&s_xi[tl][oc] =
                        make_float4(acc[i][0], acc[i][1], acc[i][2], acc[i][3]);
                } else if (tl >= 3) {
                    *(float4*)&Zb[((size_t)n * TLEN + t0 + tl - 3) * 32 + (oc - 32)] =
                        make_float4(acc[i][0], acc[i][1], acc[i][2], acc[i][3]);
                }
            }
        }
    }
    __syncthreads();  // s_v dead; pool becomes s_xc

    // ---- conv4 + silu: thread = (cc, token-group); emit xc to global here too
    {
        int cc = tid & 31, jg = tid >> 5;
        float c0 = s_cw[cc * 4 + 0], c1 = s_cw[cc * 4 + 1];
        float c2 = s_cw[cc * 4 + 2], c3 = s_cw[cc * 4 + 3];
        float cb = s_cb[cc];
        float* scb = sc + ((size_t)n * TLEN + t0) * 96;
        for (int j = jg; j < ntk; j += 8) {
            float acc = 0.f;
            acc += c0 * s_xi[j + 0][cc];
            acc += c1 * s_xi[j + 1][cc];
            acc += c2 * s_xi[j + 2][cc];
            acc += c3 * s_xi[j + 3][cc];
            float v = siluf(acc + cb);
            s_xc[j][cc] = v;
            scb[j * 96 + cc] = v;
        }
    }
    __syncthreads();

    // ---- x-proj B/C rows, 4-token x 4-q register tile
    {
        int qt = tid & 7, tt = tid >> 3;
        if (4 * tt < ntk) {
            float acc[4][4] = {{0.f}};
#pragma unroll
            for (int cc = 0; cc < 32; cc++) {
                float4 wv = *(const float4*)&s_xpT[cc][4 * qt];
                float a0 = s_xc[4 * tt + 0][cc];
                float a1 = s_xc[4 * tt + 1][cc];
                float a2 = s_xc[4 * tt + 2][cc];
                float a3 = s_xc[4 * tt + 3][cc];
                acc[0][0] += a0 * wv.x; acc[0][1] += a0 * wv.y; acc[0][2] += a0 * wv.z; acc[0][3] += a0 * wv.w;
                acc[1][0] += a1 * wv.x; acc[1][1] += a1 * wv.y; acc[1][2] += a1 * wv.z; acc[1][3] += a1 * wv.w;
                acc[2][0] += a2 * wv.x; acc[2][1] += a2 * wv.y; acc[2][2] += a2 * wv.z; acc[2][3] += a2 * wv.w;
                acc[3][0] += a3 * wv.x; acc[3][1] += a3 * wv.y; acc[3][2] += a3 * wv.z; acc[3][3] += a3 * wv.w;
            }
#pragma unroll
            for (int i = 0; i < 4; i++) {
                int j = 4 * tt + i;
                if (j < ntk)
                    *(float4*)&sc[((size_t)n * TLEN + t0 + j) * 96 + 64 + 4 * qt] =
                        make_float4(acc[i][0], acc[i][1], acc[i][2], acc[i][3]);
            }
        }
        // dt0 per token (reads only s_xc / s_xp0)
        if (tid < ntk) {
            float acc = 0.f;
#pragma unroll
            for (int cc = 0; cc < 32; cc++) acc += s_xc[tid][cc] * s_xp0[cc];
            s_dt0[tid] = acc;
        }
    }
    __syncthreads();

    // ---- dt block emit (coalesced stores)
    {
        float* scb = sc + ((size_t)n * TLEN + t0) * 96;
        for (int it = tid; it < ntk * 32; it += 256) {
            int j = it >> 5, d = it & 31;
            scb[j * 96 + 32 + d] = softplusf(s_dt0[j] * s_dw[d] + s_db[d]);
        }
    }
}

// -------- phase 2a: per-chunk scan summaries; stage only xc/dt/B (80 f) -----
template <int MODE_C>
__global__ __launch_bounds__(128) void k_scan1(
    const float* __restrict__ SC0, MP P0, MP P1, int mode_base,
    float* __restrict__ PS0, float* __restrict__ FS0, size_t arena)
{
    const int mode = (MODE_C >= 0) ? MODE_C : (mode_base + (int)blockIdx.y);
    const float* A_log = (mode == 0) ? P0.A_log : P1.A_log;
    const float* sc = SC0 + (size_t)blockIdx.y * arena;
    float* Psum = PS0 + (size_t)blockIdx.y * arena;
    float* Fsum = FS0 + (size_t)blockIdx.y * arena;

    int n = blockIdx.x >> 4;
    int c = blockIdx.x & (NCH - 1);
    int t0 = c * CHUNK;
    int nt = min(CHUNK, TLEN - t0);
    __shared__ __align__(16) float s_sc[CHUNK * 80];   // xc[32] dt[32] B[16]
    const float* src = sc + ((size_t)n * TLEN + t0) * 96;
    for (int i = threadIdx.x; i < nt * 20; i += 128) {
        int row = i / 20, q = i - row * 20;
        ((float4*)s_sc)[row * 20 + q] = *(const float4*)&src[row * 96 + q * 4];
    }
    int tid = threadIdx.x, d = tid >> 2, sg = tid & 3;
    float4 Av = *(const float4*)&A_log[d * 16 + sg * 4];
    float A0 = -__expf(Av.x), A1 = -__expf(Av.y), A2 = -__expf(Av.z), A3 = -__expf(Av.w);
    __syncthreads();
    float h0 = 0.f, h1 = 0.f, h2 = 0.f, h3 = 0.f;
    float P0v = 1.f, P1v = 1.f, P2v = 1.f, P3v = 1.f;
    for (int t = 0; t < nt; t++) {
        const float* p = s_sc + t * 80;
        float dt = p[32 + d], xc = p[d];
        float4 Bv = *(const float4*)&p[64 + sg * 4];
        float a0 = __expf(dt * A0); h0 = a0 * h0 + dt * Bv.x * xc; P0v *= a0;
        float a1 = __expf(dt * A1); h1 = a1 * h1 + dt * Bv.y * xc; P1v *= a1;
        float a2 = __expf(dt * A2); h2 = a2 * h2 + dt * Bv.z * xc; P2v *= a2;
        float a3 = __expf(dt * A3); h3 = a3 * h3 + dt * Bv.w * xc; P3v *= a3;
    }
    size_t base = ((size_t)n * NCH + c) * 512 + d * 16 + sg * 4;
    *(float4*)&Psum[base] = make_float4(P0v, P1v, P2v, P3v);
    *(float4*)&Fsum[base] = make_float4(h0, h1, h2, h3);
}

// -------- phase 2b: combine chunk summaries -> incoming state per chunk -----
__global__ __launch_bounds__(512) void k_comb(
    const float* __restrict__ PS0, const float* __restrict__ FS0,
    float* __restrict__ HI0, size_t arena)
{
    const float* Psum = PS0 + (size_t)blockIdx.y * arena;
    const float* Fsum = FS0 + (size_t)blockIdx.y * arena;
    float* Hin = HI0 + (size_t)blockIdx.y * arena;
    int n = blockIdx.x, tid = threadIdx.x;
    const float* pb = Psum + (size_t)n * NCH * 512;
    const float* fb = Fsum + (size_t)n * NCH * 512;
    float* hb = Hin + (size_t)n * NCH * 512;
    float H = 0.f;
#pragma unroll
    for (int c = 0; c < NCH; c++) {
        float P = pb[(size_t)c * 512 + tid];
        float F = fb[(size_t)c * 512 + tid];
        hb[(size_t)c * 512 + tid] = H;
        H = F + P * H;
    }
}

// --- phase 2c: scan pass 2; y overwrites staged xc slot in LDS, then SC -----
template <int MODE_C>
__global__ __launch_bounds__(128) void k_scan2(
    float* __restrict__ SC0, MP P0, MP P1, int mode_base,
    const float* __restrict__ HI0, size_t arena)
{
    const int mode = (MODE_C >= 0) ? MODE_C : (mode_base + (int)blockIdx.y);
    const float* A_log = (mode == 0) ? P0.A_log : P1.A_log;
    const float* Dp = (mode == 0) ? P0.D : P1.D;
    float* sc = SC0 + (size_t)blockIdx.y * arena;
    const float* Hin = HI0 + (size_t)blockIdx.y * arena;

    int n = blockIdx.x >> 4;
    int c = blockIdx.x & (NCH - 1);
    int t0 = c * CHUNK;
    int nt = min(CHUNK, TLEN - t0);
    __shared__ __align__(16) float s_sc[CHUNK * 96];
    const float* src = sc + ((size_t)n * TLEN + t0) * 96;
    int nv4 = nt * 24;
    for (int i = threadIdx.x; i < nv4; i += 128)
        ((float4*)s_sc)[i] = ((const float4*)src)[i];
    int tid = threadIdx.x, d = tid >> 2, sg = tid & 3;
    float4 Av = *(const float4*)&A_log[d * 16 + sg * 4];
    float A0 = -__expf(Av.x), A1 = -__expf(Av.y), A2 = -__expf(Av.z), A3 = -__expf(Av.w);
    float Dd = Dp[d];
    float4 Hv = *(const float4*)&Hin[((size_t)n * NCH + c) * 512 + d * 16 + sg * 4];
    float h0 = Hv.x, h1 = Hv.y, h2 = Hv.z, h3 = Hv.w;
    __syncthreads();
    // y[t][d] overwrites s_sc[t*96+d] after xc[t][d]'s final read.
    // Wave w owns d in [16w,16w+16): its xc reads and y writes stay in-range,
    // t is monotonic per wave -> no cross-wave hazard, no extra barrier.
    for (int t = 0; t < nt; t++) {
        float* p = s_sc + t * 96;
        float dt = p[32 + d], xc = p[d];
        float4 Bv = *(const float4*)&p[64 + sg * 4];
        float4 Cv = *(const float4*)&p[80 + sg * 4];
        float a0 = __expf(dt * A0); h0 = a0 * h0 + dt * Bv.x * xc;
        float a1 = __expf(dt * A1); h1 = a1 * h1 + dt * Bv.y * xc;
        float a2 = __expf(dt * A2); h2 = a2 * h2 + dt * Bv.z * xc;
        float a3 = __expf(dt * A3); h3 = a3 * h3 + dt * Bv.w * xc;
        float pp = h0 * Cv.x + h1 * Cv.y + h2 * Cv.z + h3 * Cv.w;
        pp += __shfl_xor(pp, 1);
        pp += __shfl_xor(pp, 2);
        if (sg == 0) p[d] = pp + Dd * xc;
    }
    __syncthreads();
    // write y (xc slot) back to SC in place
    float* yb = sc + ((size_t)n * TLEN + t0) * 96;
    for (int i = threadIdx.x; i < nt * 8; i += 128) {
        int j = i >> 3, q = i & 7;
        *(float4*)&yb[j * 96 + q * 4] = *(const float4*)&s_sc[j * 96 + q * 4];
    }
}

// ---------------- phase 3: gate + out-proj + scatter (per-mode) -------------
// y lives in SC rows (stride 96, offset 0)
template <int MODE>
__global__ void k_p3(const float* __restrict__ ysc, const float* __restrict__ Zb,
                     const float* __restrict__ out_w,  // (16,32)
                     float* __restrict__ out)
{
    __shared__ float s_w[16 * 32];
    for (int i = threadIdx.x; i < 512; i += blockDim.x) s_w[i] = out_w[i];
    __syncthreads();
    int tid = blockIdx.x * blockDim.x + threadIdx.x;
    if (tid >= NSEQ * LSEQ) return;
    int n = tid >> 10, l = tid & 1023, t = l + 1;
    const float* y = ysc + ((size_t)n * TLEN + t) * 96;
    const float* z = Zb + ((size_t)n * TLEN + t) * 32;
    float yv[32];
#pragma unroll
    for (int c = 0; c < 32; c++) yv[c] = y[c] * siluf(z[c]);
    float o[16];
#pragma unroll
    for (int j = 0; j < 16; j++) {
        float acc = 0.f;
#pragma unroll
        for (int c = 0; c < 32; c++) acc += yv[c] * s_w[j * 32 + c];
        o[j] = acc * (1.0f / 3.0f);
    }
    int b = n >> 6, cube = n & 63;
    if (MODE == 0) {
        int i2 = l >> 5, j2 = l & 31;
        int io = i2 >> 1, jo = j2 >> 1;
        int coff = ((i2 & 1) << 1) | (j2 & 1);
#pragma unroll
        for (int j = 0; j < 16; j++) out[oidx(b, cube, j * 4 + coff, io, jo)] = o[j];
    } else if (MODE == 1) {
        int c = l >> 4, jj = l & 15;
#pragma unroll
        for (int j = 0; j < 16; j++) out[oidx(b, cube, c, j, jj)] += o[j];
    } else {
        int c = l >> 4, ii = l & 15;
#pragma unroll
        for (int j = 0; j < 16; j++) out[oidx(b, cube, c, ii, j)] += o[j];
    }
}

}  // namespace

extern "C" void kernel_launch(void* const* d_in, const int* in_sizes, int n_in,
                              void* d_out, int out_size, void* d_ws, size_t ws_size,
                              hipStream_t stream) {
    const float* x   = (const float*)d_in[0];
    const float* gt1 = (const float*)d_in[1];
    const float* gt2 = (const float*)d_in[2];
    const float* ln1g = (const float*)d_in[3];
    const float* ln1b = (const float*)d_in[4];
    const float* ln2g = (const float*)d_in[5];
    const float* ln2b = (const float*)d_in[6];
    MP P[2];
    for (int mi = 0; mi < 2; mi++) {
        P[mi].in_w   = (const float*)d_in[7 + mi * 9 + 0];
        P[mi].conv_w = (const float*)d_in[7 + mi * 9 + 1];
        P[mi].conv_b = (const float*)d_in[7 + mi * 9 + 2];
        P[mi].xproj_w= (const float*)d_in[7 + mi * 9 + 3];
        P[mi].dt_w   = (const float*)d_in[7 + mi * 9 + 4];
        P[mi].dt_b   = (const float*)d_in[7 + mi * 9 + 5];
        P[mi].A_log  = (const float*)d_in[7 + mi * 9 + 6];
        P[mi].D      = (const float*)d_in[7 + mi * 9 + 7];
        P[mi].out_w  = (const float*)d_in[7 + mi * 9 + 8];
    }
    float* out = (float*)d_out;

    const size_t ZBs = (size_t)NSEQ * TLEN * 32;   // 4.2M floats
    const size_t SCs = (size_t)NSEQ * TLEN * 96;   // 12.6M (y aliased in-place)
    const size_t PSs = (size_t)NSEQ * NCH * 512;   // 1.05M
    const size_t arena = ZBs + SCs + 3 * PSs;      // 19.95M floats = 79.8 MB

    float* A0 = (float*)d_ws;
    auto ZB = [&](int y) { return A0 + (size_t)y * arena; };
    auto SC = [&](int y) { return A0 + (size_t)y * arena + ZBs; };
    auto PS = [&](int y) { return A0 + (size_t)y * arena + ZBs + SCs; };
    auto FS = [&](int y) { return PS(y) + PSs; };
    auto HI = [&](int y) { return FS(y) + PSs; };

    const bool fits3 = ws_size >= 3 * arena * sizeof(float);
    const bool fits2 = ws_size >= 2 * arena * sizeof(float);

    dim3 b256(256), b128(128), b512(512);
    dim3 grd3((NSEQ * LSEQ + 255) / 256);

    if (fits3) {
        k_p1<-1><<<dim3(NSEQ * NT, 3), b256, 0, stream>>>(
            x, gt1, gt2, ln1g, ln1b, ln2g, ln2b, P[0], P[1], 0, ZB(0), SC(0), arena);
        k_scan1<-1><<<dim3(NSEQ * NCH, 3), b128, 0, stream>>>(
            SC(0), P[0], P[1], 0, PS(0), FS(0), arena);
        k_comb<<<dim3(NSEQ, 3), b512, 0, stream>>>(PS(0), FS(0), HI(0), arena);
        k_scan2<-1><<<dim3(NSEQ * NCH, 3), b128, 0, stream>>>(
            SC(0), P[0], P[1], 0, HI(0), arena);
        k_p3<0><<<grd3, b256, 0, stream>>>(SC(0), ZB(0), P[0].out_w, out);
        k_p3<1><<<grd3, b256, 0, stream>>>(SC(1), ZB(1), P[1].out_w, out);
        k_p3<2><<<grd3, b256, 0, stream>>>(SC(2), ZB(2), P[1].out_w, out);
    } else if (fits2) {
        // mode 0 serial (templated) into arena 0
        k_p1<0><<<dim3(NSEQ * NT, 1), b256, 0, stream>>>(
            x, gt1, gt2, ln1g, ln1b, ln2g, ln2b, P[0], P[1], 0, ZB(0), SC(0), arena);
        k_scan1<0><<<dim3(NSEQ * NCH, 1), b128, 0, stream>>>(
            SC(0), P[0], P[1], 0, PS(0), FS(0), arena);
        k_comb<<<dim3(NSEQ, 1), b512, 0, stream>>>(PS(0), FS(0), HI(0), arena);
        k_scan2<0><<<dim3(NSEQ * NCH, 1), b128, 0, stream>>>(
            SC(0), P[0], P[1], 0, HI(0), arena);
        k_p3<0><<<grd3, b256, 0, stream>>>(SC(0), ZB(0), P[0].out_w, out);
        // modes 1,2 batched into arenas 0,1 (stream order protects arena-0 reuse)
        k_p1<-1><<<dim3(NSEQ * NT, 2), b256, 0, stream>>>(
            x, gt1, gt2, ln1g, ln1b, ln2g, ln2b, P[0], P[1], 1, ZB(0), SC(0), arena);
        k_scan1<-1><<<dim3(NSEQ * NCH, 2), b128, 0, stream>>>(
            SC(0), P[0], P[1], 1, PS(0), FS(0), arena);
        k_comb<<<dim3(NSEQ, 2), b512, 0, stream>>>(PS(0), FS(0), HI(0), arena);
        k_scan2<-1><<<dim3(NSEQ * NCH, 2), b128, 0, stream>>>(
            SC(0), P[0], P[1], 1, HI(0), arena);
        k_p3<1><<<grd3, b256, 0, stream>>>(SC(0), ZB(0), P[1].out_w, out);
        k_p3<2><<<grd3, b256, 0, stream>>>(SC(1), ZB(1), P[1].out_w, out);
    } else {
        // serial, arena 0 only
        for (int mode = 0; mode < 3; mode++) {
            if (mode == 0)
                k_p1<0><<<dim3(NSEQ * NT, 1), b256, 0, stream>>>(
                    x, gt1, gt2, ln1g, ln1b, ln2g, ln2b, P[0], P[1], 0, ZB(0), SC(0), arena);
            else if (mode == 1)
                k_p1<1><<<dim3(NSEQ * NT, 1), b256, 0, stream>>>(
                    x, gt1, gt2, ln1g, ln1b, ln2g, ln2b, P[0], P[1], 0, ZB(0), SC(0), arena);
            else
                k_p1<2><<<dim3(NSEQ * NT, 1), b256, 0, stream>>>(
                    x, gt1, gt2, ln1g, ln1b, ln2g, ln2b, P[0], P[1], 0, ZB(0), SC(0), arena);
            if (mode == 0)
                k_scan1<0><<<dim3(NSEQ * NCH, 1), b128, 0, stream>>>(SC(0), P[0], P[1], 0, PS(0), FS(0), arena);
            else if (mode == 1)
                k_scan1<1><<<dim3(NSEQ * NCH, 1), b128, 0, stream>>>(SC(0), P[0], P[1], 0, PS(0), FS(0), arena);
            else
                k_scan1<2><<<dim3(NSEQ * NCH, 1), b128, 0, stream>>>(SC(0), P[0], P[1], 0, PS(0), FS(0), arena);
            k_comb<<<dim3(NSEQ, 1), b512, 0, stream>>>(PS(0), FS(0), HI(0), arena);
            if (mode == 0)
                k_scan2<0><<<dim3(NSEQ * NCH, 1), b128, 0, stream>>>(SC(0), P[0], P[1], 0, HI(0), arena);
            else if (mode == 1)
                k_scan2<1><<<dim3(NSEQ * NCH, 1), b128, 0, stream>>>(SC(0), P[0], P[1], 0, HI(0), arena);
            else
                k_scan2<2><<<dim3(NSEQ * NCH, 1), b128, 0, stream>>>(SC(0), P[0], P[1], 0, HI(0), arena);
            if (mode == 0)      k_p3<0><<<grd3, b256, 0, stream>>>(SC(0), ZB(0), P[0].out_w, out);
            else if (mode == 1) k_p3<1><<<grd3, b256, 0, stream>>>(SC(0), ZB(0), P[1].out_w, out);
            else                k_p3<2><<<grd3, b256, 0, stream>>>(SC(0), ZB(0), P[1].out_w, out);
        }
    }
}

// Round 19
// 308.800 us; speedup vs baseline: 1.4703x; 1.0451x over previous
//
#include <hip/hip_runtime.h>
#include <cmath>

namespace {

constexpr int XC = 64, XH = 128, XW = 128;
constexpr int NSEQ = 128;   // B(2) * 64 cubes
constexpr int TLEN = 1025;  // gt token + 1024
constexpr int LSEQ = 1024;
constexpr int NCH = 16;     // chunks per sequence (parallel scan)
constexpr int CHUNK = 65;   // 16*65 = 1040 >= 1025
constexpr int TT = 96;      // token tile for fused p1
constexpr int NT = 11;      // ceil(1025/96)

struct MP {
    const float *in_w, *conv_w, *conv_b, *xproj_w, *dt_w, *dt_b, *A_log, *D, *out_w;
};

__device__ __forceinline__ int xidx(int b, int c, int h, int w) {
    return ((b * XC + c) * XH + h) * XW + w;
}
__device__ __forceinline__ int oidx(int b, int cube, int c, int i, int j) {
    int h = cube * 2 + (i >> 3);
    int w = ((i & 7) << 4) | j;
    return xidx(b, c, h, w);
}
__device__ __forceinline__ float siluf(float v) { return v / (1.0f + __expf(-v)); }
__device__ __forceinline__ float softplusf(float v) {
    return v > 20.0f ? v : log1pf(__expf(v));
}

template <int MODE>
__device__ __forceinline__ float gather_val(const float* __restrict__ x,
                                            const float* __restrict__ s_gt,
                                            int t, int k, int b, int bi, int bj) {
    if (t == 0) return s_gt[k];
    int l = t - 1;
    if (MODE == 0) {
        int i2 = l >> 5, j2 = l & 31;
        int h = bi * 16 + (i2 >> 1), w = bj * 16 + (j2 >> 1);
        int coff = ((i2 & 1) << 1) | (j2 & 1);
        return x[xidx(b, k * 4 + coff, h, w)];
    } else if (MODE == 1) {
        int c = l >> 4, j = l & 15;
        return x[xidx(b, c, bi * 16 + k, bj * 16 + j)];
    } else {
        int c = l >> 4, i = l & 15;
        return x[xidx(b, c, bi * 16 + i, bj * 16 + k)];
    }
}
__device__ __forceinline__ float gather_rt(int mode, const float* __restrict__ x,
                                           const float* __restrict__ s_gt,
                                           int t, int k, int b, int bi, int bj) {
    if (mode == 0) return gather_val<0>(x, s_gt, t, k, b, bi, bj);
    if (mode == 1) return gather_val<1>(x, s_gt, t, k, b, bi, bj);
    return gather_val<2>(x, s_gt, t, k, b, bi, bj);
}

// ==== phase 1: gather+LN+in-proj(xi)+conv+x-proj; LN output v -> VB =========
template <int MODE_C>
__global__ __launch_bounds__(256) void k_p1(
    const float* __restrict__ x,
    const float* __restrict__ gt1, const float* __restrict__ gt2,
    const float* __restrict__ ln1g, const float* __restrict__ ln1b,
    const float* __restrict__ ln2g, const float* __restrict__ ln2b,
    MP P0, MP P1, int mode_base,
    float* __restrict__ VB0, float* __restrict__ SC0, size_t arena)
{
    const int mode = (MODE_C >= 0) ? MODE_C : (mode_base + (int)blockIdx.y);
    const MP P = (mode == 0) ? P0 : P1;
    const float* gt  = (mode == 0) ? gt1 : gt2;
    const float* lng = (mode == 0) ? ln1g : ln2g;
    const float* lnb = (mode == 0) ? ln1b : ln2b;
    float* VB = VB0 + (size_t)blockIdx.y * arena;
    float* sc = SC0 + (size_t)blockIdx.y * arena;

    const int n = blockIdx.x / NT, tile = blockIdx.x % NT;
    const int t0 = tile * TT;
    const int ntk = min(TT, TLEN - t0);
    const int nth = ntk + 3;  // with 3-token front halo
    const int b = n >> 6, cube = n & 63, bi = cube >> 3, bj = cube & 7;
    const int tid = threadIdx.x;

    // s_v [TT+3][17] overlaid on s_xc [TT][37]: disjoint lifetimes
    __shared__ __align__(16) float s_pool[TT * 37];
    float (*s_v)[17]  = (float(*)[17])s_pool;
    float (*s_xc)[37] = (float(*)[37])s_pool;
    __shared__ __align__(16) float s_xi[TT + 3][36];
    __shared__ __align__(16) float s_wT[16][32];   // s_wT[k][oc] = in_w[oc][k], xi half
    __shared__ __align__(16) float s_xpT[32][36];  // s_xpT[cc][q] = xproj_w[q+1][cc]
    __shared__ float s_xp0[32];
    __shared__ float s_cw[128], s_cb[32], s_dw[32], s_db[32];
    __shared__ float s_g[16], s_bb[16], s_gt[16];
    __shared__ float s_dt0[TT];

    for (int i = tid; i < 32 * 16; i += 256) s_wT[i & 15][i >> 4] = P.in_w[i];
    for (int i = tid; i < 33 * 32; i += 256) {
        int r = i >> 5, cc = i & 31;
        float v = P.xproj_w[i];
        if (r == 0) s_xp0[cc] = v;
        else s_xpT[cc][r - 1] = v;
    }
    if (tid < 128) s_cw[tid] = P.conv_w[tid];
    if (tid < 32) { s_cb[tid] = P.conv_b[tid]; s_dw[tid] = P.dt_w[tid]; s_db[tid] = P.dt_b[tid]; }
    if (tid < 16) { s_g[tid] = lng[tid]; s_bb[tid] = lnb[tid]; s_gt[tid] = gt[tid]; }
    __syncthreads();

    // ---- gather, element-per-thread (all 256 threads issue loads)
    for (int it = tid; it < nth * 16; it += 256) {
        int tl = it >> 4, k = it & 15;
        int t = t0 - 3 + tl;
        float v;
        if (t < 0) v = 0.f;
        else if (MODE_C >= 0) v = gather_val<(MODE_C >= 0 ? MODE_C : 0)>(x, s_gt, t, k, b, bi, bj);
        else v = gather_rt(mode, x, s_gt, t, k, b, bi, bj);
        s_v[tl][k] = v;
    }
    __syncthreads();

    // ---- layernorm, token-per-thread from LDS
    for (int tl = tid; tl < nth; tl += 256) {
        int t = t0 - 3 + tl;
        if (t < 0) continue;
        float v[16], mu = 0.f;
#pragma unroll
        for (int k = 0; k < 16; k++) { v[k] = s_v[tl][k]; mu += v[k]; }
        mu *= (1.f / 16.f);
        float var = 0.f;
#pragma unroll
        for (int k = 0; k < 16; k++) { float d = v[k] - mu; var += d * d; }
        float inv = rsqrtf(var * (1.f / 16.f) + 1e-5f);
#pragma unroll
        for (int k = 0; k < 16; k++) s_v[tl][k] = (v[k] - mu) * inv * s_g[k] + s_bb[k];
    }
    __syncthreads();

    // ---- VB store (LN output, main tokens) + in-proj xi half, 4tok x 4oc tiles
    {
        float* vb = VB + ((size_t)n * TLEN + t0) * 16;
        for (int it = tid; it < ntk * 16; it += 256) {
            int j = it >> 4, k = it & 15;
            vb[it] = s_v[j + 3][k];
        }
        const int ntt = (nth + 3) >> 2;
        for (int tl0 = tid; tl0 < ntt * 8; tl0 += 256) {
            int tt = tl0 >> 3, og = tl0 & 7;
            int oc = og * 4;
            float acc[4][4] = {{0.f}};
#pragma unroll
            for (int k = 0; k < 16; k++) {
                float4 wv = *(const float4*)&s_wT[k][oc];
                float a0 = s_v[4 * tt + 0][k];
                float a1 = s_v[4 * tt + 1][k];
                float a2 = s_v[4 * tt + 2][k];
                float a3 = s_v[4 * tt + 3][k];
                acc[0][0] += a0 * wv.x; acc[0][1] += a0 * wv.y; acc[0][2] += a0 * wv.z; acc[0][3] += a0 * wv.w;
                acc[1][0] += a1 * wv.x; acc[1][1] += a1 * wv.y; acc[1][2] += a1 * wv.z; acc[1][3] += a1 * wv.w;
                acc[2][0] += a2 * wv.x; acc[2][1] += a2 * wv.y; acc[2][2] += a2 * wv.z; acc[2][3] += a2 * wv.w;
                acc[3][0] += a3 * wv.x; acc[3][1] += a3 * wv.y; acc[3][2] += a3 * wv.z; acc[3][3] += a3 * wv.w;
            }
#pragma unroll
            for (int i = 0; i < 4; i++) {
                int tl = 4 * tt + i;
                if (tl >= nth) break;
                *(float4*)&s_xi[tl][oc] =
                    make_float4(acc[i][0], acc[i][1], acc[i][2], acc[i][3]);
            }
        }
    }
    __syncthreads();  // s_v dead; pool becomes s_xc

    // ---- conv4 + silu: thread = (cc, token-group); emit xc to global here too
    {
        int cc = tid & 31, jg = tid >> 5;
        float c0 = s_cw[cc * 4 + 0], c1 = s_cw[cc * 4 + 1];
        float c2 = s_cw[cc * 4 + 2], c3 = s_cw[cc * 4 + 3];
        float cb = s_cb[cc];
        float* scb = sc + ((size_t)n * TLEN + t0) * 96;
        for (int j = jg; j < ntk; j += 8) {
            float acc = 0.f;
            acc += c0 * s_xi[j + 0][cc];
            acc += c1 * s_xi[j + 1][cc];
            acc += c2 * s_xi[j + 2][cc];
            acc += c3 * s_xi[j + 3][cc];
            float v = siluf(acc + cb);
            s_xc[j][cc] = v;
            scb[j * 96 + cc] = v;
        }
    }
    __syncthreads();

    // ---- x-proj B/C rows, 4-token x 4-q register tile
    {
        int qt = tid & 7, tt = tid >> 3;
        if (4 * tt < ntk) {
            float acc[4][4] = {{0.f}};
#pragma unroll
            for (int cc = 0; cc < 32; cc++) {
                float4 wv = *(const float4*)&s_xpT[cc][4 * qt];
                float a0 = s_xc[4 * tt + 0][cc];
                float a1 = s_xc[4 * tt + 1][cc];
                float a2 = s_xc[4 * tt + 2][cc];
                float a3 = s_xc[4 * tt + 3][cc];
                acc[0][0] += a0 * wv.x; acc[0][1] += a0 * wv.y; acc[0][2] += a0 * wv.z; acc[0][3] += a0 * wv.w;
                acc[1][0] += a1 * wv.x; acc[1][1] += a1 * wv.y; acc[1][2] += a1 * wv.z; acc[1][3] += a1 * wv.w;
                acc[2][0] += a2 * wv.x; acc[2][1] += a2 * wv.y; acc[2][2] += a2 * wv.z; acc[2][3] += a2 * wv.w;
                acc[3][0] += a3 * wv.x; acc[3][1] += a3 * wv.y; acc[3][2] += a3 * wv.z; acc[3][3] += a3 * wv.w;
            }
#pragma unroll
            for (int i = 0; i < 4; i++) {
                int j = 4 * tt + i;
                if (j < ntk)
                    *(float4*)&sc[((size_t)n * TLEN + t0 + j) * 96 + 64 + 4 * qt] =
                        make_float4(acc[i][0], acc[i][1], acc[i][2], acc[i][3]);
            }
        }
        // dt0 per token (reads only s_xc / s_xp0)
        if (tid < ntk) {
            float acc = 0.f;
#pragma unroll
            for (int cc = 0; cc < 32; cc++) acc += s_xc[tid][cc] * s_xp0[cc];
            s_dt0[tid] = acc;
        }
    }
    __syncthreads();

    // ---- dt block emit (coalesced stores)
    {
        float* scb = sc + ((size_t)n * TLEN + t0) * 96;
        for (int it = tid; it < ntk * 32; it += 256) {
            int j = it >> 5, d = it & 31;
            scb[j * 96 + 32 + d] = softplusf(s_dt0[j] * s_dw[d] + s_db[d]);
        }
    }
}

// -------- phase 2a: per-chunk scan summaries; stage only xc/dt/B (80 f) -----
template <int MODE_C>
__global__ __launch_bounds__(128) void k_scan1(
    const float* __restrict__ SC0, MP P0, MP P1, int mode_base,
    float* __restrict__ PS0, float* __restrict__ FS0, size_t arena)
{
    const int mode = (MODE_C >= 0) ? MODE_C : (mode_base + (int)blockIdx.y);
    const float* A_log = (mode == 0) ? P0.A_log : P1.A_log;
    const float* sc = SC0 + (size_t)blockIdx.y * arena;
    float* Psum = PS0 + (size_t)blockIdx.y * arena;
    float* Fsum = FS0 + (size_t)blockIdx.y * arena;

    int n = blockIdx.x >> 4;
    int c = blockIdx.x & (NCH - 1);
    int t0 = c * CHUNK;
    int nt = min(CHUNK, TLEN - t0);
    __shared__ __align__(16) float s_sc[CHUNK * 80];   // xc[32] dt[32] B[16]
    const float* src = sc + ((size_t)n * TLEN + t0) * 96;
    for (int i = threadIdx.x; i < nt * 20; i += 128) {
        int row = i / 20, q = i - row * 20;
        ((float4*)s_sc)[row * 20 + q] = *(const float4*)&src[row * 96 + q * 4];
    }
    int tid = threadIdx.x, d = tid >> 2, sg = tid & 3;
    float4 Av = *(const float4*)&A_log[d * 16 + sg * 4];
    float A0 = -__expf(Av.x), A1 = -__expf(Av.y), A2 = -__expf(Av.z), A3 = -__expf(Av.w);
    __syncthreads();
    float h0 = 0.f, h1 = 0.f, h2 = 0.f, h3 = 0.f;
    float P0v = 1.f, P1v = 1.f, P2v = 1.f, P3v = 1.f;
    for (int t = 0; t < nt; t++) {
        const float* p = s_sc + t * 80;
        float dt = p[32 + d], xc = p[d];
        float4 Bv = *(const float4*)&p[64 + sg * 4];
        float a0 = __expf(dt * A0); h0 = a0 * h0 + dt * Bv.x * xc; P0v *= a0;
        float a1 = __expf(dt * A1); h1 = a1 * h1 + dt * Bv.y * xc; P1v *= a1;
        float a2 = __expf(dt * A2); h2 = a2 * h2 + dt * Bv.z * xc; P2v *= a2;
        float a3 = __expf(dt * A3); h3 = a3 * h3 + dt * Bv.w * xc; P3v *= a3;
    }
    size_t base = ((size_t)n * NCH + c) * 512 + d * 16 + sg * 4;
    *(float4*)&Psum[base] = make_float4(P0v, P1v, P2v, P3v);
    *(float4*)&Fsum[base] = make_float4(h0, h1, h2, h3);
}

// -------- phase 2b: combine chunk summaries -> incoming state per chunk -----
__global__ __launch_bounds__(512) void k_comb(
    const float* __restrict__ PS0, const float* __restrict__ FS0,
    float* __restrict__ HI0, size_t arena)
{
    const float* Psum = PS0 + (size_t)blockIdx.y * arena;
    const float* Fsum = FS0 + (size_t)blockIdx.y * arena;
    float* Hin = HI0 + (size_t)blockIdx.y * arena;
    int n = blockIdx.x, tid = threadIdx.x;
    const float* pb = Psum + (size_t)n * NCH * 512;
    const float* fb = Fsum + (size_t)n * NCH * 512;
    float* hb = Hin + (size_t)n * NCH * 512;
    float H = 0.f;
#pragma unroll
    for (int c = 0; c < NCH; c++) {
        float P = pb[(size_t)c * 512 + tid];
        float F = fb[(size_t)c * 512 + tid];
        hb[(size_t)c * 512 + tid] = H;
        H = F + P * H;
    }
}

// --- phase 2c: scan pass 2; y overwrites staged xc slot in LDS, then SC -----
template <int MODE_C>
__global__ __launch_bounds__(128) void k_scan2(
    float* __restrict__ SC0, MP P0, MP P1, int mode_base,
    const float* __restrict__ HI0, size_t arena)
{
    const int mode = (MODE_C >= 0) ? MODE_C : (mode_base + (int)blockIdx.y);
    const float* A_log = (mode == 0) ? P0.A_log : P1.A_log;
    const float* Dp = (mode == 0) ? P0.D : P1.D;
    float* sc = SC0 + (size_t)blockIdx.y * arena;
    const float* Hin = HI0 + (size_t)blockIdx.y * arena;

    int n = blockIdx.x >> 4;
    int c = blockIdx.x & (NCH - 1);
    int t0 = c * CHUNK;
    int nt = min(CHUNK, TLEN - t0);
    __shared__ __align__(16) float s_sc[CHUNK * 96];
    const float* src = sc + ((size_t)n * TLEN + t0) * 96;
    int nv4 = nt * 24;
    for (int i = threadIdx.x; i < nv4; i += 128)
        ((float4*)s_sc)[i] = ((const float4*)src)[i];
    int tid = threadIdx.x, d = tid >> 2, sg = tid & 3;
    float4 Av = *(const float4*)&A_log[d * 16 + sg * 4];
    float A0 = -__expf(Av.x), A1 = -__expf(Av.y), A2 = -__expf(Av.z), A3 = -__expf(Av.w);
    float Dd = Dp[d];
    float4 Hv = *(const float4*)&Hin[((size_t)n * NCH + c) * 512 + d * 16 + sg * 4];
    float h0 = Hv.x, h1 = Hv.y, h2 = Hv.z, h3 = Hv.w;
    __syncthreads();
    // y[t][d] overwrites s_sc[t*96+d] after xc[t][d]'s final read.
    for (int t = 0; t < nt; t++) {
        float* p = s_sc + t * 96;
        float dt = p[32 + d], xc = p[d];
        float4 Bv = *(const float4*)&p[64 + sg * 4];
        float4 Cv = *(const float4*)&p[80 + sg * 4];
        float a0 = __expf(dt * A0); h0 = a0 * h0 + dt * Bv.x * xc;
        float a1 = __expf(dt * A1); h1 = a1 * h1 + dt * Bv.y * xc;
        float a2 = __expf(dt * A2); h2 = a2 * h2 + dt * Bv.z * xc;
        float a3 = __expf(dt * A3); h3 = a3 * h3 + dt * Bv.w * xc;
        float pp = h0 * Cv.x + h1 * Cv.y + h2 * Cv.z + h3 * Cv.w;
        pp += __shfl_xor(pp, 1);
        pp += __shfl_xor(pp, 2);
        if (sg == 0) p[d] = pp + Dd * xc;
    }
    __syncthreads();
    // write y (xc slot) back to SC in place
    float* yb = sc + ((size_t)n * TLEN + t0) * 96;
    for (int i = threadIdx.x; i < nt * 8; i += 128) {
        int j = i >> 3, q = i & 7;
        *(float4*)&yb[j * 96 + q * 4] = *(const float4*)&s_sc[j * 96 + q * 4];
    }
}

// -------- phase 3: z from VB + gate + out-proj + scatter (per-mode) ---------
// y lives in SC rows (stride 96, offset 0); v (LN out) in VB (16/token)
template <int MODE>
__global__ void k_p3(const float* __restrict__ ysc, const float* __restrict__ VB,
                     const float* __restrict__ in_w,   // (64,16), rows 32..63 = z
                     const float* __restrict__ out_w,  // (16,32)
                     float* __restrict__ out)
{
    __shared__ float s_w[16 * 32];
    __shared__ float s_wz[16][32];  // s_wz[k][c] = in_w[(32+c)*16+k]
    for (int i = threadIdx.x; i < 512; i += blockDim.x) {
        s_w[i] = out_w[i];
        int oc = i >> 4, k = i & 15;
        s_wz[k][oc] = in_w[(32 + oc) * 16 + k];
    }
    __syncthreads();
    int tid = blockIdx.x * blockDim.x + threadIdx.x;
    if (tid >= NSEQ * LSEQ) return;
    int n = tid >> 10, l = tid & 1023, t = l + 1;
    const float* y = ysc + ((size_t)n * TLEN + t) * 96;
    const float* vv = VB + ((size_t)n * TLEN + t) * 16;
    float v[16];
#pragma unroll
    for (int k = 0; k < 16; k++) v[k] = vv[k];
    float yv[32];
#pragma unroll
    for (int c = 0; c < 32; c++) {
        float z = 0.f;
#pragma unroll
        for (int k = 0; k < 16; k++) z += v[k] * s_wz[k][c];
        yv[c] = y[c] * siluf(z);
    }
    float o[16];
#pragma unroll
    for (int j = 0; j < 16; j++) {
        float acc = 0.f;
#pragma unroll
        for (int c = 0; c < 32; c++) acc += yv[c] * s_w[j * 32 + c];
        o[j] = acc * (1.0f / 3.0f);
    }
    int b = n >> 6, cube = n & 63;
    if (MODE == 0) {
        int i2 = l >> 5, j2 = l & 31;
        int io = i2 >> 1, jo = j2 >> 1;
        int coff = ((i2 & 1) << 1) | (j2 & 1);
#pragma unroll
        for (int j = 0; j < 16; j++) out[oidx(b, cube, j * 4 + coff, io, jo)] = o[j];
    } else if (MODE == 1) {
        int c = l >> 4, jj = l & 15;
#pragma unroll
        for (int j = 0; j < 16; j++) out[oidx(b, cube, c, j, jj)] += o[j];
    } else {
        int c = l >> 4, ii = l & 15;
#pragma unroll
        for (int j = 0; j < 16; j++) out[oidx(b, cube, c, ii, j)] += o[j];
    }
}

}  // namespace

extern "C" void kernel_launch(void* const* d_in, const int* in_sizes, int n_in,
                              void* d_out, int out_size, void* d_ws, size_t ws_size,
                              hipStream_t stream) {
    const float* x   = (const float*)d_in[0];
    const float* gt1 = (const float*)d_in[1];
    const float* gt2 = (const float*)d_in[2];
    const float* ln1g = (const float*)d_in[3];
    const float* ln1b = (const float*)d_in[4];
    const float* ln2g = (const float*)d_in[5];
    const float* ln2b = (const float*)d_in[6];
    MP P[2];
    for (int mi = 0; mi < 2; mi++) {
        P[mi].in_w   = (const float*)d_in[7 + mi * 9 + 0];
        P[mi].conv_w = (const float*)d_in[7 + mi * 9 + 1];
        P[mi].conv_b = (const float*)d_in[7 + mi * 9 + 2];
        P[mi].xproj_w= (const float*)d_in[7 + mi * 9 + 3];
        P[mi].dt_w   = (const float*)d_in[7 + mi * 9 + 4];
        P[mi].dt_b   = (const float*)d_in[7 + mi * 9 + 5];
        P[mi].A_log  = (const float*)d_in[7 + mi * 9 + 6];
        P[mi].D      = (const float*)d_in[7 + mi * 9 + 7];
        P[mi].out_w  = (const float*)d_in[7 + mi * 9 + 8];
    }
    float* out = (float*)d_out;

    const size_t VBs = (size_t)NSEQ * TLEN * 16;   // 2.1M floats (LN output)
    const size_t SCs = (size_t)NSEQ * TLEN * 96;   // 12.6M (y aliased in-place)
    const size_t PSs = (size_t)NSEQ * NCH * 512;   // 1.05M
    const size_t arena = VBs + SCs + 3 * PSs;      // 17.8M floats = 71.4 MB

    float* A0 = (float*)d_ws;
    auto VB = [&](int y) { return A0 + (size_t)y * arena; };
    auto SC = [&](int y) { return A0 + (size_t)y * arena + VBs; };
    auto PS = [&](int y) { return A0 + (size_t)y * arena + VBs + SCs; };
    auto FS = [&](int y) { return PS(y) + PSs; };
    auto HI = [&](int y) { return FS(y) + PSs; };

    const bool fits3 = ws_size >= 3 * arena * sizeof(float);
    const bool fits2 = ws_size >= 2 * arena * sizeof(float);

    dim3 b256(256), b128(128), b512(512);
    dim3 grd3((NSEQ * LSEQ + 255) / 256);

    if (fits3) {
        k_p1<-1><<<dim3(NSEQ * NT, 3), b256, 0, stream>>>(
            x, gt1, gt2, ln1g, ln1b, ln2g, ln2b, P[0], P[1], 0, VB(0), SC(0), arena);
        k_scan1<-1><<<dim3(NSEQ * NCH, 3), b128, 0, stream>>>(
            SC(0), P[0], P[1], 0, PS(0), FS(0), arena);
        k_comb<<<dim3(NSEQ, 3), b512, 0, stream>>>(PS(0), FS(0), HI(0), arena);
        k_scan2<-1><<<dim3(NSEQ * NCH, 3), b128, 0, stream>>>(
            SC(0), P[0], P[1], 0, HI(0), arena);
        k_p3<0><<<grd3, b256, 0, stream>>>(SC(0), VB(0), P[0].in_w, P[0].out_w, out);
        k_p3<1><<<grd3, b256, 0, stream>>>(SC(1), VB(1), P[1].in_w, P[1].out_w, out);
        k_p3<2><<<grd3, b256, 0, stream>>>(SC(2), VB(2), P[1].in_w, P[1].out_w, out);
    } else if (fits2) {
        k_p1<0><<<dim3(NSEQ * NT, 1), b256, 0, stream>>>(
            x, gt1, gt2, ln1g, ln1b, ln2g, ln2b, P[0], P[1], 0, VB(0), SC(0), arena);
        k_scan1<0><<<dim3(NSEQ * NCH, 1), b128, 0, stream>>>(
            SC(0), P[0], P[1], 0, PS(0), FS(0), arena);
        k_comb<<<dim3(NSEQ, 1), b512, 0, stream>>>(PS(0), FS(0), HI(0), arena);
        k_scan2<0><<<dim3(NSEQ * NCH, 1), b128, 0, stream>>>(
            SC(0), P[0], P[1], 0, HI(0), arena);
        k_p3<0><<<grd3, b256, 0, stream>>>(SC(0), VB(0), P[0].in_w, P[0].out_w, out);
        k_p1<-1><<<dim3(NSEQ * NT, 2), b256, 0, stream>>>(
            x, gt1, gt2, ln1g, ln1b, ln2g, ln2b, P[0], P[1], 1, VB(0), SC(0), arena);
        k_scan1<-1><<<dim3(NSEQ * NCH, 2), b128, 0, stream>>>(
            SC(0), P[0], P[1], 1, PS(0), FS(0), arena);
        k_comb<<<dim3(NSEQ, 2), b512, 0, stream>>>(PS(0), FS(0), HI(0), arena);
        k_scan2<-1><<<dim3(NSEQ * NCH, 2), b128, 0, stream>>>(
            SC(0), P[0], P[1], 1, HI(0), arena);
        k_p3<1><<<grd3, b256, 0, stream>>>(SC(0), VB(0), P[1].in_w, P[1].out_w, out);
        k_p3<2><<<grd3, b256, 0, stream>>>(SC(1), VB(1), P[1].in_w, P[1].out_w, out);
    } else {
        for (int mode = 0; mode < 3; mode++) {
            if (mode == 0)
                k_p1<0><<<dim3(NSEQ * NT, 1), b256, 0, stream>>>(
                    x, gt1, gt2, ln1g, ln1b, ln2g, ln2b, P[0], P[1], 0, VB(0), SC(0), arena);
            else if (mode == 1)
                k_p1<1><<<dim3(NSEQ * NT, 1), b256, 0, stream>>>(
                    x, gt1, gt2, ln1g, ln1b, ln2g, ln2b, P[0], P[1], 0, VB(0), SC(0), arena);
            else
                k_p1<2><<<dim3(NSEQ * NT, 1), b256, 0, stream>>>(
                    x, gt1, gt2, ln1g, ln1b, ln2g, ln2b, P[0], P[1], 0, VB(0), SC(0), arena);
            if (mode == 0)
                k_scan1<0><<<dim3(NSEQ * NCH, 1), b128, 0, stream>>>(SC(0), P[0], P[1], 0, PS(0), FS(0), arena);
            else if (mode == 1)
                k_scan1<1><<<dim3(NSEQ * NCH, 1), b128, 0, stream>>>(SC(0), P[0], P[1], 0, PS(0), FS(0), arena);
            else
                k_scan1<2><<<dim3(NSEQ * NCH, 1), b128, 0, stream>>>(SC(0), P[0], P[1], 0, PS(0), FS(0), arena);
            k_comb<<<dim3(NSEQ, 1), b512, 0, stream>>>(PS(0), FS(0), HI(0), arena);
            if (mode == 0)
                k_scan2<0><<<dim3(NSEQ * NCH, 1), b128, 0, stream>>>(SC(0), P[0], P[1], 0, HI(0), arena);
            else if (mode == 1)
                k_scan2<1><<<dim3(NSEQ * NCH, 1), b128, 0, stream>>>(SC(0), P[0], P[1], 0, HI(0), arena);
            else
                k_scan2<2><<<dim3(NSEQ * NCH, 1), b128, 0, stream>>>(SC(0), P[0], P[1], 0, HI(0), arena);
            if (mode == 0)      k_p3<0><<<grd3, b256, 0, stream>>>(SC(0), VB(0), P[0].in_w, P[0].out_w, out);
            else if (mode == 1) k_p3<1><<<grd3, b256, 0, stream>>>(SC(0), VB(0), P[1].in_w, P[1].out_w, out);
            else                k_p3<2><<<grd3, b256, 0, stream>>>(SC(0), VB(0), P[1].in_w, P[1].out_w, out);
        }
    }
}

// Round 20
// 293.419 us; speedup vs baseline: 1.5474x; 1.0524x over previous
//
#include <hip/hip_runtime.h>
#include <cmath>

namespace {

constexpr int XC = 64, XH = 128, XW = 128;
constexpr int NSEQ = 128;   // B(2) * 64 cubes
constexpr int TLEN = 1025;  // gt token + 1024
constexpr int LSEQ = 1024;
constexpr int TT = 96;      // token tile for fused p1
constexpr int NT = 11;      // ceil(1025/96)

struct MP {
    const float *in_w, *conv_w, *conv_b, *xproj_w, *dt_w, *dt_b, *A_log, *D, *out_w;
};

__device__ __forceinline__ int xidx(int b, int c, int h, int w) {
    return ((b * XC + c) * XH + h) * XW + w;
}
__device__ __forceinline__ int oidx(int b, int cube, int c, int i, int j) {
    int h = cube * 2 + (i >> 3);
    int w = ((i & 7) << 4) | j;
    return xidx(b, c, h, w);
}
__device__ __forceinline__ float siluf(float v) { return v / (1.0f + __expf(-v)); }
__device__ __forceinline__ float softplusf(float v) {
    return v > 20.0f ? v : log1pf(__expf(v));
}

template <int MODE>
__device__ __forceinline__ float gather_val(const float* __restrict__ x,
                                            const float* __restrict__ s_gt,
                                            int t, int k, int b, int bi, int bj) {
    if (t == 0) return s_gt[k];
    int l = t - 1;
    if (MODE == 0) {
        int i2 = l >> 5, j2 = l & 31;
        int h = bi * 16 + (i2 >> 1), w = bj * 16 + (j2 >> 1);
        int coff = ((i2 & 1) << 1) | (j2 & 1);
        return x[xidx(b, k * 4 + coff, h, w)];
    } else if (MODE == 1) {
        int c = l >> 4, j = l & 15;
        return x[xidx(b, c, bi * 16 + k, bj * 16 + j)];
    } else {
        int c = l >> 4, i = l & 15;
        return x[xidx(b, c, bi * 16 + i, bj * 16 + k)];
    }
}
__device__ __forceinline__ float gather_rt(int mode, const float* __restrict__ x,
                                           const float* __restrict__ s_gt,
                                           int t, int k, int b, int bi, int bj) {
    if (mode == 0) return gather_val<0>(x, s_gt, t, k, b, bi, bj);
    if (mode == 1) return gather_val<1>(x, s_gt, t, k, b, bi, bj);
    return gather_val<2>(x, s_gt, t, k, b, bi, bj);
}

// ==== phase 1: gather+LN+in-proj(xi)+conv+x-proj; LN output v -> VB =========
template <int MODE_C>
__global__ __launch_bounds__(256) void k_p1(
    const float* __restrict__ x,
    const float* __restrict__ gt1, const float* __restrict__ gt2,
    const float* __restrict__ ln1g, const float* __restrict__ ln1b,
    const float* __restrict__ ln2g, const float* __restrict__ ln2b,
    MP P0, MP P1, int mode_base,
    float* __restrict__ VB0, float* __restrict__ SC0, size_t arena)
{
    const int mode = (MODE_C >= 0) ? MODE_C : (mode_base + (int)blockIdx.y);
    const MP P = (mode == 0) ? P0 : P1;
    const float* gt  = (mode == 0) ? gt1 : gt2;
    const float* lng = (mode == 0) ? ln1g : ln2g;
    const float* lnb = (mode == 0) ? ln1b : ln2b;
    float* VB = VB0 + (size_t)blockIdx.y * arena;
    float* sc = SC0 + (size_t)blockIdx.y * arena;

    const int n = blockIdx.x / NT, tile = blockIdx.x % NT;
    const int t0 = tile * TT;
    const int ntk = min(TT, TLEN - t0);
    const int nth = ntk + 3;  // with 3-token front halo
    const int b = n >> 6, cube = n & 63, bi = cube >> 3, bj = cube & 7;
    const int tid = threadIdx.x;

    __shared__ __align__(16) float s_pool[TT * 37];
    float (*s_v)[17]  = (float(*)[17])s_pool;
    float (*s_xc)[37] = (float(*)[37])s_pool;
    __shared__ __align__(16) float s_xi[TT + 3][36];
    __shared__ __align__(16) float s_wT[16][32];   // in_w rows 0..31 transposed
    __shared__ __align__(16) float s_xpT[32][36];  // s_xpT[cc][q] = xproj_w[q+1][cc]
    __shared__ float s_xp0[32];
    __shared__ float s_cw[128], s_cb[32], s_dw[32], s_db[32];
    __shared__ float s_g[16], s_bb[16], s_gt[16];
    __shared__ float s_dt0[TT];

    for (int i = tid; i < 32 * 16; i += 256) s_wT[i & 15][i >> 4] = P.in_w[i];
    for (int i = tid; i < 33 * 32; i += 256) {
        int r = i >> 5, cc = i & 31;
        float v = P.xproj_w[i];
        if (r == 0) s_xp0[cc] = v;
        else s_xpT[cc][r - 1] = v;
    }
    if (tid < 128) s_cw[tid] = P.conv_w[tid];
    if (tid < 32) { s_cb[tid] = P.conv_b[tid]; s_dw[tid] = P.dt_w[tid]; s_db[tid] = P.dt_b[tid]; }
    if (tid < 16) { s_g[tid] = lng[tid]; s_bb[tid] = lnb[tid]; s_gt[tid] = gt[tid]; }
    __syncthreads();

    // ---- gather, element-per-thread
    for (int it = tid; it < nth * 16; it += 256) {
        int tl = it >> 4, k = it & 15;
        int t = t0 - 3 + tl;
        float v;
        if (t < 0) v = 0.f;
        else if (MODE_C >= 0) v = gather_val<(MODE_C >= 0 ? MODE_C : 0)>(x, s_gt, t, k, b, bi, bj);
        else v = gather_rt(mode, x, s_gt, t, k, b, bi, bj);
        s_v[tl][k] = v;
    }
    __syncthreads();

    // ---- layernorm, token-per-thread from LDS
    for (int tl = tid; tl < nth; tl += 256) {
        int t = t0 - 3 + tl;
        if (t < 0) continue;
        float v[16], mu = 0.f;
#pragma unroll
        for (int k = 0; k < 16; k++) { v[k] = s_v[tl][k]; mu += v[k]; }
        mu *= (1.f / 16.f);
        float var = 0.f;
#pragma unroll
        for (int k = 0; k < 16; k++) { float d = v[k] - mu; var += d * d; }
        float inv = rsqrtf(var * (1.f / 16.f) + 1e-5f);
#pragma unroll
        for (int k = 0; k < 16; k++) s_v[tl][k] = (v[k] - mu) * inv * s_g[k] + s_bb[k];
    }
    __syncthreads();

    // ---- VB store (LN output) + in-proj xi half, 4tok x 4oc tiles
    {
        float* vb = VB + ((size_t)n * TLEN + t0) * 16;
        for (int it = tid; it < ntk * 16; it += 256) {
            int j = it >> 4, k = it & 15;
            vb[it] = s_v[j + 3][k];
        }
        const int ntt = (nth + 3) >> 2;
        for (int tl0 = tid; tl0 < ntt * 8; tl0 += 256) {
            int tt = tl0 >> 3, og = tl0 & 7;
            int oc = og * 4;
            float acc[4][4] = {{0.f}};
#pragma unroll
            for (int k = 0; k < 16; k++) {
                float4 wv = *(const float4*)&s_wT[k][oc];
                float a0 = s_v[4 * tt + 0][k];
                float a1 = s_v[4 * tt + 1][k];
                float a2 = s_v[4 * tt + 2][k];
                float a3 = s_v[4 * tt + 3][k];
                acc[0][0] += a0 * wv.x; acc[0][1] += a0 * wv.y; acc[0][2] += a0 * wv.z; acc[0][3] += a0 * wv.w;
                acc[1][0] += a1 * wv.x; acc[1][1] += a1 * wv.y; acc[1][2] += a1 * wv.z; acc[1][3] += a1 * wv.w;
                acc[2][0] += a2 * wv.x; acc[2][1] += a2 * wv.y; acc[2][2] += a2 * wv.z; acc[2][3] += a2 * wv.w;
                acc[3][0] += a3 * wv.x; acc[3][1] += a3 * wv.y; acc[3][2] += a3 * wv.z; acc[3][3] += a3 * wv.w;
            }
#pragma unroll
            for (int i = 0; i < 4; i++) {
                int tl = 4 * tt + i;
                if (tl >= nth) break;
                *(float4*)&s_xi[tl][oc] =
                    make_float4(acc[i][0], acc[i][1], acc[i][2], acc[i][3]);
            }
        }
    }
    __syncthreads();  // s_v dead; pool becomes s_xc

    // ---- conv4 + silu; emit xc to global inline
    {
        int cc = tid & 31, jg = tid >> 5;
        float c0 = s_cw[cc * 4 + 0], c1 = s_cw[cc * 4 + 1];
        float c2 = s_cw[cc * 4 + 2], c3 = s_cw[cc * 4 + 3];
        float cb = s_cb[cc];
        float* scb = sc + ((size_t)n * TLEN + t0) * 96;
        for (int j = jg; j < ntk; j += 8) {
            float acc = 0.f;
            acc += c0 * s_xi[j + 0][cc];
            acc += c1 * s_xi[j + 1][cc];
            acc += c2 * s_xi[j + 2][cc];
            acc += c3 * s_xi[j + 3][cc];
            float v = siluf(acc + cb);
            s_xc[j][cc] = v;
            scb[j * 96 + cc] = v;
        }
    }
    __syncthreads();

    // ---- x-proj B/C rows, 4-token x 4-q register tile
    {
        int qt = tid & 7, tt = tid >> 3;
        if (4 * tt < ntk) {
            float acc[4][4] = {{0.f}};
#pragma unroll
            for (int cc = 0; cc < 32; cc++) {
                float4 wv = *(const float4*)&s_xpT[cc][4 * qt];
                float a0 = s_xc[4 * tt + 0][cc];
                float a1 = s_xc[4 * tt + 1][cc];
                float a2 = s_xc[4 * tt + 2][cc];
                float a3 = s_xc[4 * tt + 3][cc];
                acc[0][0] += a0 * wv.x; acc[0][1] += a0 * wv.y; acc[0][2] += a0 * wv.z; acc[0][3] += a0 * wv.w;
                acc[1][0] += a1 * wv.x; acc[1][1] += a1 * wv.y; acc[1][2] += a1 * wv.z; acc[1][3] += a1 * wv.w;
                acc[2][0] += a2 * wv.x; acc[2][1] += a2 * wv.y; acc[2][2] += a2 * wv.z; acc[2][3] += a2 * wv.w;
                acc[3][0] += a3 * wv.x; acc[3][1] += a3 * wv.y; acc[3][2] += a3 * wv.z; acc[3][3] += a3 * wv.w;
            }
#pragma unroll
            for (int i = 0; i < 4; i++) {
                int j = 4 * tt + i;
                if (j < ntk)
                    *(float4*)&sc[((size_t)n * TLEN + t0 + j) * 96 + 64 + 4 * qt] =
                        make_float4(acc[i][0], acc[i][1], acc[i][2], acc[i][3]);
            }
        }
        if (tid < ntk) {
            float acc = 0.f;
#pragma unroll
            for (int cc = 0; cc < 32; cc++) acc += s_xc[tid][cc] * s_xp0[cc];
            s_dt0[tid] = acc;
        }
    }
    __syncthreads();

    // ---- dt block emit
    {
        float* scb = sc + ((size_t)n * TLEN + t0) * 96;
        for (int it = tid; it < ntk * 32; it += 256) {
            int j = it >> 5, d = it & 31;
            scb[j * 96 + 32 + d] = softplusf(s_dt0[j] * s_dw[d] + s_db[d]);
        }
    }
}

// -------- phase 2a: per-chunk scan summaries; stage only xc/dt/B (80 f) -----
template <int MODE_C, int CHUNKT, int NCHT>
__global__ __launch_bounds__(128) void k_scan1(
    const float* __restrict__ SC0, MP P0, MP P1, int mode_base,
    float* __restrict__ PS0, float* __restrict__ FS0, size_t arena)
{
    const int mode = (MODE_C >= 0) ? MODE_C : (mode_base + (int)blockIdx.y);
    const float* A_log = (mode == 0) ? P0.A_log : P1.A_log;
    const float* sc = SC0 + (size_t)blockIdx.y * arena;
    float* Psum = PS0 + (size_t)blockIdx.y * arena;
    float* Fsum = FS0 + (size_t)blockIdx.y * arena;

    int n = blockIdx.x / NCHT;
    int c = blockIdx.x % NCHT;
    int t0 = c * CHUNKT;
    int nt = min(CHUNKT, TLEN - t0);
    __shared__ __align__(16) float s_sc[CHUNKT * 80];   // xc[32] dt[32] B[16]
    const float* src = sc + ((size_t)n * TLEN + t0) * 96;
    for (int i = threadIdx.x; i < nt * 20; i += 128) {
        int row = i / 20, q = i - row * 20;
        ((float4*)s_sc)[row * 20 + q] = *(const float4*)&src[row * 96 + q * 4];
    }
    int tid = threadIdx.x, d = tid >> 2, sg = tid & 3;
    float4 Av = *(const float4*)&A_log[d * 16 + sg * 4];
    float A0 = -__expf(Av.x), A1 = -__expf(Av.y), A2 = -__expf(Av.z), A3 = -__expf(Av.w);
    __syncthreads();
    float h0 = 0.f, h1 = 0.f, h2 = 0.f, h3 = 0.f;
    float P0v = 1.f, P1v = 1.f, P2v = 1.f, P3v = 1.f;
    for (int t = 0; t < nt; t++) {
        const float* p = s_sc + t * 80;
        float dt = p[32 + d], xc = p[d];
        float4 Bv = *(const float4*)&p[64 + sg * 4];
        float a0 = __expf(dt * A0); h0 = a0 * h0 + dt * Bv.x * xc; P0v *= a0;
        float a1 = __expf(dt * A1); h1 = a1 * h1 + dt * Bv.y * xc; P1v *= a1;
        float a2 = __expf(dt * A2); h2 = a2 * h2 + dt * Bv.z * xc; P2v *= a2;
        float a3 = __expf(dt * A3); h3 = a3 * h3 + dt * Bv.w * xc; P3v *= a3;
    }
    size_t base = ((size_t)n * NCHT + c) * 512 + d * 16 + sg * 4;
    *(float4*)&Psum[base] = make_float4(P0v, P1v, P2v, P3v);
    *(float4*)&Fsum[base] = make_float4(h0, h1, h2, h3);
}

// -------- phase 2b: combine chunk summaries -> incoming state per chunk -----
template <int NCHT>
__global__ __launch_bounds__(512) void k_comb(
    const float* __restrict__ PS0, const float* __restrict__ FS0,
    float* __restrict__ HI0, size_t arena)
{
    const float* Psum = PS0 + (size_t)blockIdx.y * arena;
    const float* Fsum = FS0 + (size_t)blockIdx.y * arena;
    float* Hin = HI0 + (size_t)blockIdx.y * arena;
    int n = blockIdx.x, tid = threadIdx.x;
    const float* pb = Psum + (size_t)n * NCHT * 512;
    const float* fb = Fsum + (size_t)n * NCHT * 512;
    float* hb = Hin + (size_t)n * NCHT * 512;
    float H = 0.f;
#pragma unroll
    for (int c = 0; c < NCHT; c++) {
        float P = pb[(size_t)c * 512 + tid];
        float F = fb[(size_t)c * 512 + tid];
        hb[(size_t)c * 512 + tid] = H;
        H = F + P * H;
    }
}

// --- phase 2c: scan pass 2; y overwrites staged xc slot in LDS, then SC -----
template <int MODE_C, int CHUNKT, int NCHT>
__global__ __launch_bounds__(128) void k_scan2(
    float* __restrict__ SC0, MP P0, MP P1, int mode_base,
    const float* __restrict__ HI0, size_t arena)
{
    const int mode = (MODE_C >= 0) ? MODE_C : (mode_base + (int)blockIdx.y);
    const float* A_log = (mode == 0) ? P0.A_log : P1.A_log;
    const float* Dp = (mode == 0) ? P0.D : P1.D;
    float* sc = SC0 + (size_t)blockIdx.y * arena;
    const float* Hin = HI0 + (size_t)blockIdx.y * arena;

    int n = blockIdx.x / NCHT;
    int c = blockIdx.x % NCHT;
    int t0 = c * CHUNKT;
    int nt = min(CHUNKT, TLEN - t0);
    __shared__ __align__(16) float s_sc[CHUNKT * 96];
    const float* src = sc + ((size_t)n * TLEN + t0) * 96;
    int nv4 = nt * 24;
    for (int i = threadIdx.x; i < nv4; i += 128)
        ((float4*)s_sc)[i] = ((const float4*)src)[i];
    int tid = threadIdx.x, d = tid >> 2, sg = tid & 3;
    float4 Av = *(const float4*)&A_log[d * 16 + sg * 4];
    float A0 = -__expf(Av.x), A1 = -__expf(Av.y), A2 = -__expf(Av.z), A3 = -__expf(Av.w);
    float Dd = Dp[d];
    float4 Hv = *(const float4*)&Hin[((size_t)n * NCHT + c) * 512 + d * 16 + sg * 4];
    float h0 = Hv.x, h1 = Hv.y, h2 = Hv.z, h3 = Hv.w;
    __syncthreads();
    for (int t = 0; t < nt; t++) {
        float* p = s_sc + t * 96;
        float dt = p[32 + d], xc = p[d];
        float4 Bv = *(const float4*)&p[64 + sg * 4];
        float4 Cv = *(const float4*)&p[80 + sg * 4];
        float a0 = __expf(dt * A0); h0 = a0 * h0 + dt * Bv.x * xc;
        float a1 = __expf(dt * A1); h1 = a1 * h1 + dt * Bv.y * xc;
        float a2 = __expf(dt * A2); h2 = a2 * h2 + dt * Bv.z * xc;
        float a3 = __expf(dt * A3); h3 = a3 * h3 + dt * Bv.w * xc;
        float pp = h0 * Cv.x + h1 * Cv.y + h2 * Cv.z + h3 * Cv.w;
        pp += __shfl_xor(pp, 1);
        pp += __shfl_xor(pp, 2);
        if (sg == 0) p[d] = pp + Dd * xc;
    }
    __syncthreads();
    float* yb = sc + ((size_t)n * TLEN + t0) * 96;
    for (int i = threadIdx.x; i < nt * 8; i += 128) {
        int j = i >> 3, q = i & 7;
        *(float4*)&yb[j * 96 + q * 4] = *(const float4*)&s_sc[j * 96 + q * 4];
    }
}

// -------- phase 3: z from VB + gate + out-proj + scatter (per-mode) ---------
template <int MODE>
__global__ void k_p3(const float* __restrict__ ysc, const float* __restrict__ VB,
                     const float* __restrict__ in_w,   // (64,16), rows 32..63 = z
                     const float* __restrict__ out_w,  // (16,32)
                     float* __restrict__ out)
{
    __shared__ float s_w[16 * 32];
    __shared__ float s_wz[16][32];
    for (int i = threadIdx.x; i < 512; i += blockDim.x) {
        s_w[i] = out_w[i];
        int oc = i >> 4, k = i & 15;
        s_wz[k][oc] = in_w[(32 + oc) * 16 + k];
    }
    __syncthreads();
    int tid = blockIdx.x * blockDim.x + threadIdx.x;
    if (tid >= NSEQ * LSEQ) return;
    int n = tid >> 10, l = tid & 1023, t = l + 1;
    const float* y = ysc + ((size_t)n * TLEN + t) * 96;
    const float* vv = VB + ((size_t)n * TLEN + t) * 16;
    float v[16];
#pragma unroll
    for (int k = 0; k < 16; k++) v[k] = vv[k];
    float yv[32];
#pragma unroll
    for (int c = 0; c < 32; c++) {
        float z = 0.f;
#pragma unroll
        for (int k = 0; k < 16; k++) z += v[k] * s_wz[k][c];
        yv[c] = y[c] * siluf(z);
    }
    float o[16];
#pragma unroll
    for (int j = 0; j < 16; j++) {
        float acc = 0.f;
#pragma unroll
        for (int c = 0; c < 32; c++) acc += yv[c] * s_w[j * 32 + c];
        o[j] = acc * (1.0f / 3.0f);
    }
    int b = n >> 6, cube = n & 63;
    if (MODE == 0) {
        int i2 = l >> 5, j2 = l & 31;
        int io = i2 >> 1, jo = j2 >> 1;
        int coff = ((i2 & 1) << 1) | (j2 & 1);
#pragma unroll
        for (int j = 0; j < 16; j++) out[oidx(b, cube, j * 4 + coff, io, jo)] = o[j];
    } else if (MODE == 1) {
        int c = l >> 4, jj = l & 15;
#pragma unroll
        for (int j = 0; j < 16; j++) out[oidx(b, cube, c, j, jj)] += o[j];
    } else {
        int c = l >> 4, ii = l & 15;
#pragma unroll
        for (int j = 0; j < 16; j++) out[oidx(b, cube, c, ii, j)] += o[j];
    }
}

}  // namespace

extern "C" void kernel_launch(void* const* d_in, const int* in_sizes, int n_in,
                              void* d_out, int out_size, void* d_ws, size_t ws_size,
                              hipStream_t stream) {
    const float* x   = (const float*)d_in[0];
    const float* gt1 = (const float*)d_in[1];
    const float* gt2 = (const float*)d_in[2];
    const float* ln1g = (const float*)d_in[3];
    const float* ln1b = (const float*)d_in[4];
    const float* ln2g = (const float*)d_in[5];
    const float* ln2b = (const float*)d_in[6];
    MP P[2];
    for (int mi = 0; mi < 2; mi++) {
        P[mi].in_w   = (const float*)d_in[7 + mi * 9 + 0];
        P[mi].conv_w = (const float*)d_in[7 + mi * 9 + 1];
        P[mi].conv_b = (const float*)d_in[7 + mi * 9 + 2];
        P[mi].xproj_w= (const float*)d_in[7 + mi * 9 + 3];
        P[mi].dt_w   = (const float*)d_in[7 + mi * 9 + 4];
        P[mi].dt_b   = (const float*)d_in[7 + mi * 9 + 5];
        P[mi].A_log  = (const float*)d_in[7 + mi * 9 + 6];
        P[mi].D      = (const float*)d_in[7 + mi * 9 + 7];
        P[mi].out_w  = (const float*)d_in[7 + mi * 9 + 8];
    }
    float* out = (float*)d_out;

    const size_t VBs = (size_t)NSEQ * TLEN * 16;
    const size_t SCs = (size_t)NSEQ * TLEN * 96;
    const size_t PS16 = (size_t)NSEQ * 16 * 512;
    const size_t PS32 = (size_t)NSEQ * 32 * 512;
    const size_t arena16 = VBs + SCs + 3 * PS16;   // 71.4 MB
    const size_t arena32 = VBs + SCs + 3 * PS32;   // 84.0 MB

    float* A0 = (float*)d_ws;
    dim3 b256(256), b128(128), b512(512);
    dim3 grd3((NSEQ * LSEQ + 255) / 256);

    const bool fits3_32 = ws_size >= 3 * arena32 * sizeof(float);
    const bool fits3_16 = ws_size >= 3 * arena16 * sizeof(float);
    const bool fits2_16 = ws_size >= 2 * arena16 * sizeof(float);

    if (fits3_32) {
        const size_t arena = arena32;
        auto VB = [&](int y) { return A0 + (size_t)y * arena; };
        auto SC = [&](int y) { return A0 + (size_t)y * arena + VBs; };
        auto PS = [&](int y) { return A0 + (size_t)y * arena + VBs + SCs; };
        auto FS = [&](int y) { return PS(y) + PS32; };
        auto HI = [&](int y) { return FS(y) + PS32; };
        k_p1<-1><<<dim3(NSEQ * NT, 3), b256, 0, stream>>>(
            x, gt1, gt2, ln1g, ln1b, ln2g, ln2b, P[0], P[1], 0, VB(0), SC(0), arena);
        k_scan1<-1, 33, 32><<<dim3(NSEQ * 32, 3), b128, 0, stream>>>(
            SC(0), P[0], P[1], 0, PS(0), FS(0), arena);
        k_comb<32><<<dim3(NSEQ, 3), b512, 0, stream>>>(PS(0), FS(0), HI(0), arena);
        k_scan2<-1, 33, 32><<<dim3(NSEQ * 32, 3), b128, 0, stream>>>(
            SC(0), P[0], P[1], 0, HI(0), arena);
        k_p3<0><<<grd3, b256, 0, stream>>>(SC(0), VB(0), P[0].in_w, P[0].out_w, out);
        k_p3<1><<<grd3, b256, 0, stream>>>(SC(1), VB(1), P[1].in_w, P[1].out_w, out);
        k_p3<2><<<grd3, b256, 0, stream>>>(SC(2), VB(2), P[1].in_w, P[1].out_w, out);
    } else if (fits3_16) {
        const size_t arena = arena16;
        auto VB = [&](int y) { return A0 + (size_t)y * arena; };
        auto SC = [&](int y) { return A0 + (size_t)y * arena + VBs; };
        auto PS = [&](int y) { return A0 + (size_t)y * arena + VBs + SCs; };
        auto FS = [&](int y) { return PS(y) + PS16; };
        auto HI = [&](int y) { return FS(y) + PS16; };
        k_p1<-1><<<dim3(NSEQ * NT, 3), b256, 0, stream>>>(
            x, gt1, gt2, ln1g, ln1b, ln2g, ln2b, P[0], P[1], 0, VB(0), SC(0), arena);
        k_scan1<-1, 65, 16><<<dim3(NSEQ * 16, 3), b128, 0, stream>>>(
            SC(0), P[0], P[1], 0, PS(0), FS(0), arena);
        k_comb<16><<<dim3(NSEQ, 3), b512, 0, stream>>>(PS(0), FS(0), HI(0), arena);
        k_scan2<-1, 65, 16><<<dim3(NSEQ * 16, 3), b128, 0, stream>>>(
            SC(0), P[0], P[1], 0, HI(0), arena);
        k_p3<0><<<grd3, b256, 0, stream>>>(SC(0), VB(0), P[0].in_w, P[0].out_w, out);
        k_p3<1><<<grd3, b256, 0, stream>>>(SC(1), VB(1), P[1].in_w, P[1].out_w, out);
        k_p3<2><<<grd3, b256, 0, stream>>>(SC(2), VB(2), P[1].in_w, P[1].out_w, out);
    } else if (fits2_16) {
        const size_t arena = arena16;
        auto VB = [&](int y) { return A0 + (size_t)y * arena; };
        auto SC = [&](int y) { return A0 + (size_t)y * arena + VBs; };
        auto PS = [&](int y) { return A0 + (size_t)y * arena + VBs + SCs; };
        auto FS = [&](int y) { return PS(y) + PS16; };
        auto HI = [&](int y) { return FS(y) + PS16; };
        k_p1<0><<<dim3(NSEQ * NT, 1), b256, 0, stream>>>(
            x, gt1, gt2, ln1g, ln1b, ln2g, ln2b, P[0], P[1], 0, VB(0), SC(0), arena);
        k_scan1<0, 65, 16><<<dim3(NSEQ * 16, 1), b128, 0, stream>>>(
            SC(0), P[0], P[1], 0, PS(0), FS(0), arena);
        k_comb<16><<<dim3(NSEQ, 1), b512, 0, stream>>>(PS(0), FS(0), HI(0), arena);
        k_scan2<0, 65, 16><<<dim3(NSEQ * 16, 1), b128, 0, stream>>>(
            SC(0), P[0], P[1], 0, HI(0), arena);
        k_p3<0><<<grd3, b256, 0, stream>>>(SC(0), VB(0), P[0].in_w, P[0].out_w, out);
        k_p1<-1><<<dim3(NSEQ * NT, 2), b256, 0, stream>>>(
            x, gt1, gt2, ln1g, ln1b, ln2g, ln2b, P[0], P[1], 1, VB(0), SC(0), arena);
        k_scan1<-1, 65, 16><<<dim3(NSEQ * 16, 2), b128, 0, stream>>>(
            SC(0), P[0], P[1], 1, PS(0), FS(0), arena);
        k_comb<16><<<dim3(NSEQ, 2), b512, 0, stream>>>(PS(0), FS(0), HI(0), arena);
        k_scan2<-1, 65, 16><<<dim3(NSEQ * 16, 2), b128, 0, stream>>>(
            SC(0), P[0], P[1], 1, HI(0), arena);
        k_p3<1><<<grd3, b256, 0, stream>>>(SC(0), VB(0), P[1].in_w, P[1].out_w, out);
        k_p3<2><<<grd3, b256, 0, stream>>>(SC(1), VB(1), P[1].in_w, P[1].out_w, out);
    } else {
        const size_t arena = arena16;
        auto VB = [&](int y) { return A0 + (size_t)y * arena; };
        auto SC = [&](int y) { return A0 + (size_t)y * arena + VBs; };
        auto PS = [&](int y) { return A0 + (size_t)y * arena + VBs + SCs; };
        auto FS = [&](int y) { return PS(y) + PS16; };
        auto HI = [&](int y) { return FS(y) + PS16; };
        for (int mode = 0; mode < 3; mode++) {
            if (mode == 0)
                k_p1<0><<<dim3(NSEQ * NT, 1), b256, 0, stream>>>(
                    x, gt1, gt2, ln1g, ln1b, ln2g, ln2b, P[0], P[1], 0, VB(0), SC(0), arena);
            else if (mode == 1)
                k_p1<1><<<dim3(NSEQ * NT, 1), b256, 0, stream>>>(
                    x, gt1, gt2, ln1g, ln1b, ln2g, ln2b, P[0], P[1], 0, VB(0), SC(0), arena);
            else
                k_p1<2><<<dim3(NSEQ * NT, 1), b256, 0, stream>>>(
                    x, gt1, gt2, ln1g, ln1b, ln2g, ln2b, P[0], P[1], 0, VB(0), SC(0), arena);
            if (mode == 0)
                k_scan1<0, 65, 16><<<dim3(NSEQ * 16, 1), b128, 0, stream>>>(SC(0), P[0], P[1], 0, PS(0), FS(0), arena);
            else if (mode == 1)
                k_scan1<1, 65, 16><<<dim3(NSEQ * 16, 1), b128, 0, stream>>>(SC(0), P[0], P[1], 0, PS(0), FS(0), arena);
            else
                k_scan1<2, 65, 16><<<dim3(NSEQ * 16, 1), b128, 0, stream>>>(SC(0), P[0], P[1], 0, PS(0), FS(0), arena);
            k_comb<16><<<dim3(NSEQ, 1), b512, 0, stream>>>(PS(0), FS(0), HI(0), arena);
            if (mode == 0)
                k_scan2<0, 65, 16><<<dim3(NSEQ * 16, 1), b128, 0, stream>>>(SC(0), P[0], P[1], 0, HI(0), arena);
            else if (mode == 1)
                k_scan2<1, 65, 16><<<dim3(NSEQ * 16, 1), b128, 0, stream>>>(SC(0), P[0], P[1], 0, HI(0), arena);
            else
                k_scan2<2, 65, 16><<<dim3(NSEQ * 16, 1), b128, 0, stream>>>(SC(0), P[0], P[1], 0, HI(0), arena);
            if (mode == 0)      k_p3<0><<<grd3, b256, 0, stream>>>(SC(0), VB(0), P[0].in_w, P[0].out_w, out);
            else if (mode == 1) k_p3<1><<<grd3, b256, 0, stream>>>(SC(0), VB(0), P[1].in_w, P[1].out_w, out);
            else                k_p3<2><<<grd3, b256, 0, stream>>>(SC(0), VB(0), P[1].in_w, P[1].out_w, out);
        }
    }
}